// Round 1
// baseline (1136.819 us; speedup 1.0000x reference)
//
#include <hip/hip_runtime.h>
#include <math.h>

// Problem constants
constexpr int BATCH  = 2;
constexpr int SEQ    = 2048;
constexpr int DMODEL = 512;
constexpr int NH     = 8;
constexpr int DHEAD  = 64;
constexpr int ROWS   = BATCH * SEQ;          // 4096
constexpr size_t SZ  = (size_t)ROWS * DMODEL; // one [4096][512] f32 buffer (floats)

// ---------------------------------------------------------------------------
// Mask-encoding detector: bool mask may arrive as int32 / float32 / raw bytes.
// Classify once from bit patterns; attention branches wave-uniformly on it.
//   bit0: saw int value not in {0,1}           (=> not int32 0/1)
//   bit1: saw value not in {0, 0x3F800000}     (=> not float32 0.0/1.0)
// mode: 0=int32, 1=float32, 2=bytes
// ---------------------------------------------------------------------------
__global__ void detect_mask_k(const unsigned* __restrict__ m, int* __restrict__ flag, int n)
{
    __shared__ int sh[2];
    if (threadIdx.x == 0) { sh[0] = 0; sh[1] = 0; }
    __syncthreads();
    unsigned b0 = 0, b1 = 0;
    for (int i = threadIdx.x; i < n; i += 256) {
        unsigned v = m[i];
        b0 |= (v > 1u) ? 1u : 0u;
        b1 |= (v != 0u && v != 0x3F800000u) ? 1u : 0u;
    }
    if (b0) atomicOr(&sh[0], 1);
    if (b1) atomicOr(&sh[1], 1);
    __syncthreads();
    if (threadIdx.x == 0) *flag = sh[0] | (sh[1] << 1);
}

// ---------------------------------------------------------------------------
// Tiled fp32 GEMM: C[M,Nd] = A[M,Kd] @ W[Kd,Nd] + bias, 128x128 tile, BK=8,
// 256 threads, 8x8 micro-tile per thread.
// EPI: 0 = plain+bias, 1 = relu+bias, 2 = QKV scatter to [B,H,N,64] buffers
// ---------------------------------------------------------------------------
template<int EPI>
__global__ __launch_bounds__(256) void gemm_k(
    const float* __restrict__ A, const float* __restrict__ W,
    const float* __restrict__ bias, float* __restrict__ C,
    float* __restrict__ Qo, float* __restrict__ Ko, float* __restrict__ Vo,
    int M, int Kd, int Nd)
{
    __shared__ float As[8][128];   // As[k][m]
    __shared__ float Ws[8][128];   // Ws[k][n]
    const int tid = threadIdx.x;
    const int tx = tid & 15, ty = tid >> 4;
    const int bm = blockIdx.y * 128, bn = blockIdx.x * 128;
    const int am = tid >> 1,  ak = (tid & 1) * 4;   // A tile load: 128 rows x 8 k
    const int wk = tid >> 5,  wn = (tid & 31) * 4;  // W tile load: 8 k x 128 n
    const float* Aptr = A + (size_t)(bm + am) * Kd + ak;
    const float* Wptr = W + (size_t)wk * Nd + bn + wn;

    float acc[8][8] = {};

    for (int k0 = 0; k0 < Kd; k0 += 8) {
        float4 av = *(const float4*)(Aptr + k0);
        float4 wv = *(const float4*)(Wptr + (size_t)k0 * Nd);
        __syncthreads();   // previous iteration's LDS reads complete
        As[ak+0][am] = av.x; As[ak+1][am] = av.y;
        As[ak+2][am] = av.z; As[ak+3][am] = av.w;
        *(float4*)&Ws[wk][wn] = wv;
        __syncthreads();
        #pragma unroll
        for (int kk = 0; kk < 8; ++kk) {
            float a[8], w[8];
            *(float4*)(a)     = *(const float4*)&As[kk][ty*8];
            *(float4*)(a + 4) = *(const float4*)&As[kk][ty*8 + 4];
            *(float4*)(w)     = *(const float4*)&Ws[kk][tx*8];
            *(float4*)(w + 4) = *(const float4*)&Ws[kk][tx*8 + 4];
            #pragma unroll
            for (int i = 0; i < 8; ++i)
                #pragma unroll
                for (int j = 0; j < 8; ++j)
                    acc[i][j] = fmaf(a[i], w[j], acc[i][j]);
        }
    }

    #pragma unroll
    for (int i = 0; i < 8; ++i) {
        const int mrow = bm + ty*8 + i;
        #pragma unroll
        for (int jh = 0; jh < 2; ++jh) {
            const int c0 = bn + tx*8 + jh*4;
            const float4 bi = *(const float4*)(bias + c0);
            float4 r;
            r.x = acc[i][jh*4+0] + bi.x;
            r.y = acc[i][jh*4+1] + bi.y;
            r.z = acc[i][jh*4+2] + bi.z;
            r.w = acc[i][jh*4+3] + bi.w;
            if (EPI == 1) {
                r.x = fmaxf(r.x, 0.f); r.y = fmaxf(r.y, 0.f);
                r.z = fmaxf(r.z, 0.f); r.w = fmaxf(r.w, 0.f);
            }
            if (EPI == 2) {
                // col c0 -> {q,k,v} part, head, d; row -> batch, seq
                const int part = c0 >> 9, hc = c0 & 511, hh = hc >> 6, d0 = hc & 63;
                const int bidx = mrow >> 11, nrow = mrow & 2047;
                float* dst = (part == 0) ? Qo : (part == 1) ? Ko : Vo;
                *(float4*)(dst + ((((size_t)bidx*NH + hh)*SEQ + nrow) << 6) + d0) = r;
            } else {
                *(float4*)(C + (size_t)mrow * Nd + c0) = r;
            }
        }
    }
}

// ---------------------------------------------------------------------------
// Flash-style attention, fp32, exact online softmax.
// Grid: B*H*(N/32) blocks, 256 threads. Q-tile = 32 rows, key chunks of 64.
// Thread (qp 0..15, g 0..15): rows {qp, qp+16}; scores for 4 keys; PV for 4 d.
// ---------------------------------------------------------------------------
__global__ __launch_bounds__(256) void attn_k(
    const float* __restrict__ Qb, const float* __restrict__ Kb,
    const float* __restrict__ Vb, const void* __restrict__ maskp,
    const int* __restrict__ flagp, float* __restrict__ outp)
{
    __shared__ float Qs[32][65];
    __shared__ float Ks[64][65];
    __shared__ float Vs[64][64];
    __shared__ float Ps[32][68];
    __shared__ float redA[32][16];
    __shared__ float redB[32][16];

    const int tid  = threadIdx.x;
    const int tile = blockIdx.x & 63;     // N/32 = 64 q-tiles
    const int bh   = blockIdx.x >> 6;     // 0..15
    const int b    = bh >> 3, h = bh & 7;
    const int q0   = tile * 32;
    const int g    = tid & 15, qp = tid >> 4;

    const int f = *flagp;
    const int mmode = (!(f & 1)) ? 0 : ((!(f & 2)) ? 1 : 2);
    const int*           m32 = (const int*)maskp;
    const float*         mfv = (const float*)maskp;
    const unsigned char* m8  = (const unsigned char*)maskp;
    const size_t mbase = (size_t)b * SEQ * SEQ;

    {   // stage Q tile (32x64)
        const float* Qg = Qb + ((size_t)bh * SEQ + q0) * DHEAD;
        const int q = tid >> 3, d0 = (tid & 7) * 8;
        float4 v0 = *(const float4*)(Qg + q*DHEAD + d0);
        float4 v1 = *(const float4*)(Qg + q*DHEAD + d0 + 4);
        Qs[q][d0+0]=v0.x; Qs[q][d0+1]=v0.y; Qs[q][d0+2]=v0.z; Qs[q][d0+3]=v0.w;
        Qs[q][d0+4]=v1.x; Qs[q][d0+5]=v1.y; Qs[q][d0+6]=v1.z; Qs[q][d0+7]=v1.w;
    }

    const float* Kg = Kb + (size_t)bh * SEQ * DHEAD;
    const float* Vg = Vb + (size_t)bh * SEQ * DHEAD;

    float o[2][4]  = {{0,0,0,0},{0,0,0,0}};
    float mreg[2]  = {-1e30f, -1e30f};
    float lreg[2]  = {0.f, 0.f};

    for (int j0 = 0; j0 < SEQ; j0 += 64) {
        __syncthreads();   // prior PV reads of Ks/Vs/Ps complete
        {   // stage K,V chunk (64x64 each), coalesced
            const int r = tid >> 2, d0 = (tid & 3) * 4;
            #pragma unroll
            for (int t = 0; t < 4; ++t) {
                const int c = d0 + t*16;
                float4 kv = *(const float4*)(Kg + (size_t)(j0 + r)*DHEAD + c);
                Ks[r][c+0]=kv.x; Ks[r][c+1]=kv.y; Ks[r][c+2]=kv.z; Ks[r][c+3]=kv.w;
                *(float4*)&Vs[r][c] = *(const float4*)(Vg + (size_t)(j0 + r)*DHEAD + c);
            }
        }
        __syncthreads();

        // scores: rows {qp, qp+16} x keys j0 + g*4 .. +4
        float s[2][4] = {{0,0,0,0},{0,0,0,0}};
        #pragma unroll 8
        for (int d = 0; d < DHEAD; ++d) {
            const float qv0 = Qs[qp][d], qv1 = Qs[qp+16][d];
            #pragma unroll
            for (int jj = 0; jj < 4; ++jj) {
                const float kv = Ks[g*4+jj][d];
                s[0][jj] = fmaf(qv0, kv, s[0][jj]);
                s[1][jj] = fmaf(qv1, kv, s[1][jj]);
            }
        }
        // mask + 1/sqrt(dh) scale
        #pragma unroll
        for (int i = 0; i < 2; ++i) {
            const int qrow = q0 + qp + i*16;
            const size_t base = mbase + (size_t)qrow * SEQ + j0 + g*4;
            #pragma unroll
            for (int jj = 0; jj < 4; ++jj) {
                bool mv;
                if      (mmode == 0) mv = m32[base + jj] != 0;
                else if (mmode == 1) mv = mfv[base + jj] != 0.f;
                else                 mv = m8 [base + jj] != 0;
                s[i][jj] = mv ? s[i][jj] * 0.125f : -1e9f;
            }
        }
        redA[qp]   [g] = fmaxf(fmaxf(s[0][0], s[0][1]), fmaxf(s[0][2], s[0][3]));
        redA[qp+16][g] = fmaxf(fmaxf(s[1][0], s[1][1]), fmaxf(s[1][2], s[1][3]));
        __syncthreads();

        float mnew[2], scale[2];
        #pragma unroll
        for (int i = 0; i < 2; ++i) {
            float cm = redA[qp+i*16][0];
            #pragma unroll
            for (int gg = 1; gg < 16; ++gg) cm = fmaxf(cm, redA[qp+i*16][gg]);
            mnew[i]  = fmaxf(mreg[i], cm);
            scale[i] = __expf(mreg[i] - mnew[i]);
            float ls = 0.f;
            #pragma unroll
            for (int jj = 0; jj < 4; ++jj) {
                const float p = __expf(s[i][jj] - mnew[i]);
                Ps[qp+i*16][g*4+jj] = p;
                ls += p;
            }
            redB[qp+i*16][g] = ls;
            #pragma unroll
            for (int dd = 0; dd < 4; ++dd) o[i][dd] *= scale[i];
        }
        __syncthreads();
        #pragma unroll
        for (int i = 0; i < 2; ++i) {
            float cs = 0.f;
            #pragma unroll
            for (int gg = 0; gg < 16; ++gg) cs += redB[qp+i*16][gg];
            lreg[i] = lreg[i]*scale[i] + cs;
            mreg[i] = mnew[i];
        }
        // PV: o[i][0..4) over d = g*4..+4
        #pragma unroll 4
        for (int j = 0; j < 64; ++j) {
            const float p0 = Ps[qp][j], p1 = Ps[qp+16][j];
            const float4 vv = *(const float4*)&Vs[j][g*4];
            o[0][0] = fmaf(p0, vv.x, o[0][0]);
            o[0][1] = fmaf(p0, vv.y, o[0][1]);
            o[0][2] = fmaf(p0, vv.z, o[0][2]);
            o[0][3] = fmaf(p0, vv.w, o[0][3]);
            o[1][0] = fmaf(p1, vv.x, o[1][0]);
            o[1][1] = fmaf(p1, vv.y, o[1][1]);
            o[1][2] = fmaf(p1, vv.z, o[1][2]);
            o[1][3] = fmaf(p1, vv.w, o[1][3]);
        }
    }

    #pragma unroll
    for (int i = 0; i < 2; ++i) {
        const int qrow = q0 + qp + i*16;
        const float inv = 1.0f / lreg[i];
        float4 r;
        r.x = o[i][0]*inv; r.y = o[i][1]*inv; r.z = o[i][2]*inv; r.w = o[i][3]*inv;
        *(float4*)(outp + ((size_t)(b*SEQ + qrow))*DMODEL + h*DHEAD + g*4) = r;
    }
}

// ---------------------------------------------------------------------------
// out[r] = LayerNorm(X[r] + A[r]) * g + b   over DMODEL=512, one block per row
// ---------------------------------------------------------------------------
__global__ __launch_bounds__(256) void add_ln_k(
    const float* __restrict__ X, const float* __restrict__ Aa,
    const float* __restrict__ gg, const float* __restrict__ bb,
    float* __restrict__ out)
{
    const int r = blockIdx.x;
    const int t = threadIdx.x;
    const float2 x2 = ((const float2*)(X  + (size_t)r * DMODEL))[t];
    const float2 a2 = ((const float2*)(Aa + (size_t)r * DMODEL))[t];
    const float v0 = x2.x + a2.x, v1 = x2.y + a2.y;
    float s  = v0 + v1;
    float ss = v0*v0 + v1*v1;
    #pragma unroll
    for (int off = 32; off > 0; off >>= 1) {
        s  += __shfl_down(s,  off);
        ss += __shfl_down(ss, off);
    }
    __shared__ float ps[4], pss[4];
    const int wid = t >> 6;
    if ((t & 63) == 0) { ps[wid] = s; pss[wid] = ss; }
    __syncthreads();
    const float tot  = ps[0] + ps[1] + ps[2] + ps[3];
    const float tots = pss[0] + pss[1] + pss[2] + pss[3];
    const float mean = tot * (1.0f / DMODEL);
    const float var  = tots * (1.0f / DMODEL) - mean * mean;
    const float rstd = rsqrtf(var + 1e-5f);
    const float2 g2 = ((const float2*)gg)[t];
    const float2 b2 = ((const float2*)bb)[t];
    float2 r2;
    r2.x = (v0 - mean) * rstd * g2.x + b2.x;
    r2.y = (v1 - mean) * rstd * g2.y + b2.y;
    ((float2*)(out + (size_t)r * DMODEL))[t] = r2;
}

// ---------------------------------------------------------------------------
extern "C" void kernel_launch(void* const* d_in, const int* in_sizes, int n_in,
                              void* d_out, int out_size, void* d_ws, size_t ws_size,
                              hipStream_t stream)
{
    const float* x      = (const float*)d_in[0];
    const void*  mask   = d_in[1];
    const float* W_qkv  = (const float*)d_in[2];
    const float* b_qkv  = (const float*)d_in[3];
    const float* W_proj = (const float*)d_in[4];
    const float* b_proj = (const float*)d_in[5];
    const float* ln1_g  = (const float*)d_in[6];
    const float* ln1_b  = (const float*)d_in[7];
    const float* W1     = (const float*)d_in[8];
    const float* b1     = (const float*)d_in[9];
    const float* W2     = (const float*)d_in[10];
    const float* b2     = (const float*)d_in[11];
    const float* ln2_g  = (const float*)d_in[12];
    const float* ln2_b  = (const float*)d_in[13];

    float* ws = (float*)d_ws;
    // workspace layout (floats); h reuses Q/K/V/attn, m reuses proj-out.
    float* Q    = ws;             // [B,H,N,64]
    float* K    = ws + SZ;
    float* V    = ws + 2*SZ;
    float* attn = ws + 3*SZ;      // [4096,512]
    float* ap   = ws + 4*SZ;      // proj out
    float* x1   = ws + 5*SZ;      // post-LN1
    float* hbuf = ws;             // [4096,2048] (over Q..attn, dead by then)
    float* mbuf = ws + 4*SZ;      // MLP out (over ap, dead by then)
    int*   flag = (int*)(ws + 6*SZ);

    float* out = (float*)d_out;

    detect_mask_k<<<1, 256, 0, stream>>>((const unsigned*)mask, flag, 65536);

    // QKV: [4096,512] @ [512,1536] -> scatter Q/K/V
    gemm_k<2><<<dim3(12, 32), 256, 0, stream>>>(x, W_qkv, b_qkv, nullptr, Q, K, V,
                                                ROWS, DMODEL, 3*DMODEL);
    // attention -> attn [4096,512]
    attn_k<<<BATCH*NH*(SEQ/32), 256, 0, stream>>>(Q, K, V, mask, flag, attn);
    // proj: [4096,512] @ [512,512]
    gemm_k<0><<<dim3(4, 32), 256, 0, stream>>>(attn, W_proj, b_proj, ap,
                                               nullptr, nullptr, nullptr,
                                               ROWS, DMODEL, DMODEL);
    // x1 = LN(x + ap)
    add_ln_k<<<ROWS, 256, 0, stream>>>(x, ap, ln1_g, ln1_b, x1);
    // MLP1: relu([4096,512] @ [512,2048])
    gemm_k<1><<<dim3(16, 32), 256, 0, stream>>>(x1, W1, b1, hbuf,
                                                nullptr, nullptr, nullptr,
                                                ROWS, DMODEL, 2048);
    // MLP2: relu([4096,2048] @ [2048,512])
    gemm_k<1><<<dim3(4, 32), 256, 0, stream>>>(hbuf, W2, b2, mbuf,
                                               nullptr, nullptr, nullptr,
                                               ROWS, 2048, DMODEL);
    // out = LN(x1 + mbuf)
    add_ln_k<<<ROWS, 256, 0, stream>>>(x1, mbuf, ln2_g, ln2_b, out);
}

// Round 2
// 716.085 us; speedup vs baseline: 1.5875x; 1.5875x over previous
//
#include <hip/hip_runtime.h>
#include <math.h>

// Problem constants
constexpr int BATCH  = 2;
constexpr int SEQ    = 2048;
constexpr int DMODEL = 512;
constexpr int NH     = 8;
constexpr int DHEAD  = 64;
constexpr int ROWS   = BATCH * SEQ;           // 4096
constexpr size_t SZ  = (size_t)ROWS * DMODEL; // elems of one [4096][512] buffer

typedef __attribute__((ext_vector_type(8))) short bf16x8;
typedef __attribute__((ext_vector_type(4))) float f32x4;

__device__ __forceinline__ ushort f2bf(float f) {
    unsigned u = __float_as_uint(f);
    unsigned r = (u + 0x7FFFu + ((u >> 16) & 1u)) >> 16;
    return (ushort)r;
}

// ---------------------------------------------------------------------------
// Mask-encoding detector (bool mask may arrive as int32 / float32 / bytes).
// ---------------------------------------------------------------------------
__global__ void detect_mask_k(const unsigned* __restrict__ m, int* __restrict__ flag, int n)
{
    __shared__ int sh[2];
    if (threadIdx.x == 0) { sh[0] = 0; sh[1] = 0; }
    __syncthreads();
    unsigned b0 = 0, b1 = 0;
    for (int i = threadIdx.x; i < n; i += 256) {
        unsigned v = m[i];
        b0 |= (v > 1u) ? 1u : 0u;
        b1 |= (v != 0u && v != 0x3F800000u) ? 1u : 0u;
    }
    if (b0) atomicOr(&sh[0], 1);
    if (b1) atomicOr(&sh[1], 1);
    __syncthreads();
    if (threadIdx.x == 0) *flag = sh[0] | (sh[1] << 1);
}

// ---------------------------------------------------------------------------
// Compact mask -> bitmask: bits[w] bit i = mask[w*64 + i] != 0.
// One wave per word via __ballot. nwords = B*N*(N/64).
// ---------------------------------------------------------------------------
__global__ __launch_bounds__(256) void mask_prep_k(
    const void* __restrict__ maskp, const int* __restrict__ flagp,
    unsigned long long* __restrict__ bits, int nwords)
{
    const int w = blockIdx.x * 4 + (threadIdx.x >> 6);
    if (w >= nwords) return;
    const int lane = threadIdx.x & 63;
    const size_t idx = ((size_t)w << 6) + lane;
    const int f = *flagp;
    bool mv;
    if (!(f & 1))      mv = ((const int*)maskp)[idx] != 0;
    else if (!(f & 2)) mv = ((const float*)maskp)[idx] != 0.f;
    else               mv = ((const unsigned char*)maskp)[idx] != 0;
    unsigned long long bal = __ballot(mv);
    if (lane == 0) bits[w] = bal;
}

// ---------------------------------------------------------------------------
// Tiled fp32 GEMM: C[M,Nd] = A[M,Kd] @ W[Kd,Nd] + bias, 128x128 tile, BK=8.
// EPI: 0 = plain+bias, 1 = relu+bias, 2 = QKV scatter (bf16) to [B,H,N,64]
// ---------------------------------------------------------------------------
template<int EPI>
__global__ __launch_bounds__(256) void gemm_k(
    const float* __restrict__ A, const float* __restrict__ W,
    const float* __restrict__ bias, float* __restrict__ C,
    ushort* __restrict__ Qo, ushort* __restrict__ Ko, ushort* __restrict__ Vo,
    int M, int Kd, int Nd)
{
    __shared__ float As[8][128];   // As[k][m]
    __shared__ float Ws[8][128];   // Ws[k][n]
    const int tid = threadIdx.x;
    const int tx = tid & 15, ty = tid >> 4;
    const int bm = blockIdx.y * 128, bn = blockIdx.x * 128;
    const int am = tid >> 1,  ak = (tid & 1) * 4;
    const int wk = tid >> 5,  wn = (tid & 31) * 4;
    const float* Aptr = A + (size_t)(bm + am) * Kd + ak;
    const float* Wptr = W + (size_t)wk * Nd + bn + wn;

    float acc[8][8] = {};

    for (int k0 = 0; k0 < Kd; k0 += 8) {
        float4 av = *(const float4*)(Aptr + k0);
        float4 wv = *(const float4*)(Wptr + (size_t)k0 * Nd);
        __syncthreads();
        As[ak+0][am] = av.x; As[ak+1][am] = av.y;
        As[ak+2][am] = av.z; As[ak+3][am] = av.w;
        *(float4*)&Ws[wk][wn] = wv;
        __syncthreads();
        #pragma unroll
        for (int kk = 0; kk < 8; ++kk) {
            float a[8], w[8];
            *(float4*)(a)     = *(const float4*)&As[kk][ty*8];
            *(float4*)(a + 4) = *(const float4*)&As[kk][ty*8 + 4];
            *(float4*)(w)     = *(const float4*)&Ws[kk][tx*8];
            *(float4*)(w + 4) = *(const float4*)&Ws[kk][tx*8 + 4];
            #pragma unroll
            for (int i = 0; i < 8; ++i)
                #pragma unroll
                for (int j = 0; j < 8; ++j)
                    acc[i][j] = fmaf(a[i], w[j], acc[i][j]);
        }
    }

    #pragma unroll
    for (int i = 0; i < 8; ++i) {
        const int mrow = bm + ty*8 + i;
        #pragma unroll
        for (int jh = 0; jh < 2; ++jh) {
            const int c0 = bn + tx*8 + jh*4;
            const float4 bi = *(const float4*)(bias + c0);
            float4 r;
            r.x = acc[i][jh*4+0] + bi.x;
            r.y = acc[i][jh*4+1] + bi.y;
            r.z = acc[i][jh*4+2] + bi.z;
            r.w = acc[i][jh*4+3] + bi.w;
            if (EPI == 1) {
                r.x = fmaxf(r.x, 0.f); r.y = fmaxf(r.y, 0.f);
                r.z = fmaxf(r.z, 0.f); r.w = fmaxf(r.w, 0.f);
            }
            if (EPI == 2) {
                const int part = c0 >> 9, hc = c0 & 511, hh = hc >> 6, d0 = hc & 63;
                const int bidx = mrow >> 11, nrow = mrow & 2047;
                ushort* dst = (part == 0) ? Qo : (part == 1) ? Ko : Vo;
                ushort4 sv;
                sv.x = f2bf(r.x); sv.y = f2bf(r.y);
                sv.z = f2bf(r.z); sv.w = f2bf(r.w);
                *(ushort4*)(dst + ((((size_t)bidx*NH + hh)*SEQ + nrow) << 6) + d0) = sv;
            } else {
                *(float4*)(C + (size_t)mrow * Nd + c0) = r;
            }
        }
    }
}

// ---------------------------------------------------------------------------
// bf16 MFMA flash attention.
// Grid: B*H*(N/64) = 512 blocks, 256 threads (4 waves). Wave owns 16 q rows.
// KV chunk = 64 keys. Swapped QK^T (S^T = mfma(K, Q)) so each lane's scores
// share one q; softmax reduce = in-lane + shfl_xor(16,32).
// MFMA 16x16x32 bf16 layouts (m89/m91-verified):
//   A-frag: row = lane&15, k = (lane>>4)*8 + j   (8 contiguous bf16)
//   B-frag: col = lane&15, k = (lane>>4)*8 + j
//   C/D   : col = lane&15, row = (lane>>4)*4 + reg
// LDS rows padded to 72 shorts (144B) -> b128 frag reads are 2-way (free).
// ---------------------------------------------------------------------------
__global__ __launch_bounds__(256) void attn_mfma_k(
    const ushort* __restrict__ Qb, const ushort* __restrict__ Kb,
    const ushort* __restrict__ Vb, const unsigned long long* __restrict__ mbits,
    float* __restrict__ outp)
{
    __shared__ ushort Klds[64][72];      // [key][d]
    __shared__ ushort Vt[64][72];        // [d][key]  (transposed V)
    __shared__ ushort Plds[4][16][72];   // per-wave [q][key]

    const int tid  = threadIdx.x;
    const int wid  = tid >> 6;
    const int lane = tid & 63;
    const int lq   = lane & 15;          // frag row/col index
    const int lg   = lane >> 4;          // 16-lane group 0..3

    const int tile = blockIdx.x & 31;    // 2048/64 q-tiles
    const int bh   = blockIdx.x >> 5;    // 0..15
    const int b    = bh >> 3, h = bh & 7;
    const int q0   = tile * 64;
    const int qw   = q0 + wid * 16;      // wave's q base

    // hoisted Q fragments (B-operand): Q[qw+lq][d], two d-halves
    const ushort* Qg = Qb + ((size_t)bh * SEQ + qw + lq) * DHEAD;
    const bf16x8 qf0 = *(const bf16x8*)(Qg + lg * 8);
    const bf16x8 qf1 = *(const bf16x8*)(Qg + 32 + lg * 8);

    // staging: thread -> (row = tid>>2, d-quarter = (tid&3)*16), coalesced
    const int srow = tid >> 2;
    const int sdq  = (tid & 3) * 16;
    const ushort* Kg = Kb + (size_t)bh * SEQ * DHEAD;
    const ushort* Vg = Vb + (size_t)bh * SEQ * DHEAD;

    const unsigned long long* mrow = mbits + ((size_t)b * SEQ + qw + lq) * (SEQ / 64);

    f32x4 o[4] = {};
    float mrun = -1e30f, lrun = 0.f;

    for (int c = 0; c < SEQ / 64; ++c) {
        const size_t gbase = (size_t)(c * 64 + srow) * DHEAD + sdq;
        __syncthreads();   // all waves done reading previous K/Vt
        {
            bf16x8 k0 = *(const bf16x8*)(Kg + gbase);
            bf16x8 k1 = *(const bf16x8*)(Kg + gbase + 8);
            bf16x8 v0 = *(const bf16x8*)(Vg + gbase);
            bf16x8 v1 = *(const bf16x8*)(Vg + gbase + 8);
            *(bf16x8*)&Klds[srow][sdq]     = k0;
            *(bf16x8*)&Klds[srow][sdq + 8] = k1;
            #pragma unroll
            for (int i = 0; i < 8; ++i) {
                Vt[sdq + i][srow]     = (ushort)v0[i];
                Vt[sdq + 8 + i][srow] = (ushort)v1[i];
            }
        }
        __syncthreads();

        const unsigned long long mw = mrow[c];

        // S^T tiles: 4 x (16 keys x 16 q), accumulate over d = 0..63
        f32x4 st[4];
        #pragma unroll
        for (int kt = 0; kt < 4; ++kt) {
            bf16x8 kf0 = *(const bf16x8*)&Klds[kt*16 + lq][lg*8];
            bf16x8 kf1 = *(const bf16x8*)&Klds[kt*16 + lq][32 + lg*8];
            f32x4 a = {};
            a = __builtin_amdgcn_mfma_f32_16x16x32_bf16(kf0, qf0, a, 0, 0, 0);
            a = __builtin_amdgcn_mfma_f32_16x16x32_bf16(kf1, qf1, a, 0, 0, 0);
            st[kt] = a;
        }

        // mask + scale; lane holds 16 scores for q = lq, keys kt*16 + lg*4 + r
        float sv[16];
        float cmax = -1e30f;
        #pragma unroll
        for (int kt = 0; kt < 4; ++kt)
            #pragma unroll
            for (int r = 0; r < 4; ++r) {
                const int bitpos = kt*16 + lg*4 + r;
                const float s = ((mw >> bitpos) & 1ull) ? st[kt][r] * 0.125f : -1e9f;
                sv[kt*4 + r] = s;
                cmax = fmaxf(cmax, s);
            }
        cmax = fmaxf(cmax, __shfl_xor(cmax, 16));
        cmax = fmaxf(cmax, __shfl_xor(cmax, 32));

        const float mnew  = fmaxf(mrun, cmax);
        const float scale = __expf(mrun - mnew);
        float lsum = 0.f;
        #pragma unroll
        for (int kt = 0; kt < 4; ++kt) {
            ushort4 pv;
            float p0 = __expf(sv[kt*4+0] - mnew);
            float p1 = __expf(sv[kt*4+1] - mnew);
            float p2 = __expf(sv[kt*4+2] - mnew);
            float p3 = __expf(sv[kt*4+3] - mnew);
            lsum += (p0 + p1) + (p2 + p3);
            pv.x = f2bf(p0); pv.y = f2bf(p1); pv.z = f2bf(p2); pv.w = f2bf(p3);
            *(ushort4*)&Plds[wid][lq][kt*16 + lg*4] = pv;
        }
        lsum += __shfl_xor(lsum, 16);
        lsum += __shfl_xor(lsum, 32);
        lrun = lrun * scale + lsum;
        mrun = mnew;

        // rescale O: factor for row q' = lg*4+r lives in lane q'
        float sc[4];
        #pragma unroll
        for (int r = 0; r < 4; ++r) sc[r] = __shfl(scale, lg*4 + r);
        #pragma unroll
        for (int nt = 0; nt < 4; ++nt)
            #pragma unroll
            for (int r = 0; r < 4; ++r) o[nt][r] *= sc[r];

        // PV: O[q][d] += P[q][key] * V[key][d]
        #pragma unroll
        for (int kk = 0; kk < 2; ++kk) {
            bf16x8 pf = *(const bf16x8*)&Plds[wid][lq][kk*32 + lg*8];
            #pragma unroll
            for (int nt = 0; nt < 4; ++nt) {
                bf16x8 vf = *(const bf16x8*)&Vt[nt*16 + lq][kk*32 + lg*8];
                o[nt] = __builtin_amdgcn_mfma_f32_16x16x32_bf16(pf, vf, o[nt], 0, 0, 0);
            }
        }
    }

    // epilogue: O rows q' = lg*4+r, cols d = nt*16 + lq
    float linv[4];
    #pragma unroll
    for (int r = 0; r < 4; ++r) linv[r] = 1.0f / __shfl(lrun, lg*4 + r);
    #pragma unroll
    for (int nt = 0; nt < 4; ++nt)
        #pragma unroll
        for (int r = 0; r < 4; ++r) {
            const size_t row = (size_t)b * SEQ + qw + lg*4 + r;
            outp[row * DMODEL + h*DHEAD + nt*16 + lq] = o[nt][r] * linv[r];
        }
}

// ---------------------------------------------------------------------------
// out[r] = LayerNorm(X[r] + A[r]) * g + b   over DMODEL=512, one block per row
// ---------------------------------------------------------------------------
__global__ __launch_bounds__(256) void add_ln_k(
    const float* __restrict__ X, const float* __restrict__ Aa,
    const float* __restrict__ gg, const float* __restrict__ bb,
    float* __restrict__ out)
{
    const int r = blockIdx.x;
    const int t = threadIdx.x;
    const float2 x2 = ((const float2*)(X  + (size_t)r * DMODEL))[t];
    const float2 a2 = ((const float2*)(Aa + (size_t)r * DMODEL))[t];
    const float v0 = x2.x + a2.x, v1 = x2.y + a2.y;
    float s  = v0 + v1;
    float ss = v0*v0 + v1*v1;
    #pragma unroll
    for (int off = 32; off > 0; off >>= 1) {
        s  += __shfl_down(s,  off);
        ss += __shfl_down(ss, off);
    }
    __shared__ float ps[4], pss[4];
    const int wid = t >> 6;
    if ((t & 63) == 0) { ps[wid] = s; pss[wid] = ss; }
    __syncthreads();
    const float tot  = ps[0] + ps[1] + ps[2] + ps[3];
    const float tots = pss[0] + pss[1] + pss[2] + pss[3];
    const float mean = tot * (1.0f / DMODEL);
    const float var  = tots * (1.0f / DMODEL) - mean * mean;
    const float rstd = rsqrtf(var + 1e-5f);
    const float2 g2 = ((const float2*)gg)[t];
    const float2 b2 = ((const float2*)bb)[t];
    float2 r2;
    r2.x = (v0 - mean) * rstd * g2.x + b2.x;
    r2.y = (v1 - mean) * rstd * g2.y + b2.y;
    ((float2*)(out + (size_t)r * DMODEL))[t] = r2;
}

// ---------------------------------------------------------------------------
extern "C" void kernel_launch(void* const* d_in, const int* in_sizes, int n_in,
                              void* d_out, int out_size, void* d_ws, size_t ws_size,
                              hipStream_t stream)
{
    const float* x      = (const float*)d_in[0];
    const void*  mask   = d_in[1];
    const float* W_qkv  = (const float*)d_in[2];
    const float* b_qkv  = (const float*)d_in[3];
    const float* W_proj = (const float*)d_in[4];
    const float* b_proj = (const float*)d_in[5];
    const float* ln1_g  = (const float*)d_in[6];
    const float* ln1_b  = (const float*)d_in[7];
    const float* W1     = (const float*)d_in[8];
    const float* b1     = (const float*)d_in[9];
    const float* W2     = (const float*)d_in[10];
    const float* b2     = (const float*)d_in[11];
    const float* ln2_g  = (const float*)d_in[12];
    const float* ln2_b  = (const float*)d_in[13];

    float* ws = (float*)d_ws;
    // Workspace layout (float-element offsets; SZ = 2,097,152):
    //   [0,      0.5SZ) Qb (bf16, SZ elems)     -- dead after attn
    //   [0.5SZ,  1.0SZ) Kb (bf16)               -- dead after attn
    //   [1.0SZ,  1.5SZ) Vb (bf16)               -- dead after attn
    //   [1.5SZ,  2.5SZ) attn f32                -- dead after proj
    //   [2.5SZ,  3.5SZ) ap f32                  -- dead after LN1
    //   [3.5SZ,  3.625SZ) mask bitmask (1 MB)   -- dead after attn
    //   [3.625SZ, +1) flag                      -- dead after mask_prep
    //   [0,      4SZ)   hbuf f32 (overlays all of the above, MLP phase)
    //   [4SZ,    5SZ)   x1 f32
    //   [5SZ,    6SZ)   mbuf f32
    ushort* Qb = (ushort*)ws;
    ushort* Kb = (ushort*)(ws + SZ/2);
    ushort* Vb = (ushort*)(ws + SZ);
    float* attn = ws + SZ + SZ/2;
    float* ap   = ws + 2*SZ + SZ/2;
    unsigned long long* bits = (unsigned long long*)(ws + 3*SZ + SZ/2);
    int*   flag = (int*)(ws + 3*SZ + SZ/2 + 262144);
    float* hbuf = ws;
    float* x1   = ws + 4*SZ;
    float* mbuf = ws + 5*SZ;

    float* out = (float*)d_out;

    const int nwords = BATCH * SEQ * (SEQ / 64);   // 131072

    detect_mask_k<<<1, 256, 0, stream>>>((const unsigned*)mask, flag, 65536);
    mask_prep_k<<<nwords / 4, 256, 0, stream>>>(mask, flag, bits, nwords);

    // QKV: [4096,512] @ [512,1536] -> scatter bf16 Q/K/V [B,H,N,64]
    gemm_k<2><<<dim3(12, 32), 256, 0, stream>>>(x, W_qkv, b_qkv, nullptr, Qb, Kb, Vb,
                                                ROWS, DMODEL, 3*DMODEL);
    // attention -> attn [4096,512] f32
    attn_mfma_k<<<BATCH*NH*(SEQ/64), 256, 0, stream>>>(Qb, Kb, Vb, bits, attn);
    // proj: [4096,512] @ [512,512]
    gemm_k<0><<<dim3(4, 32), 256, 0, stream>>>(attn, W_proj, b_proj, ap,
                                               nullptr, nullptr, nullptr,
                                               ROWS, DMODEL, DMODEL);
    // x1 = LN(x + ap)
    add_ln_k<<<ROWS, 256, 0, stream>>>(x, ap, ln1_g, ln1_b, x1);
    // MLP1: relu([4096,512] @ [512,2048])
    gemm_k<1><<<dim3(16, 32), 256, 0, stream>>>(x1, W1, b1, hbuf,
                                                nullptr, nullptr, nullptr,
                                                ROWS, DMODEL, 2048);
    // MLP2: relu([4096,2048] @ [2048,512])
    gemm_k<1><<<dim3(4, 32), 256, 0, stream>>>(hbuf, W2, b2, mbuf,
                                               nullptr, nullptr, nullptr,
                                               ROWS, 2048, DMODEL);
    // out = LN(x1 + mbuf)
    add_ln_k<<<ROWS, 256, 0, stream>>>(x1, mbuf, ln2_g, ln2_b, out);
}

// Round 3
// 237.168 us; speedup vs baseline: 4.7933x; 3.0193x over previous
//
#include <hip/hip_runtime.h>
#include <math.h>

// Problem constants
constexpr int BATCH  = 2;
constexpr int SEQ    = 2048;
constexpr int DMODEL = 512;
constexpr int NH     = 8;
constexpr int DHEAD  = 64;
constexpr int ROWS   = BATCH * SEQ;           // 4096
constexpr size_t SZ  = (size_t)ROWS * DMODEL; // elems of one [4096][512] buffer

typedef __attribute__((ext_vector_type(8))) short bf16x8;
typedef __attribute__((ext_vector_type(4))) float f32x4;

__device__ __forceinline__ ushort f2bf(float f) {
    unsigned u = __float_as_uint(f);
    unsigned r = (u + 0x7FFFu + ((u >> 16) & 1u)) >> 16;
    return (ushort)r;
}

__device__ __forceinline__ void gload_lds16(const void* g, void* l) {
    __builtin_amdgcn_global_load_lds(
        (const __attribute__((address_space(1))) void*)g,
        (__attribute__((address_space(3))) void*)l, 16, 0, 0);
}

// ---------------------------------------------------------------------------
// Mask-encoding detector (bool mask may arrive as int32 / float32 / bytes).
// ---------------------------------------------------------------------------
__global__ void detect_mask_k(const unsigned* __restrict__ m, int* __restrict__ flag, int n)
{
    __shared__ int sh[2];
    if (threadIdx.x == 0) { sh[0] = 0; sh[1] = 0; }
    __syncthreads();
    unsigned b0 = 0, b1 = 0;
    for (int i = threadIdx.x; i < n; i += 256) {
        unsigned v = m[i];
        b0 |= (v > 1u) ? 1u : 0u;
        b1 |= (v != 0u && v != 0x3F800000u) ? 1u : 0u;
    }
    if (b0) atomicOr(&sh[0], 1);
    if (b1) atomicOr(&sh[1], 1);
    __syncthreads();
    if (threadIdx.x == 0) *flag = sh[0] | (sh[1] << 1);
}

// ---------------------------------------------------------------------------
// Compact mask -> bitmask: bits[w] bit i = mask[w*64 + i] != 0.
// ---------------------------------------------------------------------------
__global__ __launch_bounds__(256) void mask_prep_k(
    const void* __restrict__ maskp, const int* __restrict__ flagp,
    unsigned long long* __restrict__ bits, int nwords)
{
    const int w = blockIdx.x * 4 + (threadIdx.x >> 6);
    if (w >= nwords) return;
    const int lane = threadIdx.x & 63;
    const size_t idx = ((size_t)w << 6) + lane;
    const int f = *flagp;
    bool mv;
    if (!(f & 1))      mv = ((const int*)maskp)[idx] != 0;
    else if (!(f & 2)) mv = ((const float*)maskp)[idx] != 0.f;
    else               mv = ((const unsigned char*)maskp)[idx] != 0;
    unsigned long long bal = __ballot(mv);
    if (lane == 0) bits[w] = bal;
}

// ---------------------------------------------------------------------------
// f32 -> bf16 elementwise convert (x for QKV input). n multiple of 1024.
// ---------------------------------------------------------------------------
__global__ __launch_bounds__(256) void conv_bf16_k(
    const float* __restrict__ in, ushort* __restrict__ out)
{
    const size_t i = ((size_t)blockIdx.x * 256 + threadIdx.x) * 4;
    float4 v = *(const float4*)(in + i);
    ushort4 o;
    o.x = f2bf(v.x); o.y = f2bf(v.y); o.z = f2bf(v.z); o.w = f2bf(v.w);
    *(ushort4*)(out + i) = o;
}

// ---------------------------------------------------------------------------
// Weight prep: W[K][N] f32 -> Wt[N][K] bf16 (transpose + convert), 64x64 tiles.
// grid = (N/64, K/64)
// ---------------------------------------------------------------------------
__global__ __launch_bounds__(256) void wprep_k(
    const float* __restrict__ W, ushort* __restrict__ Wt, int K, int N)
{
    __shared__ ushort T[64][65];   // T[n][k]
    const int t = threadIdx.x;
    const int k0 = blockIdx.y * 64, n0 = blockIdx.x * 64;
    const int r = t >> 4, c4 = (t & 15) * 4;
    #pragma unroll
    for (int it = 0; it < 4; ++it) {
        const int row = it*16 + r;    // k within tile
        float4 v = *(const float4*)&W[(size_t)(k0 + row) * N + n0 + c4];
        T[c4+0][row] = f2bf(v.x);
        T[c4+1][row] = f2bf(v.y);
        T[c4+2][row] = f2bf(v.z);
        T[c4+3][row] = f2bf(v.w);
    }
    __syncthreads();
    #pragma unroll
    for (int it = 0; it < 4; ++it) {
        const int row = it*16 + r;    // n within tile
        ushort4 o;
        o.x = T[row][c4+0]; o.y = T[row][c4+1];
        o.z = T[row][c4+2]; o.w = T[row][c4+3];
        *(ushort4*)&Wt[(size_t)(n0 + row) * K + k0 + c4] = o;
    }
}

// ---------------------------------------------------------------------------
// bf16 MFMA GEMM, m97 structure: C[M,N] = A[M,K] @ Wt[N,K]^T + bias.
// 128x128 tile, BK=64, 256 threads = 4 waves (2x2), 64x64 per wave.
// Staging: global_load_lds width=16, linear LDS dest + inverse-swizzled
// per-lane global source; ds_read uses the same XOR swizzle (chunk ^= row&7).
// EPI: 0 = bias -> f32 (proj) | 1 = relu(bias) -> bf16 (MLP1)
//      2 = relu(bias) -> f32 (MLP2) | 3 = bias -> bf16 QKV scatter
// ---------------------------------------------------------------------------
template<int EPI>
__global__ __launch_bounds__(256) void mgemm_k(
    const ushort* __restrict__ A,   // [M][K] bf16
    const ushort* __restrict__ Wt,  // [N][K] bf16
    const float* __restrict__ bias, // [N] f32
    float* __restrict__ Cf, ushort* __restrict__ Cb,
    ushort* __restrict__ Qo, ushort* __restrict__ Ko, ushort* __restrict__ Vo,
    int M, int N, int K)
{
    __shared__ ushort As[128 * 64];   // 16 KB, swizzled rows of 64 bf16
    __shared__ ushort Bs[128 * 64];

    const int tid  = threadIdx.x;
    const int wid  = tid >> 6, lane = tid & 63;
    const int lq   = lane & 15, lg = lane >> 4;
    const int wr   = wid >> 1,  wc = wid & 1;
    const int bm   = blockIdx.y * 128, bn = blockIdx.x * 128;

    // staging decomposition: 16 segments of 1KB per tile; wave w owns 4.
    const int srow0 = (lane >> 3);       // +seg*8
    const int sch   = lane & 7;          // stored chunk (16B units)

    f32x4 acc[4][4] = {};

    for (int k0 = 0; k0 < K; k0 += 64) {
        __syncthreads();   // prior iteration's ds_reads complete
        #pragma unroll
        for (int i = 0; i < 4; ++i) {
            const int seg = wid * 4 + i;
            const int row = seg * 8 + srow0;
            const int c16 = sch ^ (row & 7);   // logical col16 stored at chunk sch
            gload_lds16(A  + (size_t)(bm + row) * K + k0 + c16 * 8, As + seg * 512);
            gload_lds16(Wt + (size_t)(bn + row) * K + k0 + c16 * 8, Bs + seg * 512);
        }
        __syncthreads();   // barrier drains vmcnt -> tiles ready

        #pragma unroll
        for (int ks = 0; ks < 2; ++ks) {
            bf16x8 af[4], bfr[4];
            #pragma unroll
            for (int m = 0; m < 4; ++m) {
                const int row = wr*64 + m*16 + lq;
                const int c16 = (ks*4 + lg) ^ (row & 7);
                af[m] = *(const bf16x8*)&As[row * 64 + c16 * 8];
            }
            #pragma unroll
            for (int n = 0; n < 4; ++n) {
                const int row = wc*64 + n*16 + lq;
                const int c16 = (ks*4 + lg) ^ (row & 7);
                bfr[n] = *(const bf16x8*)&Bs[row * 64 + c16 * 8];
            }
            #pragma unroll
            for (int m = 0; m < 4; ++m)
                #pragma unroll
                for (int n = 0; n < 4; ++n)
                    acc[m][n] = __builtin_amdgcn_mfma_f32_16x16x32_bf16(
                        af[m], bfr[n], acc[m][n], 0, 0, 0);
        }
    }

    // epilogue: C row = bm + wr*64 + m*16 + lg*4 + r ; col = bn + wc*64 + n*16 + lq
    #pragma unroll
    for (int n = 0; n < 4; ++n) {
        const int col = bn + wc*64 + n*16 + lq;
        const float bv = bias[col];
        #pragma unroll
        for (int m = 0; m < 4; ++m) {
            #pragma unroll
            for (int r = 0; r < 4; ++r) {
                const int row = bm + wr*64 + m*16 + lg*4 + r;
                float v = acc[m][n][r] + bv;
                if (EPI == 1 || EPI == 2) v = fmaxf(v, 0.f);
                if (EPI == 0) {
                    Cf[(size_t)row * N + col] = v;
                } else if (EPI == 1) {
                    Cb[(size_t)row * N + col] = f2bf(v);
                } else if (EPI == 2) {
                    Cf[(size_t)row * N + col] = v;
                } else {
                    const int part = col >> 9, hc = col & 511;
                    const int hh = hc >> 6, d0 = hc & 63;
                    const int bidx = row >> 11, nrow = row & 2047;
                    ushort* dst = (part == 0) ? Qo : (part == 1) ? Ko : Vo;
                    dst[((((size_t)bidx*NH + hh)*SEQ + nrow) << 6) + d0] = f2bf(v);
                }
            }
        }
    }
}

// ---------------------------------------------------------------------------
// bf16 MFMA flash attention (round-1 kernel, bf16 output for proj input).
// ---------------------------------------------------------------------------
__global__ __launch_bounds__(256) void attn_mfma_k(
    const ushort* __restrict__ Qb, const ushort* __restrict__ Kb,
    const ushort* __restrict__ Vb, const unsigned long long* __restrict__ mbits,
    ushort* __restrict__ outp)
{
    __shared__ ushort Klds[64][72];
    __shared__ ushort Vt[64][72];
    __shared__ ushort Plds[4][16][72];

    const int tid  = threadIdx.x;
    const int wid  = tid >> 6;
    const int lane = tid & 63;
    const int lq   = lane & 15;
    const int lg   = lane >> 4;

    const int tile = blockIdx.x & 31;
    const int bh   = blockIdx.x >> 5;
    const int b    = bh >> 3, h = bh & 7;
    const int q0   = tile * 64;
    const int qw   = q0 + wid * 16;

    const ushort* Qg = Qb + ((size_t)bh * SEQ + qw + lq) * DHEAD;
    const bf16x8 qf0 = *(const bf16x8*)(Qg + lg * 8);
    const bf16x8 qf1 = *(const bf16x8*)(Qg + 32 + lg * 8);

    const int srow = tid >> 2;
    const int sdq  = (tid & 3) * 16;
    const ushort* Kg = Kb + (size_t)bh * SEQ * DHEAD;
    const ushort* Vg = Vb + (size_t)bh * SEQ * DHEAD;

    const unsigned long long* mrow = mbits + ((size_t)b * SEQ + qw + lq) * (SEQ / 64);

    f32x4 o[4] = {};
    float mrun = -1e30f, lrun = 0.f;

    for (int c = 0; c < SEQ / 64; ++c) {
        const size_t gbase = (size_t)(c * 64 + srow) * DHEAD + sdq;
        __syncthreads();
        {
            bf16x8 k0 = *(const bf16x8*)(Kg + gbase);
            bf16x8 k1 = *(const bf16x8*)(Kg + gbase + 8);
            bf16x8 v0 = *(const bf16x8*)(Vg + gbase);
            bf16x8 v1 = *(const bf16x8*)(Vg + gbase + 8);
            *(bf16x8*)&Klds[srow][sdq]     = k0;
            *(bf16x8*)&Klds[srow][sdq + 8] = k1;
            #pragma unroll
            for (int i = 0; i < 8; ++i) {
                Vt[sdq + i][srow]     = (ushort)v0[i];
                Vt[sdq + 8 + i][srow] = (ushort)v1[i];
            }
        }
        __syncthreads();

        const unsigned long long mw = mrow[c];

        f32x4 st[4];
        #pragma unroll
        for (int kt = 0; kt < 4; ++kt) {
            bf16x8 kf0 = *(const bf16x8*)&Klds[kt*16 + lq][lg*8];
            bf16x8 kf1 = *(const bf16x8*)&Klds[kt*16 + lq][32 + lg*8];
            f32x4 a = {};
            a = __builtin_amdgcn_mfma_f32_16x16x32_bf16(kf0, qf0, a, 0, 0, 0);
            a = __builtin_amdgcn_mfma_f32_16x16x32_bf16(kf1, qf1, a, 0, 0, 0);
            st[kt] = a;
        }

        float sv[16];
        float cmax = -1e30f;
        #pragma unroll
        for (int kt = 0; kt < 4; ++kt)
            #pragma unroll
            for (int r = 0; r < 4; ++r) {
                const int bitpos = kt*16 + lg*4 + r;
                const float s = ((mw >> bitpos) & 1ull) ? st[kt][r] * 0.125f : -1e9f;
                sv[kt*4 + r] = s;
                cmax = fmaxf(cmax, s);
            }
        cmax = fmaxf(cmax, __shfl_xor(cmax, 16));
        cmax = fmaxf(cmax, __shfl_xor(cmax, 32));

        const float mnew  = fmaxf(mrun, cmax);
        const float scale = __expf(mrun - mnew);
        float lsum = 0.f;
        #pragma unroll
        for (int kt = 0; kt < 4; ++kt) {
            ushort4 pv;
            float p0 = __expf(sv[kt*4+0] - mnew);
            float p1 = __expf(sv[kt*4+1] - mnew);
            float p2 = __expf(sv[kt*4+2] - mnew);
            float p3 = __expf(sv[kt*4+3] - mnew);
            lsum += (p0 + p1) + (p2 + p3);
            pv.x = f2bf(p0); pv.y = f2bf(p1); pv.z = f2bf(p2); pv.w = f2bf(p3);
            *(ushort4*)&Plds[wid][lq][kt*16 + lg*4] = pv;
        }
        lsum += __shfl_xor(lsum, 16);
        lsum += __shfl_xor(lsum, 32);
        lrun = lrun * scale + lsum;
        mrun = mnew;

        float sc[4];
        #pragma unroll
        for (int r = 0; r < 4; ++r) sc[r] = __shfl(scale, lg*4 + r);
        #pragma unroll
        for (int nt = 0; nt < 4; ++nt)
            #pragma unroll
            for (int r = 0; r < 4; ++r) o[nt][r] *= sc[r];

        #pragma unroll
        for (int kk = 0; kk < 2; ++kk) {
            bf16x8 pf = *(const bf16x8*)&Plds[wid][lq][kk*32 + lg*8];
            #pragma unroll
            for (int nt = 0; nt < 4; ++nt) {
                bf16x8 vf = *(const bf16x8*)&Vt[nt*16 + lq][kk*32 + lg*8];
                o[nt] = __builtin_amdgcn_mfma_f32_16x16x32_bf16(pf, vf, o[nt], 0, 0, 0);
            }
        }
    }

    float linv[4];
    #pragma unroll
    for (int r = 0; r < 4; ++r) linv[r] = 1.0f / __shfl(lrun, lg*4 + r);
    #pragma unroll
    for (int nt = 0; nt < 4; ++nt)
        #pragma unroll
        for (int r = 0; r < 4; ++r) {
            const size_t row = (size_t)b * SEQ + qw + lg*4 + r;
            outp[row * DMODEL + h*DHEAD + nt*16 + lq] = f2bf(o[nt][r] * linv[r]);
        }
}

// ---------------------------------------------------------------------------
// out = LayerNorm(X + A)*g + b over DMODEL=512; optional bf16 copy.
// ---------------------------------------------------------------------------
__global__ __launch_bounds__(256) void add_ln_k(
    const float* __restrict__ X, const float* __restrict__ Aa,
    const float* __restrict__ gg, const float* __restrict__ bb,
    float* __restrict__ out, ushort* __restrict__ outb)
{
    const int r = blockIdx.x;
    const int t = threadIdx.x;
    const float2 x2 = ((const float2*)(X  + (size_t)r * DMODEL))[t];
    const float2 a2 = ((const float2*)(Aa + (size_t)r * DMODEL))[t];
    const float v0 = x2.x + a2.x, v1 = x2.y + a2.y;
    float s  = v0 + v1;
    float ss = v0*v0 + v1*v1;
    #pragma unroll
    for (int off = 32; off > 0; off >>= 1) {
        s  += __shfl_down(s,  off);
        ss += __shfl_down(ss, off);
    }
    __shared__ float ps[4], pss[4];
    const int wid = t >> 6;
    if ((t & 63) == 0) { ps[wid] = s; pss[wid] = ss; }
    __syncthreads();
    const float tot  = ps[0] + ps[1] + ps[2] + ps[3];
    const float tots = pss[0] + pss[1] + pss[2] + pss[3];
    const float mean = tot * (1.0f / DMODEL);
    const float var  = tots * (1.0f / DMODEL) - mean * mean;
    const float rstd = rsqrtf(var + 1e-5f);
    const float2 g2 = ((const float2*)gg)[t];
    const float2 b2 = ((const float2*)bb)[t];
    float2 r2;
    r2.x = (v0 - mean) * rstd * g2.x + b2.x;
    r2.y = (v1 - mean) * rstd * g2.y + b2.y;
    ((float2*)(out + (size_t)r * DMODEL))[t] = r2;
    if (outb) {
        ushort2 ob; ob.x = f2bf(r2.x); ob.y = f2bf(r2.y);
        *(ushort2*)(outb + (size_t)r * DMODEL + t*2) = ob;
    }
}

// ---------------------------------------------------------------------------
extern "C" void kernel_launch(void* const* d_in, const int* in_sizes, int n_in,
                              void* d_out, int out_size, void* d_ws, size_t ws_size,
                              hipStream_t stream)
{
    const float* x      = (const float*)d_in[0];
    const void*  mask   = d_in[1];
    const float* W_qkv  = (const float*)d_in[2];
    const float* b_qkv  = (const float*)d_in[3];
    const float* W_proj = (const float*)d_in[4];
    const float* b_proj = (const float*)d_in[5];
    const float* ln1_g  = (const float*)d_in[6];
    const float* ln1_b  = (const float*)d_in[7];
    const float* W1     = (const float*)d_in[8];
    const float* b1     = (const float*)d_in[9];
    const float* W2     = (const float*)d_in[10];
    const float* b2     = (const float*)d_in[11];
    const float* ln2_g  = (const float*)d_in[12];
    const float* ln2_b  = (const float*)d_in[13];

    float* ws = (float*)d_ws;
    // Workspace (float-element offsets; SZ = 2,097,152):
    //  [0,   0.5) xb bf16          (dead after QKV)   \
    //  [0.5, 2.0) Qb,Kb,Vb bf16    (dead after attn)   } hb bf16 [0,2.0) in MLP phase
    //  [2.0, 2.5) attnb bf16       (dead after proj)  \
    //  [2.5, 3.5) ap f32           (dead after LN1)    } mbuf f32 [2.0,3.0) in MLP phase
    //  [3.5, 4.5) x1 f32
    //  [4.5, 5.0) x1b bf16
    //  [5.0, ...) WqkvT, WprojT, W1T, W2T bf16; bits; flag   (~5.875 SZ total)
    ushort* xb    = (ushort*)ws;
    ushort* Qb    = (ushort*)(ws + SZ/2);
    ushort* Kb    = (ushort*)(ws + SZ);
    ushort* Vb    = (ushort*)(ws + SZ + SZ/2);
    ushort* attnb = (ushort*)(ws + 2*SZ);
    float*  ap    = ws + 2*SZ + SZ/2;
    float*  mbuf  = ws + 2*SZ;
    float*  x1    = ws + 3*SZ + SZ/2;
    ushort* x1b   = (ushort*)(ws + 4*SZ + SZ/2);
    ushort* hb    = (ushort*)ws;
    ushort* WqkvT = (ushort*)(ws + 5*SZ);                    // 512*1536
    ushort* WprojT= (ushort*)(ws + 5*SZ + 393216);           // 512*512
    ushort* W1T   = (ushort*)(ws + 5*SZ + 524288);           // 2048*512
    ushort* W2T   = (ushort*)(ws + 5*SZ + 1048576);          // 512*2048
    unsigned long long* bits = (unsigned long long*)(ws + 5*SZ + 1572864);
    int*    flag  = (int*)(ws + 5*SZ + 1572864 + 262144);

    float* out = (float*)d_out;
    const int nwords = BATCH * SEQ * (SEQ / 64);   // 131072

    detect_mask_k<<<1, 256, 0, stream>>>((const unsigned*)mask, flag, 65536);
    mask_prep_k<<<nwords / 4, 256, 0, stream>>>(mask, flag, bits, nwords);
    conv_bf16_k<<<2048, 256, 0, stream>>>(x, xb);
    wprep_k<<<dim3(24, 8),  256, 0, stream>>>(W_qkv,  WqkvT,  512, 1536);
    wprep_k<<<dim3(8, 8),   256, 0, stream>>>(W_proj, WprojT, 512, 512);
    wprep_k<<<dim3(32, 8),  256, 0, stream>>>(W1,     W1T,    512, 2048);
    wprep_k<<<dim3(8, 32),  256, 0, stream>>>(W2,     W2T,    2048, 512);

    // QKV: [4096,512]@[512,1536] -> bf16 Q/K/V [B,H,N,64]
    mgemm_k<3><<<dim3(12, 32), 256, 0, stream>>>(xb, WqkvT, b_qkv,
        nullptr, nullptr, Qb, Kb, Vb, ROWS, 3*DMODEL, DMODEL);
    // attention -> attnb bf16 [4096,512]
    attn_mfma_k<<<BATCH*NH*(SEQ/64), 256, 0, stream>>>(Qb, Kb, Vb, bits, attnb);
    // proj: [4096,512]@[512,512] -> ap f32
    mgemm_k<0><<<dim3(4, 32), 256, 0, stream>>>(attnb, WprojT, b_proj,
        ap, nullptr, nullptr, nullptr, nullptr, ROWS, DMODEL, DMODEL);
    // x1 = LN(x + ap)  (+ bf16 copy for MLP1)
    add_ln_k<<<ROWS, 256, 0, stream>>>(x, ap, ln1_g, ln1_b, x1, x1b);
    // MLP1: relu([4096,512]@[512,2048]) -> bf16 hb
    mgemm_k<1><<<dim3(16, 32), 256, 0, stream>>>(x1b, W1T, b1,
        nullptr, hb, nullptr, nullptr, nullptr, ROWS, 2048, DMODEL);
    // MLP2: relu([4096,2048]@[2048,512]) -> f32 mbuf
    mgemm_k<2><<<dim3(4, 32), 256, 0, stream>>>(hb, W2T, b2,
        mbuf, nullptr, nullptr, nullptr, nullptr, ROWS, DMODEL, 2048);
    // out = LN(x1 + mbuf)
    add_ln_k<<<ROWS, 256, 0, stream>>>(x1, mbuf, ln2_g, ln2_b, out, nullptr);
}

// Round 4
// 222.419 us; speedup vs baseline: 5.1112x; 1.0663x over previous
//
#include <hip/hip_runtime.h>
#include <math.h>

// Problem constants
constexpr int BATCH  = 2;
constexpr int SEQ    = 2048;
constexpr int DMODEL = 512;
constexpr int NH     = 8;
constexpr int DHEAD  = 64;
constexpr int ROWS   = BATCH * SEQ;           // 4096
constexpr size_t SZ  = (size_t)ROWS * DMODEL; // elems of one [4096][512] buffer

typedef __attribute__((ext_vector_type(8))) short bf16x8;
typedef __attribute__((ext_vector_type(4))) float f32x4;

__device__ __forceinline__ ushort f2bf(float f) {
    unsigned u = __float_as_uint(f);
    unsigned r = (u + 0x7FFFu + ((u >> 16) & 1u)) >> 16;
    return (ushort)r;
}

// pack 2 f32 -> 2 bf16 (RNE) in one instruction
__device__ __forceinline__ unsigned cvtpk_bf16(float lo, float hi) {
    unsigned r;
    asm("v_cvt_pk_bf16_f32 %0, %1, %2" : "=v"(r) : "v"(lo), "v"(hi));
    return r;
}

__device__ __forceinline__ void gload_lds16(const void* g, void* l) {
    __builtin_amdgcn_global_load_lds(
        (const __attribute__((address_space(1))) void*)g,
        (__attribute__((address_space(3))) void*)l, 16, 0, 0);
}

// ---------------------------------------------------------------------------
// Mask-encoding detector (bool mask may arrive as int32 / float32 / bytes).
// ---------------------------------------------------------------------------
__global__ void detect_mask_k(const unsigned* __restrict__ m, int* __restrict__ flag, int n)
{
    __shared__ int sh[2];
    if (threadIdx.x == 0) { sh[0] = 0; sh[1] = 0; }
    __syncthreads();
    unsigned b0 = 0, b1 = 0;
    for (int i = threadIdx.x; i < n; i += 256) {
        unsigned v = m[i];
        b0 |= (v > 1u) ? 1u : 0u;
        b1 |= (v != 0u && v != 0x3F800000u) ? 1u : 0u;
    }
    if (b0) atomicOr(&sh[0], 1);
    if (b1) atomicOr(&sh[1], 1);
    __syncthreads();
    if (threadIdx.x == 0) *flag = sh[0] | (sh[1] << 1);
}

// ---------------------------------------------------------------------------
// Compact mask -> bitmask: bits[w] bit i = mask[w*64 + i] != 0.
// ---------------------------------------------------------------------------
__global__ __launch_bounds__(256) void mask_prep_k(
    const void* __restrict__ maskp, const int* __restrict__ flagp,
    unsigned long long* __restrict__ bits, int nwords)
{
    const int w = blockIdx.x * 4 + (threadIdx.x >> 6);
    if (w >= nwords) return;
    const int lane = threadIdx.x & 63;
    const size_t idx = ((size_t)w << 6) + lane;
    const int f = *flagp;
    bool mv;
    if (!(f & 1))      mv = ((const int*)maskp)[idx] != 0;
    else if (!(f & 2)) mv = ((const float*)maskp)[idx] != 0.f;
    else               mv = ((const unsigned char*)maskp)[idx] != 0;
    unsigned long long bal = __ballot(mv);
    if (lane == 0) bits[w] = bal;
}

// ---------------------------------------------------------------------------
// f32 -> bf16 elementwise convert (x for QKV input).
// ---------------------------------------------------------------------------
__global__ __launch_bounds__(256) void conv_bf16_k(
    const float* __restrict__ in, ushort* __restrict__ out)
{
    const size_t i = ((size_t)blockIdx.x * 256 + threadIdx.x) * 4;
    float4 v = *(const float4*)(in + i);
    ushort4 o;
    o.x = f2bf(v.x); o.y = f2bf(v.y); o.z = f2bf(v.z); o.w = f2bf(v.w);
    *(ushort4*)(out + i) = o;
}

// ---------------------------------------------------------------------------
// Weight prep: W[K][N] f32 -> Wt[N][K] bf16 (transpose + convert), 64x64 tiles.
// ---------------------------------------------------------------------------
__global__ __launch_bounds__(256) void wprep_k(
    const float* __restrict__ W, ushort* __restrict__ Wt, int K, int N)
{
    __shared__ ushort T[64][65];
    const int t = threadIdx.x;
    const int k0 = blockIdx.y * 64, n0 = blockIdx.x * 64;
    const int r = t >> 4, c4 = (t & 15) * 4;
    #pragma unroll
    for (int it = 0; it < 4; ++it) {
        const int row = it*16 + r;
        float4 v = *(const float4*)&W[(size_t)(k0 + row) * N + n0 + c4];
        T[c4+0][row] = f2bf(v.x);
        T[c4+1][row] = f2bf(v.y);
        T[c4+2][row] = f2bf(v.z);
        T[c4+3][row] = f2bf(v.w);
    }
    __syncthreads();
    #pragma unroll
    for (int it = 0; it < 4; ++it) {
        const int row = it*16 + r;
        ushort4 o;
        o.x = T[row][c4+0]; o.y = T[row][c4+1];
        o.z = T[row][c4+2]; o.w = T[row][c4+3];
        *(ushort4*)&Wt[(size_t)(n0 + row) * K + k0 + c4] = o;
    }
}

// ---------------------------------------------------------------------------
// bf16 MFMA GEMM (m97 structure): C[M,N] = A[M,K] @ Wt[N,K]^T + bias.
// BM x 128 tile, BK=64, 256 threads = 4 waves (2x2).
// EPI: 0 = bias -> f32 | 1 = relu(bias) -> bf16 | 2 = relu(bias) -> f32
//      3 = bias -> bf16 QKV scatter, V written TRANSPOSED [b][h][d][token]
// ---------------------------------------------------------------------------
template<int EPI, int BM>
__global__ __launch_bounds__(256) void mgemm_k(
    const ushort* __restrict__ A,   // [M][K] bf16
    const ushort* __restrict__ Wt,  // [N][K] bf16
    const float* __restrict__ bias, // [N] f32
    float* __restrict__ Cf, ushort* __restrict__ Cb,
    ushort* __restrict__ Qo, ushort* __restrict__ Ko, ushort* __restrict__ Vo,
    int M, int N, int K)
{
    constexpr int WM   = BM / 2;     // per-wave M extent
    constexpr int MF   = WM / 16;    // m-fragments per wave
    constexpr int APW  = (BM / 8) / 4;  // A segs per wave

    __shared__ ushort As[BM * 64];
    __shared__ ushort Bs[128 * 64];

    const int tid  = threadIdx.x;
    const int wid  = tid >> 6, lane = tid & 63;
    const int lq   = lane & 15, lg = lane >> 4;
    const int wr   = wid >> 1,  wc = wid & 1;
    const int bm   = blockIdx.y * BM, bn = blockIdx.x * 128;

    const int srow0 = lane >> 3;
    const int sch   = lane & 7;

    f32x4 acc[MF][4] = {};

    for (int k0 = 0; k0 < K; k0 += 64) {
        __syncthreads();
        #pragma unroll
        for (int i = 0; i < APW; ++i) {
            const int seg = wid * APW + i;
            const int row = seg * 8 + srow0;
            const int c16 = sch ^ (row & 7);
            gload_lds16(A + (size_t)(bm + row) * K + k0 + c16 * 8, As + seg * 512);
        }
        #pragma unroll
        for (int i = 0; i < 4; ++i) {
            const int seg = wid * 4 + i;
            const int row = seg * 8 + srow0;
            const int c16 = sch ^ (row & 7);
            gload_lds16(Wt + (size_t)(bn + row) * K + k0 + c16 * 8, Bs + seg * 512);
        }
        __syncthreads();

        #pragma unroll
        for (int ks = 0; ks < 2; ++ks) {
            bf16x8 af[MF], bfr[4];
            #pragma unroll
            for (int m = 0; m < MF; ++m) {
                const int row = wr*WM + m*16 + lq;
                const int c16 = (ks*4 + lg) ^ (row & 7);
                af[m] = *(const bf16x8*)&As[row * 64 + c16 * 8];
            }
            #pragma unroll
            for (int n = 0; n < 4; ++n) {
                const int row = wc*64 + n*16 + lq;
                const int c16 = (ks*4 + lg) ^ (row & 7);
                bfr[n] = *(const bf16x8*)&Bs[row * 64 + c16 * 8];
            }
            #pragma unroll
            for (int m = 0; m < MF; ++m)
                #pragma unroll
                for (int n = 0; n < 4; ++n)
                    acc[m][n] = __builtin_amdgcn_mfma_f32_16x16x32_bf16(
                        af[m], bfr[n], acc[m][n], 0, 0, 0);
        }
    }

    #pragma unroll
    for (int m = 0; m < MF; ++m) {
        const int row0 = bm + wr*WM + m*16 + lg*4;
        #pragma unroll
        for (int n = 0; n < 4; ++n) {
            const int col = bn + wc*64 + n*16 + lq;
            const float bv = bias[col];
            float v[4];
            #pragma unroll
            for (int r = 0; r < 4; ++r) {
                v[r] = acc[m][n][r] + bv;
                if (EPI == 1 || EPI == 2) v[r] = fmaxf(v[r], 0.f);
            }
            if (EPI == 3) {
                const int part = col >> 9, hc = col & 511;
                const int hh = hc >> 6, d0 = hc & 63;
                const int bidx = row0 >> 11, nrow0 = row0 & 2047;
                if (part == 2) {
                    // V transposed: Vt[b][h][d][token], 4 consecutive tokens
                    ushort4 pv;
                    pv.x = f2bf(v[0]); pv.y = f2bf(v[1]);
                    pv.z = f2bf(v[2]); pv.w = f2bf(v[3]);
                    *(ushort4*)(Vo + (((size_t)bidx*NH + hh)*DHEAD + d0)*SEQ + nrow0) = pv;
                } else {
                    ushort* dst = (part == 0) ? Qo : Ko;
                    #pragma unroll
                    for (int r = 0; r < 4; ++r)
                        dst[((((size_t)bidx*NH + hh)*SEQ + nrow0 + r) << 6) + d0] = f2bf(v[r]);
                }
            } else {
                #pragma unroll
                for (int r = 0; r < 4; ++r) {
                    const int row = row0 + r;
                    if (EPI == 1) Cb[(size_t)row * N + col] = f2bf(v[r]);
                    else          Cf[(size_t)row * N + col] = v[r];
                }
            }
        }
    }
}

// ---------------------------------------------------------------------------
// bf16 MFMA flash attention, v2.
//  - K staged via global_load_lds + XOR swizzle (both sides), double-buffered
//  - V pre-transposed in GLOBAL ([b][h][d][token]) -> no in-kernel transpose
//  - base-2 softmax (native v_exp_f32), cvt_pk bf16 packing, exact defer-max
//  - one barrier per chunk
// Grid: B*H*(N/64) = 512 blocks, 256 threads; wave owns 16 q rows.
// ---------------------------------------------------------------------------
__global__ __launch_bounds__(256) void attn_mfma_k(
    const ushort* __restrict__ Qb, const ushort* __restrict__ Kb,
    const ushort* __restrict__ Vtb, const unsigned long long* __restrict__ mbits,
    ushort* __restrict__ outp)
{
    __shared__ ushort Klds[2][64 * 64];   // [key][d], XOR-swizzled 16B chunks
    __shared__ ushort Vlds[2][64 * 64];   // [d][key], XOR-swizzled
    __shared__ ushort Plds[4][16 * 64];   // per-wave [q][key], XOR-swizzled

    const int tid  = threadIdx.x;
    const int wid  = tid >> 6;
    const int lane = tid & 63;
    const int lq   = lane & 15;
    const int lg   = lane >> 4;

    const int tile = blockIdx.x & 31;
    const int bh   = blockIdx.x >> 5;
    const int b    = bh >> 3, h = bh & 7;
    const int qw   = tile * 64 + wid * 16;

    // hoisted Q fragments (B-operand)
    const ushort* Qg = Qb + ((size_t)bh * SEQ + qw + lq) * DHEAD;
    const bf16x8 qf0 = *(const bf16x8*)(Qg + lg * 8);
    const bf16x8 qf1 = *(const bf16x8*)(Qg + 32 + lg * 8);

    const ushort* Kg = Kb  + (size_t)bh * SEQ * DHEAD;     // [key][d]
    const ushort* Vg = Vtb + (size_t)bh * DHEAD * SEQ;     // [d][key]

    const int srow0 = lane >> 3;   // row within 8-row segment
    const int sch   = lane & 7;    // stored 16B chunk

    const unsigned long long* mrow = mbits + ((size_t)b * SEQ + qw + lq) * (SEQ / 64);

    f32x4 o[4] = {};
    float mrun = -1e30f, lrun = 0.f;
    const float k2 = 0.125f * 1.44269504f;   // 1/sqrt(dh) * log2(e)

    // stage chunk 0 into buf 0 (wave wid: segs wid*2, wid*2+1 of K and V)
    #pragma unroll
    for (int i = 0; i < 2; ++i) {
        const int seg = wid * 2 + i;
        const int row = seg * 8 + srow0;
        const int gc  = sch ^ (row & 7);
        gload_lds16(Kg + (size_t)row * DHEAD + gc * 8, &Klds[0][seg * 512]);
        gload_lds16(Vg + (size_t)row * SEQ + gc * 8, &Vlds[0][seg * 512]);
    }
    __syncthreads();

    for (int c = 0; c < SEQ / 64; ++c) {
        const int cur = c & 1;
        if (c + 1 < SEQ / 64) {   // issue next-chunk loads early
            #pragma unroll
            for (int i = 0; i < 2; ++i) {
                const int seg = wid * 2 + i;
                const int row = seg * 8 + srow0;
                const int gc  = sch ^ (row & 7);
                gload_lds16(Kg + (size_t)((c+1)*64 + row) * DHEAD + gc * 8,
                            &Klds[cur ^ 1][seg * 512]);
                gload_lds16(Vg + (size_t)row * SEQ + (c+1)*64 + gc * 8,
                            &Vlds[cur ^ 1][seg * 512]);
            }
        }

        // QK^T: S^T tiles (16 keys x 16 q), d = 0..63
        f32x4 st[4];
        #pragma unroll
        for (int kt = 0; kt < 4; ++kt) {
            const int row = kt*16 + lq;
            bf16x8 kf0 = *(const bf16x8*)&Klds[cur][row*64 + ((lg  ) ^ (lq & 7))*8];
            bf16x8 kf1 = *(const bf16x8*)&Klds[cur][row*64 + ((4+lg) ^ (lq & 7))*8];
            f32x4 a = {};
            a = __builtin_amdgcn_mfma_f32_16x16x32_bf16(kf0, qf0, a, 0, 0, 0);
            a = __builtin_amdgcn_mfma_f32_16x16x32_bf16(kf1, qf1, a, 0, 0, 0);
            st[kt] = a;
        }

        // mask + scale into base-2 domain
        const unsigned long long mw = mrow[c];
        float sv[16];
        float cmax = -1e30f;
        #pragma unroll
        for (int kt = 0; kt < 4; ++kt)
            #pragma unroll
            for (int r = 0; r < 4; ++r) {
                const int bitpos = kt*16 + lg*4 + r;
                const float s = ((mw >> bitpos) & 1ull) ? st[kt][r] * k2 : -1e9f;
                sv[kt*4 + r] = s;
                cmax = fmaxf(cmax, s);
            }
        cmax = fmaxf(cmax, __shfl_xor(cmax, 16));
        cmax = fmaxf(cmax, __shfl_xor(cmax, 32));

        // exact defer-max: skip rescale when no row grew
        float mnew = mrun, scale = 1.0f;
        if (!__all(cmax <= mrun)) {
            mnew  = fmaxf(mrun, cmax);
            scale = exp2f(mrun - mnew);
            float sc[4];
            #pragma unroll
            for (int r = 0; r < 4; ++r) sc[r] = __shfl(scale, lg*4 + r);
            #pragma unroll
            for (int nt = 0; nt < 4; ++nt)
                #pragma unroll
                for (int r = 0; r < 4; ++r) o[nt][r] *= sc[r];
        }

        float lsum = 0.f;
        #pragma unroll
        for (int kt = 0; kt < 4; ++kt) {
            const float p0 = exp2f(sv[kt*4+0] - mnew);
            const float p1 = exp2f(sv[kt*4+1] - mnew);
            const float p2 = exp2f(sv[kt*4+2] - mnew);
            const float p3 = exp2f(sv[kt*4+3] - mnew);
            lsum += (p0 + p1) + (p2 + p3);
            uint2 pk;
            pk.x = cvtpk_bf16(p0, p1);
            pk.y = cvtpk_bf16(p2, p3);
            // swizzled write: key0 = kt*16+lg*4 -> chunk kt*2+(lg>>1), half (lg&1)
            const int addr = lq*64 + (((kt*2 + (lg>>1)) ^ (lq & 7)) * 8) + (lg & 1)*4;
            *(uint2*)&Plds[wid][addr] = pk;
        }
        lsum += __shfl_xor(lsum, 16);
        lsum += __shfl_xor(lsum, 32);
        lrun = lrun * scale + lsum;
        mrun = mnew;

        // PV: O[q][d] += P[q][key] * V[key][d]
        #pragma unroll
        for (int kk = 0; kk < 2; ++kk) {
            const int ch = (kk*4 + lg) ^ (lq & 7);
            bf16x8 pf = *(const bf16x8*)&Plds[wid][lq*64 + ch*8];
            #pragma unroll
            for (int nt = 0; nt < 4; ++nt) {
                bf16x8 vf = *(const bf16x8*)&Vlds[cur][(nt*16 + lq)*64 + ch*8];
                o[nt] = __builtin_amdgcn_mfma_f32_16x16x32_bf16(pf, vf, o[nt], 0, 0, 0);
            }
        }

        __syncthreads();   // drains next-chunk loads; all waves done with cur
    }

    float linv[4];
    #pragma unroll
    for (int r = 0; r < 4; ++r) linv[r] = 1.0f / __shfl(lrun, lg*4 + r);
    #pragma unroll
    for (int nt = 0; nt < 4; ++nt)
        #pragma unroll
        for (int r = 0; r < 4; ++r) {
            const size_t row = (size_t)b * SEQ + qw + lg*4 + r;
            outp[row * DMODEL + h*DHEAD + nt*16 + lq] = f2bf(o[nt][r] * linv[r]);
        }
}

// ---------------------------------------------------------------------------
// out = LayerNorm(X + A)*g + b over DMODEL=512; optional bf16 copy.
// ---------------------------------------------------------------------------
__global__ __launch_bounds__(256) void add_ln_k(
    const float* __restrict__ X, const float* __restrict__ Aa,
    const float* __restrict__ gg, const float* __restrict__ bb,
    float* __restrict__ out, ushort* __restrict__ outb)
{
    const int r = blockIdx.x;
    const int t = threadIdx.x;
    const float2 x2 = ((const float2*)(X  + (size_t)r * DMODEL))[t];
    const float2 a2 = ((const float2*)(Aa + (size_t)r * DMODEL))[t];
    const float v0 = x2.x + a2.x, v1 = x2.y + a2.y;
    float s  = v0 + v1;
    float ss = v0*v0 + v1*v1;
    #pragma unroll
    for (int off = 32; off > 0; off >>= 1) {
        s  += __shfl_down(s,  off);
        ss += __shfl_down(ss, off);
    }
    __shared__ float ps[4], pss[4];
    const int wid = t >> 6;
    if ((t & 63) == 0) { ps[wid] = s; pss[wid] = ss; }
    __syncthreads();
    const float tot  = ps[0] + ps[1] + ps[2] + ps[3];
    const float tots = pss[0] + pss[1] + pss[2] + pss[3];
    const float mean = tot * (1.0f / DMODEL);
    const float var  = tots * (1.0f / DMODEL) - mean * mean;
    const float rstd = rsqrtf(var + 1e-5f);
    const float2 g2 = ((const float2*)gg)[t];
    const float2 b2 = ((const float2*)bb)[t];
    float2 r2;
    r2.x = (v0 - mean) * rstd * g2.x + b2.x;
    r2.y = (v1 - mean) * rstd * g2.y + b2.y;
    ((float2*)(out + (size_t)r * DMODEL))[t] = r2;
    if (outb) {
        ushort2 ob; ob.x = f2bf(r2.x); ob.y = f2bf(r2.y);
        *(ushort2*)(outb + (size_t)r * DMODEL + t*2) = ob;
    }
}

// ---------------------------------------------------------------------------
extern "C" void kernel_launch(void* const* d_in, const int* in_sizes, int n_in,
                              void* d_out, int out_size, void* d_ws, size_t ws_size,
                              hipStream_t stream)
{
    const float* x      = (const float*)d_in[0];
    const void*  mask   = d_in[1];
    const float* W_qkv  = (const float*)d_in[2];
    const float* b_qkv  = (const float*)d_in[3];
    const float* W_proj = (const float*)d_in[4];
    const float* b_proj = (const float*)d_in[5];
    const float* ln1_g  = (const float*)d_in[6];
    const float* ln1_b  = (const float*)d_in[7];
    const float* W1     = (const float*)d_in[8];
    const float* b1     = (const float*)d_in[9];
    const float* W2     = (const float*)d_in[10];
    const float* b2     = (const float*)d_in[11];
    const float* ln2_g  = (const float*)d_in[12];
    const float* ln2_b  = (const float*)d_in[13];

    float* ws = (float*)d_ws;
    // Workspace (float-element offsets; SZ = 2,097,152):
    //  [0,   0.5) xb bf16           \
    //  [0.5, 2.0) Qb,Kb,Vtb bf16     } hb bf16 [0,2.0) in MLP phase
    //  [2.0, 2.5) attnb bf16        \
    //  [2.5, 3.5) ap f32             } mbuf f32 [2.0,3.0) in MLP phase
    //  [3.5, 4.5) x1 f32
    //  [4.5, 5.0) x1b bf16
    //  [5.0, ...) WqkvT, WprojT, W1T, W2T bf16; bits; flag
    ushort* xb    = (ushort*)ws;
    ushort* Qb    = (ushort*)(ws + SZ/2);
    ushort* Kb    = (ushort*)(ws + SZ);
    ushort* Vtb   = (ushort*)(ws + SZ + SZ/2);   // [B,H,DHEAD,SEQ]
    ushort* attnb = (ushort*)(ws + 2*SZ);
    float*  ap    = ws + 2*SZ + SZ/2;
    float*  mbuf  = ws + 2*SZ;
    float*  x1    = ws + 3*SZ + SZ/2;
    ushort* x1b   = (ushort*)(ws + 4*SZ + SZ/2);
    ushort* hb    = (ushort*)ws;
    ushort* WqkvT = (ushort*)(ws + 5*SZ);                    // 512*1536
    ushort* WprojT= (ushort*)(ws + 5*SZ + 393216);           // 512*512
    ushort* W1T   = (ushort*)(ws + 5*SZ + 524288);           // 2048*512
    ushort* W2T   = (ushort*)(ws + 5*SZ + 1048576);          // 512*2048
    unsigned long long* bits = (unsigned long long*)(ws + 5*SZ + 1572864);
    int*    flag  = (int*)(ws + 5*SZ + 1572864 + 262144);

    float* out = (float*)d_out;
    const int nwords = BATCH * SEQ * (SEQ / 64);   // 131072

    detect_mask_k<<<1, 256, 0, stream>>>((const unsigned*)mask, flag, 65536);
    mask_prep_k<<<nwords / 4, 256, 0, stream>>>(mask, flag, bits, nwords);
    conv_bf16_k<<<2048, 256, 0, stream>>>(x, xb);
    wprep_k<<<dim3(24, 8),  256, 0, stream>>>(W_qkv,  WqkvT,  512, 1536);
    wprep_k<<<dim3(8, 8),   256, 0, stream>>>(W_proj, WprojT, 512, 512);
    wprep_k<<<dim3(32, 8),  256, 0, stream>>>(W1,     W1T,    512, 2048);
    wprep_k<<<dim3(8, 32),  256, 0, stream>>>(W2,     W2T,    2048, 512);

    // QKV: [4096,512]@[512,1536] -> bf16 Q/K (row) + V (transposed)
    mgemm_k<3,128><<<dim3(12, 32), 256, 0, stream>>>(xb, WqkvT, b_qkv,
        nullptr, nullptr, Qb, Kb, Vtb, ROWS, 3*DMODEL, DMODEL);
    // attention -> attnb bf16 [4096,512]
    attn_mfma_k<<<BATCH*NH*(SEQ/64), 256, 0, stream>>>(Qb, Kb, Vtb, bits, attnb);
    // proj: [4096,512]@[512,512] -> ap f32   (BM=64: 256 blocks)
    mgemm_k<0,64><<<dim3(4, 64), 256, 0, stream>>>(attnb, WprojT, b_proj,
        ap, nullptr, nullptr, nullptr, nullptr, ROWS, DMODEL, DMODEL);
    // x1 = LN(x + ap)  (+ bf16 copy)
    add_ln_k<<<ROWS, 256, 0, stream>>>(x, ap, ln1_g, ln1_b, x1, x1b);
    // MLP1: relu([4096,512]@[512,2048]) -> bf16 hb
    mgemm_k<1,128><<<dim3(16, 32), 256, 0, stream>>>(x1b, W1T, b1,
        nullptr, hb, nullptr, nullptr, nullptr, ROWS, 2048, DMODEL);
    // MLP2: relu([4096,2048]@[2048,512]) -> f32 mbuf  (BM=64: 256 blocks)
    mgemm_k<2,64><<<dim3(4, 64), 256, 0, stream>>>(hb, W2T, b2,
        mbuf, nullptr, nullptr, nullptr, nullptr, ROWS, DMODEL, 2048);
    // out = LN(x1 + mbuf)
    add_ln_k<<<ROWS, 256, 0, stream>>>(x1, mbuf, ln2_g, ln2_b, out, nullptr);
}

// Round 5
// 210.837 us; speedup vs baseline: 5.3919x; 1.0549x over previous
//
#include <hip/hip_runtime.h>
#include <math.h>

// Problem constants
constexpr int BATCH  = 2;
constexpr int SEQ    = 2048;
constexpr int DMODEL = 512;
constexpr int NH     = 8;
constexpr int DHEAD  = 64;
constexpr int ROWS   = BATCH * SEQ;           // 4096
constexpr size_t SZ  = (size_t)ROWS * DMODEL; // elems of one [4096][512] buffer

typedef __attribute__((ext_vector_type(8))) short bf16x8;
typedef __attribute__((ext_vector_type(4))) float f32x4;

__device__ __forceinline__ ushort f2bf(float f) {
    unsigned u = __float_as_uint(f);
    unsigned r = (u + 0x7FFFu + ((u >> 16) & 1u)) >> 16;
    return (ushort)r;
}

// pack 2 f32 -> 2 bf16 (RNE) in one instruction
__device__ __forceinline__ unsigned cvtpk_bf16(float lo, float hi) {
    unsigned r;
    asm("v_cvt_pk_bf16_f32 %0, %1, %2" : "=v"(r) : "v"(lo), "v"(hi));
    return r;
}

__device__ __forceinline__ void gload_lds16(const void* g, void* l) {
    __builtin_amdgcn_global_load_lds(
        (const __attribute__((address_space(1))) void*)g,
        (__attribute__((address_space(3))) void*)l, 16, 0, 0);
}

// ---------------------------------------------------------------------------
// Mask-encoding detector (bool mask may arrive as int32 / float32 / bytes).
// ---------------------------------------------------------------------------
__global__ void detect_mask_k(const unsigned* __restrict__ m, int* __restrict__ flag, int n)
{
    __shared__ int sh[2];
    if (threadIdx.x == 0) { sh[0] = 0; sh[1] = 0; }
    __syncthreads();
    unsigned b0 = 0, b1 = 0;
    for (int i = threadIdx.x; i < n; i += 256) {
        unsigned v = m[i];
        b0 |= (v > 1u) ? 1u : 0u;
        b1 |= (v != 0u && v != 0x3F800000u) ? 1u : 0u;
    }
    if (b0) atomicOr(&sh[0], 1);
    if (b1) atomicOr(&sh[1], 1);
    __syncthreads();
    if (threadIdx.x == 0) *flag = sh[0] | (sh[1] << 1);
}

// ---------------------------------------------------------------------------
// Compact mask -> bitmask: bits[w] bit i = mask[w*64 + i] != 0.
// ---------------------------------------------------------------------------
__global__ __launch_bounds__(256) void mask_prep_k(
    const void* __restrict__ maskp, const int* __restrict__ flagp,
    unsigned long long* __restrict__ bits, int nwords)
{
    const int w = blockIdx.x * 4 + (threadIdx.x >> 6);
    if (w >= nwords) return;
    const int lane = threadIdx.x & 63;
    const size_t idx = ((size_t)w << 6) + lane;
    const int f = *flagp;
    bool mv;
    if (!(f & 1))      mv = ((const int*)maskp)[idx] != 0;
    else if (!(f & 2)) mv = ((const float*)maskp)[idx] != 0.f;
    else               mv = ((const unsigned char*)maskp)[idx] != 0;
    unsigned long long bal = __ballot(mv);
    if (lane == 0) bits[w] = bal;
}

// ---------------------------------------------------------------------------
// f32 -> bf16 elementwise convert (x for QKV input).
// ---------------------------------------------------------------------------
__global__ __launch_bounds__(256) void conv_bf16_k(
    const float* __restrict__ in, ushort* __restrict__ out)
{
    const size_t i = ((size_t)blockIdx.x * 256 + threadIdx.x) * 4;
    float4 v = *(const float4*)(in + i);
    ushort4 o;
    o.x = f2bf(v.x); o.y = f2bf(v.y); o.z = f2bf(v.z); o.w = f2bf(v.w);
    *(ushort4*)(out + i) = o;
}

// ---------------------------------------------------------------------------
// Fused weight prep: all four W[K][N] f32 -> Wt[N][K] bf16, 64x64 tiles.
// 1D grid of 192+64+256+256 = 768 blocks.
// ---------------------------------------------------------------------------
__global__ __launch_bounds__(256) void wprep_all_k(
    const float* __restrict__ Wq, const float* __restrict__ Wp,
    const float* __restrict__ W1w, const float* __restrict__ W2w,
    ushort* __restrict__ WqT, ushort* __restrict__ WpT,
    ushort* __restrict__ W1T, ushort* __restrict__ W2T)
{
    __shared__ ushort T[64][65];
    const int bid = blockIdx.x;
    const float* W; ushort* Wt; int K, N, tix, tiy;
    if (bid < 192)      { W = Wq;  Wt = WqT; K = 512;  N = 1536; tix = bid % 24;        tiy = bid / 24; }
    else if (bid < 256) { W = Wp;  Wt = WpT; K = 512;  N = 512;  tix = (bid-192) % 8;   tiy = (bid-192) / 8; }
    else if (bid < 512) { W = W1w; Wt = W1T; K = 512;  N = 2048; tix = (bid-256) % 32;  tiy = (bid-256) / 32; }
    else                { W = W2w; Wt = W2T; K = 2048; N = 512;  tix = (bid-512) % 8;   tiy = (bid-512) / 8; }
    const int k0 = tiy * 64, n0 = tix * 64;
    const int t = threadIdx.x;
    const int r = t >> 4, c4 = (t & 15) * 4;
    #pragma unroll
    for (int it = 0; it < 4; ++it) {
        const int row = it*16 + r;
        float4 v = *(const float4*)&W[(size_t)(k0 + row) * N + n0 + c4];
        T[c4+0][row] = f2bf(v.x);
        T[c4+1][row] = f2bf(v.y);
        T[c4+2][row] = f2bf(v.z);
        T[c4+3][row] = f2bf(v.w);
    }
    __syncthreads();
    #pragma unroll
    for (int it = 0; it < 4; ++it) {
        const int row = it*16 + r;
        ushort4 o;
        o.x = T[row][c4+0]; o.y = T[row][c4+1];
        o.z = T[row][c4+2]; o.w = T[row][c4+3];
        *(ushort4*)&Wt[(size_t)(n0 + row) * K + k0 + c4] = o;
    }
}

// ---------------------------------------------------------------------------
// bf16 MFMA GEMM (m97 structure): C[M,N] = A[M,K] @ Wt[N,K]^T + bias.
// BM x 128 tile, BK=64, 256 threads = 4 waves (2x2).
// EPI: 0 = bias -> f32 | 1 = relu(bias) -> bf16 | 2 = relu(bias) -> f32
//      3 = bias -> bf16 QKV scatter, V written TRANSPOSED [b][h][d][token]
// ---------------------------------------------------------------------------
template<int EPI, int BM>
__global__ __launch_bounds__(256) void mgemm_k(
    const ushort* __restrict__ A,   // [M][K] bf16
    const ushort* __restrict__ Wt,  // [N][K] bf16
    const float* __restrict__ bias, // [N] f32
    float* __restrict__ Cf, ushort* __restrict__ Cb,
    ushort* __restrict__ Qo, ushort* __restrict__ Ko, ushort* __restrict__ Vo,
    int M, int N, int K)
{
    constexpr int WM   = BM / 2;
    constexpr int MF   = WM / 16;
    constexpr int APW  = (BM / 8) / 4;

    __shared__ ushort As[BM * 64];
    __shared__ ushort Bs[128 * 64];

    const int tid  = threadIdx.x;
    const int wid  = tid >> 6, lane = tid & 63;
    const int lq   = lane & 15, lg = lane >> 4;
    const int wr   = wid >> 1,  wc = wid & 1;
    const int bm   = blockIdx.y * BM, bn = blockIdx.x * 128;

    const int srow0 = lane >> 3;
    const int sch   = lane & 7;

    f32x4 acc[MF][4] = {};

    for (int k0 = 0; k0 < K; k0 += 64) {
        __syncthreads();
        #pragma unroll
        for (int i = 0; i < APW; ++i) {
            const int seg = wid * APW + i;
            const int row = seg * 8 + srow0;
            const int c16 = sch ^ (row & 7);
            gload_lds16(A + (size_t)(bm + row) * K + k0 + c16 * 8, As + seg * 512);
        }
        #pragma unroll
        for (int i = 0; i < 4; ++i) {
            const int seg = wid * 4 + i;
            const int row = seg * 8 + srow0;
            const int c16 = sch ^ (row & 7);
            gload_lds16(Wt + (size_t)(bn + row) * K + k0 + c16 * 8, Bs + seg * 512);
        }
        __syncthreads();

        #pragma unroll
        for (int ks = 0; ks < 2; ++ks) {
            bf16x8 af[MF], bfr[4];
            #pragma unroll
            for (int m = 0; m < MF; ++m) {
                const int row = wr*WM + m*16 + lq;
                const int c16 = (ks*4 + lg) ^ (row & 7);
                af[m] = *(const bf16x8*)&As[row * 64 + c16 * 8];
            }
            #pragma unroll
            for (int n = 0; n < 4; ++n) {
                const int row = wc*64 + n*16 + lq;
                const int c16 = (ks*4 + lg) ^ (row & 7);
                bfr[n] = *(const bf16x8*)&Bs[row * 64 + c16 * 8];
            }
            #pragma unroll
            for (int m = 0; m < MF; ++m)
                #pragma unroll
                for (int n = 0; n < 4; ++n)
                    acc[m][n] = __builtin_amdgcn_mfma_f32_16x16x32_bf16(
                        af[m], bfr[n], acc[m][n], 0, 0, 0);
        }
    }

    #pragma unroll
    for (int m = 0; m < MF; ++m) {
        const int row0 = bm + wr*WM + m*16 + lg*4;
        #pragma unroll
        for (int n = 0; n < 4; ++n) {
            const int col = bn + wc*64 + n*16 + lq;
            const float bv = bias[col];
            float v[4];
            #pragma unroll
            for (int r = 0; r < 4; ++r) {
                v[r] = acc[m][n][r] + bv;
                if (EPI == 1 || EPI == 2) v[r] = fmaxf(v[r], 0.f);
            }
            if (EPI == 3) {
                const int part = col >> 9, hc = col & 511;
                const int hh = hc >> 6, d0 = hc & 63;
                const int bidx = row0 >> 11, nrow0 = row0 & 2047;
                if (part == 2) {
                    ushort4 pv;
                    pv.x = f2bf(v[0]); pv.y = f2bf(v[1]);
                    pv.z = f2bf(v[2]); pv.w = f2bf(v[3]);
                    *(ushort4*)(Vo + (((size_t)bidx*NH + hh)*DHEAD + d0)*SEQ + nrow0) = pv;
                } else {
                    ushort* dst = (part == 0) ? Qo : Ko;
                    #pragma unroll
                    for (int r = 0; r < 4; ++r)
                        dst[((((size_t)bidx*NH + hh)*SEQ + nrow0 + r) << 6) + d0] = f2bf(v[r]);
                }
            } else {
                #pragma unroll
                for (int r = 0; r < 4; ++r) {
                    const int row = row0 + r;
                    if (EPI == 1) Cb[(size_t)row * N + col] = f2bf(v[r]);
                    else          Cf[(size_t)row * N + col] = v[r];
                }
            }
        }
    }
}

// ---------------------------------------------------------------------------
// bf16 MFMA flash attention, v3: 2-way KV-split for occupancy.
// Grid: (512, 2). blockIdx.y = key-range half s; each block does 16 of 32
// 64-key chunks and writes UNNORMALIZED partial O plus per-row (m, l).
// Chunk loop unrolled x2 so the double-buffer index is compile-time.
// ---------------------------------------------------------------------------
__global__ __launch_bounds__(256) void attn_mfma_k(
    const ushort* __restrict__ Qb, const ushort* __restrict__ Kb,
    const ushort* __restrict__ Vtb, const unsigned long long* __restrict__ mbits,
    float* __restrict__ Opart, float2* __restrict__ MLpart)
{
    __shared__ ushort Klds[2][64 * 64];   // [key][d], XOR-swizzled 16B chunks
    __shared__ ushort Vlds[2][64 * 64];   // [d][key], XOR-swizzled
    __shared__ ushort Plds[4][16 * 64];   // per-wave [q][key], XOR-swizzled

    const int tid  = threadIdx.x;
    const int wid  = tid >> 6;
    const int lane = tid & 63;
    const int lq   = lane & 15;
    const int lg   = lane >> 4;

    const int tile = blockIdx.x & 31;
    const int bh   = blockIdx.x >> 5;
    const int b    = bh >> 3;
    const int qw   = tile * 64 + wid * 16;
    const int s    = blockIdx.y;           // key-range half
    const int c0   = s * 16, c1 = c0 + 16; // chunk range

    // hoisted Q fragments (B-operand)
    const ushort* Qg = Qb + ((size_t)bh * SEQ + qw + lq) * DHEAD;
    const bf16x8 qf0 = *(const bf16x8*)(Qg + lg * 8);
    const bf16x8 qf1 = *(const bf16x8*)(Qg + 32 + lg * 8);

    const ushort* Kg = Kb  + (size_t)bh * SEQ * DHEAD;     // [key][d]
    const ushort* Vg = Vtb + (size_t)bh * DHEAD * SEQ;     // [d][key]

    const int srow0 = lane >> 3;
    const int sch   = lane & 7;

    const unsigned long long* mrow = mbits + ((size_t)b * SEQ + qw + lq) * (SEQ / 64);

    f32x4 o[4] = {};
    float mrun = -1e30f, lrun = 0.f;
    const float k2 = 0.125f * 1.44269504f;   // 1/sqrt(dh) * log2(e)

    auto STAGE = [&](int c, int buf) {
        #pragma unroll
        for (int i = 0; i < 2; ++i) {
            const int seg = wid * 2 + i;
            const int row = seg * 8 + srow0;
            const int gc  = sch ^ (row & 7);
            gload_lds16(Kg + (size_t)(c*64 + row) * DHEAD + gc * 8, &Klds[buf][seg * 512]);
            gload_lds16(Vg + (size_t)row * SEQ + c*64 + gc * 8, &Vlds[buf][seg * 512]);
        }
    };

    auto CHUNK = [&](int c, int cur) {
        if (c + 1 < c1) STAGE(c + 1, cur ^ 1);

        // QK^T: S^T tiles (16 keys x 16 q), d = 0..63
        f32x4 st[4];
        #pragma unroll
        for (int kt = 0; kt < 4; ++kt) {
            const int row = kt*16 + lq;
            bf16x8 kf0 = *(const bf16x8*)&Klds[cur][row*64 + ((lg  ) ^ (lq & 7))*8];
            bf16x8 kf1 = *(const bf16x8*)&Klds[cur][row*64 + ((4+lg) ^ (lq & 7))*8];
            f32x4 a = {};
            a = __builtin_amdgcn_mfma_f32_16x16x32_bf16(kf0, qf0, a, 0, 0, 0);
            a = __builtin_amdgcn_mfma_f32_16x16x32_bf16(kf1, qf1, a, 0, 0, 0);
            st[kt] = a;
        }

        // mask + scale (base-2 domain); single shift, then const extracts
        const unsigned long long mws = mrow[c] >> (lg * 4);
        const unsigned mlo = (unsigned)mws, mhi = (unsigned)(mws >> 32);
        float sv[16];
        float cmax = -1e30f;
        #pragma unroll
        for (int kt = 0; kt < 4; ++kt) {
            const unsigned half = (kt & 2) ? mhi : mlo;
            #pragma unroll
            for (int r = 0; r < 4; ++r) {
                const unsigned bit = (half >> ((kt & 1)*16 + r)) & 1u;
                const float sc = bit ? st[kt][r] * k2 : -1e9f;
                sv[kt*4 + r] = sc;
                cmax = fmaxf(cmax, sc);
            }
        }
        cmax = fmaxf(cmax, __shfl_xor(cmax, 16));
        cmax = fmaxf(cmax, __shfl_xor(cmax, 32));

        // exact defer-max: skip rescale when no row grew
        float mnew = mrun, scale = 1.0f;
        if (!__all(cmax <= mrun)) {
            mnew  = fmaxf(mrun, cmax);
            scale = exp2f(mrun - mnew);
            float sc[4];
            #pragma unroll
            for (int r = 0; r < 4; ++r) sc[r] = __shfl(scale, lg*4 + r);
            #pragma unroll
            for (int nt = 0; nt < 4; ++nt)
                #pragma unroll
                for (int r = 0; r < 4; ++r) o[nt][r] *= sc[r];
        }

        float lsum = 0.f;
        #pragma unroll
        for (int kt = 0; kt < 4; ++kt) {
            const float p0 = exp2f(sv[kt*4+0] - mnew);
            const float p1 = exp2f(sv[kt*4+1] - mnew);
            const float p2 = exp2f(sv[kt*4+2] - mnew);
            const float p3 = exp2f(sv[kt*4+3] - mnew);
            lsum += (p0 + p1) + (p2 + p3);
            uint2 pk;
            pk.x = cvtpk_bf16(p0, p1);
            pk.y = cvtpk_bf16(p2, p3);
            const int addr = lq*64 + (((kt*2 + (lg>>1)) ^ (lq & 7)) * 8) + (lg & 1)*4;
            *(uint2*)&Plds[wid][addr] = pk;
        }
        lsum += __shfl_xor(lsum, 16);
        lsum += __shfl_xor(lsum, 32);
        lrun = lrun * scale + lsum;
        mrun = mnew;

        // PV: O[q][d] += P[q][key] * V[key][d]
        #pragma unroll
        for (int kk = 0; kk < 2; ++kk) {
            const int ch = (kk*4 + lg) ^ (lq & 7);
            bf16x8 pf = *(const bf16x8*)&Plds[wid][lq*64 + ch*8];
            #pragma unroll
            for (int nt = 0; nt < 4; ++nt) {
                bf16x8 vf = *(const bf16x8*)&Vlds[cur][(nt*16 + lq)*64 + ch*8];
                o[nt] = __builtin_amdgcn_mfma_f32_16x16x32_bf16(pf, vf, o[nt], 0, 0, 0);
            }
        }

        __syncthreads();   // drains prefetch; all waves done with cur buffer
    };

    STAGE(c0, 0);
    __syncthreads();
    for (int c = c0; c < c1; c += 2) {
        CHUNK(c, 0);
        CHUNK(c + 1, 1);
    }

    // partial epilogue: unnormalized O + (m, l)
    #pragma unroll
    for (int nt = 0; nt < 4; ++nt)
        #pragma unroll
        for (int r = 0; r < 4; ++r) {
            const int qrow = qw + lg*4 + r;
            Opart[(((size_t)s*16 + bh)*SEQ + qrow)*64 + nt*16 + lq] = o[nt][r];
        }
    if (lg == 0) {
        float2 ml; ml.x = mrun; ml.y = lrun;
        MLpart[((size_t)s*16 + bh)*SEQ + qw + lq] = ml;
    }
}

// ---------------------------------------------------------------------------
// Combine the two KV-split halves (exact log-sum-exp merge, base-2 domain).
// Grid: B*H*SEQ/4 blocks of 256; one wave per row, lane = d.
// ---------------------------------------------------------------------------
__global__ __launch_bounds__(256) void attn_combine_k(
    const float* __restrict__ Op, const float2* __restrict__ ML,
    ushort* __restrict__ attnb)
{
    const int row  = blockIdx.x * 4 + (threadIdx.x >> 6);  // bh*SEQ + q
    const int lane = threadIdx.x & 63;
    const int bh = row >> 11, q = row & 2047;
    const int b = bh >> 3, h = bh & 7;
    const float2 ml0 = ML[row];
    const float2 ml1 = ML[16*SEQ + row];
    const float m  = fmaxf(ml0.x, ml1.x);
    const float a0 = exp2f(ml0.x - m), a1 = exp2f(ml1.x - m);
    const float l  = ml0.y*a0 + ml1.y*a1;
    const float o0 = Op[(size_t)row*64 + lane];
    const float o1 = Op[((size_t)16*SEQ + row)*64 + lane];
    const float o  = (o0*a0 + o1*a1) / l;
    attnb[((size_t)(b*SEQ + q))*DMODEL + h*DHEAD + lane] = f2bf(o);
}

// ---------------------------------------------------------------------------
// out = LayerNorm(X + A)*g + b over DMODEL=512; optional bf16 copy.
// ---------------------------------------------------------------------------
__global__ __launch_bounds__(256) void add_ln_k(
    const float* __restrict__ X, const float* __restrict__ Aa,
    const float* __restrict__ gg, const float* __restrict__ bb,
    float* __restrict__ out, ushort* __restrict__ outb)
{
    const int r = blockIdx.x;
    const int t = threadIdx.x;
    const float2 x2 = ((const float2*)(X  + (size_t)r * DMODEL))[t];
    const float2 a2 = ((const float2*)(Aa + (size_t)r * DMODEL))[t];
    const float v0 = x2.x + a2.x, v1 = x2.y + a2.y;
    float s  = v0 + v1;
    float ss = v0*v0 + v1*v1;
    #pragma unroll
    for (int off = 32; off > 0; off >>= 1) {
        s  += __shfl_down(s,  off);
        ss += __shfl_down(ss, off);
    }
    __shared__ float ps[4], pss[4];
    const int wid = t >> 6;
    if ((t & 63) == 0) { ps[wid] = s; pss[wid] = ss; }
    __syncthreads();
    const float tot  = ps[0] + ps[1] + ps[2] + ps[3];
    const float tots = pss[0] + pss[1] + pss[2] + pss[3];
    const float mean = tot * (1.0f / DMODEL);
    const float var  = tots * (1.0f / DMODEL) - mean * mean;
    const float rstd = rsqrtf(var + 1e-5f);
    const float2 g2 = ((const float2*)gg)[t];
    const float2 b2 = ((const float2*)bb)[t];
    float2 r2;
    r2.x = (v0 - mean) * rstd * g2.x + b2.x;
    r2.y = (v1 - mean) * rstd * g2.y + b2.y;
    ((float2*)(out + (size_t)r * DMODEL))[t] = r2;
    if (outb) {
        ushort2 ob; ob.x = f2bf(r2.x); ob.y = f2bf(r2.y);
        *(ushort2*)(outb + (size_t)r * DMODEL + t*2) = ob;
    }
}

// ---------------------------------------------------------------------------
extern "C" void kernel_launch(void* const* d_in, const int* in_sizes, int n_in,
                              void* d_out, int out_size, void* d_ws, size_t ws_size,
                              hipStream_t stream)
{
    const float* x      = (const float*)d_in[0];
    const void*  mask   = d_in[1];
    const float* W_qkv  = (const float*)d_in[2];
    const float* b_qkv  = (const float*)d_in[3];
    const float* W_proj = (const float*)d_in[4];
    const float* b_proj = (const float*)d_in[5];
    const float* ln1_g  = (const float*)d_in[6];
    const float* ln1_b  = (const float*)d_in[7];
    const float* W1     = (const float*)d_in[8];
    const float* b1     = (const float*)d_in[9];
    const float* W2     = (const float*)d_in[10];
    const float* b2     = (const float*)d_in[11];
    const float* ln2_g  = (const float*)d_in[12];
    const float* ln2_b  = (const float*)d_in[13];

    float* ws = (float*)d_ws;
    // Workspace (float-element offsets; SZ = 2,097,152):
    //  [0,   0.5) xb bf16           \
    //  [0.5, 2.0) Qb,Kb,Vtb bf16     } hb bf16 [0,2.0) in MLP phase
    //  [2.0, 2.5) attnb bf16
    //  [2.5, 4.5) Opart f32 (attn phase) / ap f32 [2.5,3.5) + x1 f32 [3.5,4.5)
    //  [4.5, 5.0) MLpart (attn) / x1b bf16
    //  mbuf f32 overlays [2.0,3.0) in MLP phase
    //  [5.0, ...) WqkvT, WprojT, W1T, W2T bf16; bits; flag
    ushort* xb    = (ushort*)ws;
    ushort* Qb    = (ushort*)(ws + SZ/2);
    ushort* Kb    = (ushort*)(ws + SZ);
    ushort* Vtb   = (ushort*)(ws + SZ + SZ/2);   // [B,H,DHEAD,SEQ]
    ushort* attnb = (ushort*)(ws + 2*SZ);
    float*  Opart = ws + 2*SZ + SZ/2;            // [2][16][SEQ][64] f32 = 2*SZ
    float2* MLp   = (float2*)(ws + 4*SZ + SZ/2); // [2][16][SEQ]
    float*  ap    = ws + 2*SZ + SZ/2;
    float*  mbuf  = ws + 2*SZ;
    float*  x1    = ws + 3*SZ + SZ/2;
    ushort* x1b   = (ushort*)(ws + 4*SZ + SZ/2);
    ushort* hb    = (ushort*)ws;
    ushort* WqkvT = (ushort*)(ws + 5*SZ);                    // 512*1536
    ushort* WprojT= (ushort*)(ws + 5*SZ + 393216);           // 512*512
    ushort* W1T   = (ushort*)(ws + 5*SZ + 524288);           // 2048*512
    ushort* W2T   = (ushort*)(ws + 5*SZ + 1048576);          // 512*2048
    unsigned long long* bits = (unsigned long long*)(ws + 5*SZ + 1572864);
    int*    flag  = (int*)(ws + 5*SZ + 1572864 + 262144);

    float* out = (float*)d_out;
    const int nwords = BATCH * SEQ * (SEQ / 64);   // 131072

    detect_mask_k<<<1, 256, 0, stream>>>((const unsigned*)mask, flag, 65536);
    mask_prep_k<<<nwords / 4, 256, 0, stream>>>(mask, flag, bits, nwords);
    conv_bf16_k<<<2048, 256, 0, stream>>>(x, xb);
    wprep_all_k<<<768, 256, 0, stream>>>(W_qkv, W_proj, W1, W2,
                                         WqkvT, WprojT, W1T, W2T);

    // QKV: [4096,512]@[512,1536] -> bf16 Q/K (row) + V (transposed)
    mgemm_k<3,128><<<dim3(12, 32), 256, 0, stream>>>(xb, WqkvT, b_qkv,
        nullptr, nullptr, Qb, Kb, Vtb, ROWS, 3*DMODEL, DMODEL);
    // attention partials (2-way KV split) -> combine -> attnb bf16
    attn_mfma_k<<<dim3(BATCH*NH*(SEQ/64), 2), 256, 0, stream>>>(
        Qb, Kb, Vtb, bits, Opart, MLp);
    attn_combine_k<<<BATCH*NH*SEQ/4, 256, 0, stream>>>(Opart, MLp, attnb);
    // proj: [4096,512]@[512,512] -> ap f32
    mgemm_k<0,64><<<dim3(4, 64), 256, 0, stream>>>(attnb, WprojT, b_proj,
        ap, nullptr, nullptr, nullptr, nullptr, ROWS, DMODEL, DMODEL);
    // x1 = LN(x + ap)  (+ bf16 copy)
    add_ln_k<<<ROWS, 256, 0, stream>>>(x, ap, ln1_g, ln1_b, x1, x1b);
    // MLP1: relu([4096,512]@[512,2048]) -> bf16 hb
    mgemm_k<1,128><<<dim3(16, 32), 256, 0, stream>>>(x1b, W1T, b1,
        nullptr, hb, nullptr, nullptr, nullptr, ROWS, 2048, DMODEL);
    // MLP2: relu([4096,2048]@[2048,512]) -> f32 mbuf
    mgemm_k<2,64><<<dim3(4, 64), 256, 0, stream>>>(hb, W2T, b2,
        mbuf, nullptr, nullptr, nullptr, nullptr, ROWS, DMODEL, 2048);
    // out = LN(x1 + mbuf)
    add_ln_k<<<ROWS, 256, 0, stream>>>(x1, mbuf, ln2_g, ln2_b, out, nullptr);
}

// Round 6
// 174.259 us; speedup vs baseline: 6.5237x; 1.2099x over previous
//
#include <hip/hip_runtime.h>
#include <math.h>

// Problem constants
constexpr int BATCH  = 2;
constexpr int SEQ    = 2048;
constexpr int DMODEL = 512;
constexpr int NH     = 8;
constexpr int DHEAD  = 64;
constexpr int ROWS   = BATCH * SEQ;           // 4096
constexpr size_t SZ  = (size_t)ROWS * DMODEL; // elems of one [4096][512] buffer

typedef __attribute__((ext_vector_type(8))) short bf16x8;
typedef __attribute__((ext_vector_type(4))) float f32x4;

__device__ __forceinline__ ushort f2bf(float f) {
    unsigned u = __float_as_uint(f);
    unsigned r = (u + 0x7FFFu + ((u >> 16) & 1u)) >> 16;
    return (ushort)r;
}

// pack 2 f32 -> 2 bf16 (RNE) in one instruction
__device__ __forceinline__ unsigned cvtpk_bf16(float lo, float hi) {
    unsigned r;
    asm("v_cvt_pk_bf16_f32 %0, %1, %2" : "=v"(r) : "v"(lo), "v"(hi));
    return r;
}

__device__ __forceinline__ void gload_lds16(const void* g, void* l) {
    __builtin_amdgcn_global_load_lds(
        (const __attribute__((address_space(1))) void*)g,
        (__attribute__((address_space(3))) void*)l, 16, 0, 0);
}

// ---------------------------------------------------------------------------
// Mask-encoding detector, parallel. flag MUST be zeroed (hipMemsetAsync)
// before launch. 64 blocks x 256 threads x uint4 = 65536 sampled values.
//   bit0 set: saw value >1            (=> not int32 0/1)
//   bit1 set: saw value not in {0, 0x3F800000}  (=> not float32 0.0/1.0)
// mode: 0=int32, 1=float32, 2=bytes
// ---------------------------------------------------------------------------
__global__ __launch_bounds__(256) void detect_mask_k(
    const uint4* __restrict__ m, int* __restrict__ flag)
{
    const int i = blockIdx.x * 256 + threadIdx.x;
    const uint4 v = m[i];
    unsigned b0 = 0, b1 = 0;
    #pragma unroll
    for (int c = 0; c < 4; ++c) {
        const unsigned u = (&v.x)[c];
        b0 |= (u > 1u) ? 1u : 0u;
        b1 |= (u != 0u && u != 0x3F800000u) ? 1u : 0u;
    }
    const int lane = threadIdx.x & 63;
    if (__any(b0) && lane == 0) atomicOr(flag, 1);
    if (__any(b1) && lane == 0) atomicOr(flag, 2);
}

// ---------------------------------------------------------------------------
// Fused prep: [0,2048) x f32->bf16 conv | [2048,2816) weight transpose+conv
//             [2816, 2816+32768) mask bitmask compaction
// ---------------------------------------------------------------------------
__global__ __launch_bounds__(256) void prep_all_k(
    const float* __restrict__ x, ushort* __restrict__ xb,
    const float* __restrict__ Wq, const float* __restrict__ Wp,
    const float* __restrict__ W1w, const float* __restrict__ W2w,
    ushort* __restrict__ WqT, ushort* __restrict__ WpT,
    ushort* __restrict__ W1T, ushort* __restrict__ W2T,
    const void* __restrict__ maskp, const int* __restrict__ flagp,
    unsigned long long* __restrict__ bits)
{
    __shared__ ushort T[64][65];
    const int bid = blockIdx.x;
    const int t = threadIdx.x;

    if (bid < 2048) {           // x f32 -> bf16
        const size_t i = ((size_t)bid * 256 + t) * 4;
        float4 v = *(const float4*)(x + i);
        ushort4 o;
        o.x = f2bf(v.x); o.y = f2bf(v.y); o.z = f2bf(v.z); o.w = f2bf(v.w);
        *(ushort4*)(xb + i) = o;
        return;
    }
    if (bid >= 2816) {          // mask -> bitmask
        const int w = (bid - 2816) * 4 + (t >> 6);
        const int lane = t & 63;
        const size_t idx = ((size_t)w << 6) + lane;
        const int f = *flagp;
        bool mv;
        if (!(f & 1))      mv = ((const int*)maskp)[idx] != 0;
        else if (!(f & 2)) mv = ((const float*)maskp)[idx] != 0.f;
        else               mv = ((const unsigned char*)maskp)[idx] != 0;
        unsigned long long bal = __ballot(mv);
        if (lane == 0) bits[w] = bal;
        return;
    }
    // weight transpose+convert, 64x64 tiles
    const int wb = bid - 2048;
    const float* W; ushort* Wt; int K, N, tix, tiy;
    if (wb < 192)      { W = Wq;  Wt = WqT; K = 512;  N = 1536; tix = wb % 24;        tiy = wb / 24; }
    else if (wb < 256) { W = Wp;  Wt = WpT; K = 512;  N = 512;  tix = (wb-192) % 8;   tiy = (wb-192) / 8; }
    else if (wb < 512) { W = W1w; Wt = W1T; K = 512;  N = 2048; tix = (wb-256) % 32;  tiy = (wb-256) / 32; }
    else               { W = W2w; Wt = W2T; K = 2048; N = 512;  tix = (wb-512) % 8;   tiy = (wb-512) / 8; }
    const int k0 = tiy * 64, n0 = tix * 64;
    const int r = t >> 4, c4 = (t & 15) * 4;
    #pragma unroll
    for (int it = 0; it < 4; ++it) {
        const int row = it*16 + r;
        float4 v = *(const float4*)&W[(size_t)(k0 + row) * N + n0 + c4];
        T[c4+0][row] = f2bf(v.x);
        T[c4+1][row] = f2bf(v.y);
        T[c4+2][row] = f2bf(v.z);
        T[c4+3][row] = f2bf(v.w);
    }
    __syncthreads();
    #pragma unroll
    for (int it = 0; it < 4; ++it) {
        const int row = it*16 + r;
        ushort4 o;
        o.x = T[row][c4+0]; o.y = T[row][c4+1];
        o.z = T[row][c4+2]; o.w = T[row][c4+3];
        *(ushort4*)&Wt[(size_t)(n0 + row) * K + k0 + c4] = o;
    }
}

// ---------------------------------------------------------------------------
// bf16 MFMA GEMM (m97 structure): C[M,N] = A[M,K] @ Wt[N,K]^T + bias.
// BM x 128 tile, BK=64, 256 threads = 4 waves (2x2).
// EPI: 0 = bias -> f32 | 1 = relu(bias) -> bf16 | 2 = relu(bias) -> f32
//      3 = bias -> bf16 QKV scatter, V written TRANSPOSED [b][h][d][token]
// ---------------------------------------------------------------------------
template<int EPI, int BM>
__global__ __launch_bounds__(256) void mgemm_k(
    const ushort* __restrict__ A,   // [M][K] bf16
    const ushort* __restrict__ Wt,  // [N][K] bf16
    const float* __restrict__ bias, // [N] f32
    float* __restrict__ Cf, ushort* __restrict__ Cb,
    ushort* __restrict__ Qo, ushort* __restrict__ Ko, ushort* __restrict__ Vo,
    int M, int N, int K)
{
    constexpr int WM   = BM / 2;
    constexpr int MF   = WM / 16;
    constexpr int APW  = (BM / 8) / 4;

    __shared__ ushort As[BM * 64];
    __shared__ ushort Bs[128 * 64];

    const int tid  = threadIdx.x;
    const int wid  = tid >> 6, lane = tid & 63;
    const int lq   = lane & 15, lg = lane >> 4;
    const int wr   = wid >> 1,  wc = wid & 1;
    const int bm   = blockIdx.y * BM, bn = blockIdx.x * 128;

    const int srow0 = lane >> 3;
    const int sch   = lane & 7;

    f32x4 acc[MF][4] = {};

    for (int k0 = 0; k0 < K; k0 += 64) {
        __syncthreads();
        #pragma unroll
        for (int i = 0; i < APW; ++i) {
            const int seg = wid * APW + i;
            const int row = seg * 8 + srow0;
            const int c16 = sch ^ (row & 7);
            gload_lds16(A + (size_t)(bm + row) * K + k0 + c16 * 8, As + seg * 512);
        }
        #pragma unroll
        for (int i = 0; i < 4; ++i) {
            const int seg = wid * 4 + i;
            const int row = seg * 8 + srow0;
            const int c16 = sch ^ (row & 7);
            gload_lds16(Wt + (size_t)(bn + row) * K + k0 + c16 * 8, Bs + seg * 512);
        }
        __syncthreads();

        #pragma unroll
        for (int ks = 0; ks < 2; ++ks) {
            bf16x8 af[MF], bfr[4];
            #pragma unroll
            for (int m = 0; m < MF; ++m) {
                const int row = wr*WM + m*16 + lq;
                const int c16 = (ks*4 + lg) ^ (row & 7);
                af[m] = *(const bf16x8*)&As[row * 64 + c16 * 8];
            }
            #pragma unroll
            for (int n = 0; n < 4; ++n) {
                const int row = wc*64 + n*16 + lq;
                const int c16 = (ks*4 + lg) ^ (row & 7);
                bfr[n] = *(const bf16x8*)&Bs[row * 64 + c16 * 8];
            }
            #pragma unroll
            for (int m = 0; m < MF; ++m)
                #pragma unroll
                for (int n = 0; n < 4; ++n)
                    acc[m][n] = __builtin_amdgcn_mfma_f32_16x16x32_bf16(
                        af[m], bfr[n], acc[m][n], 0, 0, 0);
        }
    }

    #pragma unroll
    for (int m = 0; m < MF; ++m) {
        const int row0 = bm + wr*WM + m*16 + lg*4;
        #pragma unroll
        for (int n = 0; n < 4; ++n) {
            const int col = bn + wc*64 + n*16 + lq;
            const float bv = bias[col];
            float v[4];
            #pragma unroll
            for (int r = 0; r < 4; ++r) {
                v[r] = acc[m][n][r] + bv;
                if (EPI == 1 || EPI == 2) v[r] = fmaxf(v[r], 0.f);
            }
            if (EPI == 3) {
                const int part = col >> 9, hc = col & 511;
                const int hh = hc >> 6, d0 = hc & 63;
                const int bidx = row0 >> 11, nrow0 = row0 & 2047;
                if (part == 2) {
                    ushort4 pv;
                    pv.x = f2bf(v[0]); pv.y = f2bf(v[1]);
                    pv.z = f2bf(v[2]); pv.w = f2bf(v[3]);
                    *(ushort4*)(Vo + (((size_t)bidx*NH + hh)*DHEAD + d0)*SEQ + nrow0) = pv;
                } else {
                    ushort* dst = (part == 0) ? Qo : Ko;
                    #pragma unroll
                    for (int r = 0; r < 4; ++r)
                        dst[((((size_t)bidx*NH + hh)*SEQ + nrow0 + r) << 6) + d0] = f2bf(v[r]);
                }
            } else {
                #pragma unroll
                for (int r = 0; r < 4; ++r) {
                    const int row = row0 + r;
                    if (EPI == 1) Cb[(size_t)row * N + col] = f2bf(v[r]);
                    else          Cf[(size_t)row * N + col] = v[r];
                }
            }
        }
    }
}

// ---------------------------------------------------------------------------
// bf16 MFMA flash attention, v3: 2-way KV-split for occupancy.
// Grid: (512, 2). blockIdx.y = key-range half s; each block does 16 of 32
// 64-key chunks and writes UNNORMALIZED partial O plus per-row (m, l).
// ---------------------------------------------------------------------------
__global__ __launch_bounds__(256) void attn_mfma_k(
    const ushort* __restrict__ Qb, const ushort* __restrict__ Kb,
    const ushort* __restrict__ Vtb, const unsigned long long* __restrict__ mbits,
    float* __restrict__ Opart, float2* __restrict__ MLpart)
{
    __shared__ ushort Klds[2][64 * 64];   // [key][d], XOR-swizzled 16B chunks
    __shared__ ushort Vlds[2][64 * 64];   // [d][key], XOR-swizzled
    __shared__ ushort Plds[4][16 * 64];   // per-wave [q][key], XOR-swizzled

    const int tid  = threadIdx.x;
    const int wid  = tid >> 6;
    const int lane = tid & 63;
    const int lq   = lane & 15;
    const int lg   = lane >> 4;

    const int tile = blockIdx.x & 31;
    const int bh   = blockIdx.x >> 5;
    const int b    = bh >> 3;
    const int qw   = tile * 64 + wid * 16;
    const int s    = blockIdx.y;           // key-range half
    const int c0   = s * 16, c1 = c0 + 16; // chunk range

    const ushort* Qg = Qb + ((size_t)bh * SEQ + qw + lq) * DHEAD;
    const bf16x8 qf0 = *(const bf16x8*)(Qg + lg * 8);
    const bf16x8 qf1 = *(const bf16x8*)(Qg + 32 + lg * 8);

    const ushort* Kg = Kb  + (size_t)bh * SEQ * DHEAD;     // [key][d]
    const ushort* Vg = Vtb + (size_t)bh * DHEAD * SEQ;     // [d][key]

    const int srow0 = lane >> 3;
    const int sch   = lane & 7;

    const unsigned long long* mrow = mbits + ((size_t)b * SEQ + qw + lq) * (SEQ / 64);

    f32x4 o[4] = {};
    float mrun = -1e30f, lrun = 0.f;
    const float k2 = 0.125f * 1.44269504f;   // 1/sqrt(dh) * log2(e)

    auto STAGE = [&](int c, int buf) {
        #pragma unroll
        for (int i = 0; i < 2; ++i) {
            const int seg = wid * 2 + i;
            const int row = seg * 8 + srow0;
            const int gc  = sch ^ (row & 7);
            gload_lds16(Kg + (size_t)(c*64 + row) * DHEAD + gc * 8, &Klds[buf][seg * 512]);
            gload_lds16(Vg + (size_t)row * SEQ + c*64 + gc * 8, &Vlds[buf][seg * 512]);
        }
    };

    auto CHUNK = [&](int c, int cur) {
        if (c + 1 < c1) STAGE(c + 1, cur ^ 1);

        // QK^T: S^T tiles (16 keys x 16 q), d = 0..63
        f32x4 st[4];
        #pragma unroll
        for (int kt = 0; kt < 4; ++kt) {
            const int row = kt*16 + lq;
            bf16x8 kf0 = *(const bf16x8*)&Klds[cur][row*64 + ((lg  ) ^ (lq & 7))*8];
            bf16x8 kf1 = *(const bf16x8*)&Klds[cur][row*64 + ((4+lg) ^ (lq & 7))*8];
            f32x4 a = {};
            a = __builtin_amdgcn_mfma_f32_16x16x32_bf16(kf0, qf0, a, 0, 0, 0);
            a = __builtin_amdgcn_mfma_f32_16x16x32_bf16(kf1, qf1, a, 0, 0, 0);
            st[kt] = a;
        }

        // mask + scale (base-2 domain); single shift, then const extracts
        const unsigned long long mws = mrow[c] >> (lg * 4);
        const unsigned mlo = (unsigned)mws, mhi = (unsigned)(mws >> 32);
        float sv[16];
        float cmax = -1e30f;
        #pragma unroll
        for (int kt = 0; kt < 4; ++kt) {
            const unsigned half = (kt & 2) ? mhi : mlo;
            #pragma unroll
            for (int r = 0; r < 4; ++r) {
                const unsigned bit = (half >> ((kt & 1)*16 + r)) & 1u;
                const float sc = bit ? st[kt][r] * k2 : -1e9f;
                sv[kt*4 + r] = sc;
                cmax = fmaxf(cmax, sc);
            }
        }
        cmax = fmaxf(cmax, __shfl_xor(cmax, 16));
        cmax = fmaxf(cmax, __shfl_xor(cmax, 32));

        // exact defer-max: skip rescale when no row grew
        float mnew = mrun, scale = 1.0f;
        if (!__all(cmax <= mrun)) {
            mnew  = fmaxf(mrun, cmax);
            scale = exp2f(mrun - mnew);
            float sc[4];
            #pragma unroll
            for (int r = 0; r < 4; ++r) sc[r] = __shfl(scale, lg*4 + r);
            #pragma unroll
            for (int nt = 0; nt < 4; ++nt)
                #pragma unroll
                for (int r = 0; r < 4; ++r) o[nt][r] *= sc[r];
        }

        float lsum = 0.f;
        #pragma unroll
        for (int kt = 0; kt < 4; ++kt) {
            const float p0 = exp2f(sv[kt*4+0] - mnew);
            const float p1 = exp2f(sv[kt*4+1] - mnew);
            const float p2 = exp2f(sv[kt*4+2] - mnew);
            const float p3 = exp2f(sv[kt*4+3] - mnew);
            lsum += (p0 + p1) + (p2 + p3);
            uint2 pk;
            pk.x = cvtpk_bf16(p0, p1);
            pk.y = cvtpk_bf16(p2, p3);
            const int addr = lq*64 + (((kt*2 + (lg>>1)) ^ (lq & 7)) * 8) + (lg & 1)*4;
            *(uint2*)&Plds[wid][addr] = pk;
        }
        lsum += __shfl_xor(lsum, 16);
        lsum += __shfl_xor(lsum, 32);
        lrun = lrun * scale + lsum;
        mrun = mnew;

        // PV: O[q][d] += P[q][key] * V[key][d]
        #pragma unroll
        for (int kk = 0; kk < 2; ++kk) {
            const int ch = (kk*4 + lg) ^ (lq & 7);
            bf16x8 pf = *(const bf16x8*)&Plds[wid][lq*64 + ch*8];
            #pragma unroll
            for (int nt = 0; nt < 4; ++nt) {
                bf16x8 vf = *(const bf16x8*)&Vlds[cur][(nt*16 + lq)*64 + ch*8];
                o[nt] = __builtin_amdgcn_mfma_f32_16x16x32_bf16(pf, vf, o[nt], 0, 0, 0);
            }
        }

        __syncthreads();
    };

    STAGE(c0, 0);
    __syncthreads();
    for (int c = c0; c < c1; c += 2) {
        CHUNK(c, 0);
        CHUNK(c + 1, 1);
    }

    // partial epilogue: unnormalized O + (m, l)
    #pragma unroll
    for (int nt = 0; nt < 4; ++nt)
        #pragma unroll
        for (int r = 0; r < 4; ++r) {
            const int qrow = qw + lg*4 + r;
            Opart[(((size_t)s*16 + bh)*SEQ + qrow)*64 + nt*16 + lq] = o[nt][r];
        }
    if (lg == 0) {
        float2 ml; ml.x = mrun; ml.y = lrun;
        MLpart[((size_t)s*16 + bh)*SEQ + qw + lq] = ml;
    }
}

// ---------------------------------------------------------------------------
// Combine the two KV-split halves (exact log-sum-exp merge, base-2 domain).
// ---------------------------------------------------------------------------
__global__ __launch_bounds__(256) void attn_combine_k(
    const float* __restrict__ Op, const float2* __restrict__ ML,
    ushort* __restrict__ attnb)
{
    const int row  = blockIdx.x * 4 + (threadIdx.x >> 6);  // bh*SEQ + q
    const int lane = threadIdx.x & 63;
    const int bh = row >> 11, q = row & 2047;
    const int b = bh >> 3, h = bh & 7;
    const float2 ml0 = ML[row];
    const float2 ml1 = ML[16*SEQ + row];
    const float m  = fmaxf(ml0.x, ml1.x);
    const float a0 = exp2f(ml0.x - m), a1 = exp2f(ml1.x - m);
    const float l  = ml0.y*a0 + ml1.y*a1;
    const float o0 = Op[(size_t)row*64 + lane];
    const float o1 = Op[((size_t)16*SEQ + row)*64 + lane];
    const float o  = (o0*a0 + o1*a1) / l;
    attnb[((size_t)(b*SEQ + q))*DMODEL + h*DHEAD + lane] = f2bf(o);
}

// ---------------------------------------------------------------------------
// out = LayerNorm(X + A)*g + b over DMODEL=512; optional bf16 copy.
// ---------------------------------------------------------------------------
__global__ __launch_bounds__(256) void add_ln_k(
    const float* __restrict__ X, const float* __restrict__ Aa,
    const float* __restrict__ gg, const float* __restrict__ bb,
    float* __restrict__ out, ushort* __restrict__ outb)
{
    const int r = blockIdx.x;
    const int t = threadIdx.x;
    const float2 x2 = ((const float2*)(X  + (size_t)r * DMODEL))[t];
    const float2 a2 = ((const float2*)(Aa + (size_t)r * DMODEL))[t];
    const float v0 = x2.x + a2.x, v1 = x2.y + a2.y;
    float s  = v0 + v1;
    float ss = v0*v0 + v1*v1;
    #pragma unroll
    for (int off = 32; off > 0; off >>= 1) {
        s  += __shfl_down(s,  off);
        ss += __shfl_down(ss, off);
    }
    __shared__ float ps[4], pss[4];
    const int wid = t >> 6;
    if ((t & 63) == 0) { ps[wid] = s; pss[wid] = ss; }
    __syncthreads();
    const float tot  = ps[0] + ps[1] + ps[2] + ps[3];
    const float tots = pss[0] + pss[1] + pss[2] + pss[3];
    const float mean = tot * (1.0f / DMODEL);
    const float var  = tots * (1.0f / DMODEL) - mean * mean;
    const float rstd = rsqrtf(var + 1e-5f);
    const float2 g2 = ((const float2*)gg)[t];
    const float2 b2 = ((const float2*)bb)[t];
    float2 r2;
    r2.x = (v0 - mean) * rstd * g2.x + b2.x;
    r2.y = (v1 - mean) * rstd * g2.y + b2.y;
    ((float2*)(out + (size_t)r * DMODEL))[t] = r2;
    if (outb) {
        ushort2 ob; ob.x = f2bf(r2.x); ob.y = f2bf(r2.y);
        *(ushort2*)(outb + (size_t)r * DMODEL + t*2) = ob;
    }
}

// ---------------------------------------------------------------------------
extern "C" void kernel_launch(void* const* d_in, const int* in_sizes, int n_in,
                              void* d_out, int out_size, void* d_ws, size_t ws_size,
                              hipStream_t stream)
{
    const float* x      = (const float*)d_in[0];
    const void*  mask   = d_in[1];
    const float* W_qkv  = (const float*)d_in[2];
    const float* b_qkv  = (const float*)d_in[3];
    const float* W_proj = (const float*)d_in[4];
    const float* b_proj = (const float*)d_in[5];
    const float* ln1_g  = (const float*)d_in[6];
    const float* ln1_b  = (const float*)d_in[7];
    const float* W1     = (const float*)d_in[8];
    const float* b1     = (const float*)d_in[9];
    const float* W2     = (const float*)d_in[10];
    const float* b2     = (const float*)d_in[11];
    const float* ln2_g  = (const float*)d_in[12];
    const float* ln2_b  = (const float*)d_in[13];

    float* ws = (float*)d_ws;
    // Workspace (float-element offsets; SZ = 2,097,152):
    //  [0,   0.5) xb bf16           \
    //  [0.5, 2.0) Qb,Kb,Vtb bf16     } hb bf16 [0,2.0) in MLP phase
    //  [2.0, 2.5) attnb bf16
    //  [2.5, 4.5) Opart f32 (attn phase) / ap f32 [2.5,3.5) + x1 f32 [3.5,4.5)
    //  [4.5, 5.0) MLpart (attn) / x1b bf16
    //  mbuf f32 overlays [2.0,3.0) in MLP phase
    //  [5.0, ...) WqkvT, WprojT, W1T, W2T bf16; bits; flag
    ushort* xb    = (ushort*)ws;
    ushort* Qb    = (ushort*)(ws + SZ/2);
    ushort* Kb    = (ushort*)(ws + SZ);
    ushort* Vtb   = (ushort*)(ws + SZ + SZ/2);   // [B,H,DHEAD,SEQ]
    ushort* attnb = (ushort*)(ws + 2*SZ);
    float*  Opart = ws + 2*SZ + SZ/2;            // [2][16][SEQ][64] f32 = 2*SZ
    float2* MLp   = (float2*)(ws + 4*SZ + SZ/2); // [2][16][SEQ]
    float*  ap    = ws + 2*SZ + SZ/2;
    float*  mbuf  = ws + 2*SZ;
    float*  x1    = ws + 3*SZ + SZ/2;
    ushort* x1b   = (ushort*)(ws + 4*SZ + SZ/2);
    ushort* hb    = (ushort*)ws;
    ushort* WqkvT = (ushort*)(ws + 5*SZ);                    // 512*1536
    ushort* WprojT= (ushort*)(ws + 5*SZ + 393216);           // 512*512
    ushort* W1T   = (ushort*)(ws + 5*SZ + 524288);           // 2048*512
    ushort* W2T   = (ushort*)(ws + 5*SZ + 1048576);          // 512*2048
    unsigned long long* bits = (unsigned long long*)(ws + 5*SZ + 1572864);
    int*    flag  = (int*)(ws + 5*SZ + 1572864 + 262144);

    float* out = (float*)d_out;

    // flag = 0, then parallel detect (atomicOr), then fused prep.
    hipMemsetAsync(flag, 0, 4, stream);
    detect_mask_k<<<64, 256, 0, stream>>>((const uint4*)mask, flag);
    prep_all_k<<<2816 + 32768, 256, 0, stream>>>(
        x, xb, W_qkv, W_proj, W1, W2, WqkvT, WprojT, W1T, W2T,
        mask, flag, bits);

    // QKV: [4096,512]@[512,1536] -> bf16 Q/K (row) + V (transposed)
    mgemm_k<3,128><<<dim3(12, 32), 256, 0, stream>>>(xb, WqkvT, b_qkv,
        nullptr, nullptr, Qb, Kb, Vtb, ROWS, 3*DMODEL, DMODEL);
    // attention partials (2-way KV split) -> combine -> attnb bf16
    attn_mfma_k<<<dim3(BATCH*NH*(SEQ/64), 2), 256, 0, stream>>>(
        Qb, Kb, Vtb, bits, Opart, MLp);
    attn_combine_k<<<BATCH*NH*SEQ/4, 256, 0, stream>>>(Opart, MLp, attnb);
    // proj: [4096,512]@[512,512] -> ap f32
    mgemm_k<0,64><<<dim3(4, 64), 256, 0, stream>>>(attnb, WprojT, b_proj,
        ap, nullptr, nullptr, nullptr, nullptr, ROWS, DMODEL, DMODEL);
    // x1 = LN(x + ap)  (+ bf16 copy)
    add_ln_k<<<ROWS, 256, 0, stream>>>(x, ap, ln1_g, ln1_b, x1, x1b);
    // MLP1: relu([4096,512]@[512,2048]) -> bf16 hb
    mgemm_k<1,128><<<dim3(16, 32), 256, 0, stream>>>(x1b, W1T, b1,
        nullptr, hb, nullptr, nullptr, nullptr, ROWS, 2048, DMODEL);
    // MLP2: relu([4096,2048]@[2048,512]) -> f32 mbuf
    mgemm_k<2,64><<<dim3(4, 64), 256, 0, stream>>>(hb, W2T, b2,
        mbuf, nullptr, nullptr, nullptr, nullptr, ROWS, DMODEL, 2048);
    // out = LN(x1 + mbuf)
    add_ln_k<<<ROWS, 256, 0, stream>>>(x1, mbuf, ln2_g, ln2_b, out, nullptr);
}

// Round 7
// 171.958 us; speedup vs baseline: 6.6110x; 1.0134x over previous
//
#include <hip/hip_runtime.h>
#include <math.h>

// Problem constants
constexpr int BATCH  = 2;
constexpr int SEQ    = 2048;
constexpr int DMODEL = 512;
constexpr int NH     = 8;
constexpr int DHEAD  = 64;
constexpr int ROWS   = BATCH * SEQ;           // 4096
constexpr size_t SZ  = (size_t)ROWS * DMODEL; // elems of one [4096][512] buffer

typedef __attribute__((ext_vector_type(8))) short bf16x8;
typedef __attribute__((ext_vector_type(4))) float f32x4;

__device__ __forceinline__ ushort f2bf(float f) {
    unsigned u = __float_as_uint(f);
    unsigned r = (u + 0x7FFFu + ((u >> 16) & 1u)) >> 16;
    return (ushort)r;
}

// pack 2 f32 -> 2 bf16 (RNE) in one instruction
__device__ __forceinline__ unsigned cvtpk_bf16(float lo, float hi) {
    unsigned r;
    asm("v_cvt_pk_bf16_f32 %0, %1, %2" : "=v"(r) : "v"(lo), "v"(hi));
    return r;
}

__device__ __forceinline__ void gload_lds16(const void* g, void* l) {
    __builtin_amdgcn_global_load_lds(
        (const __attribute__((address_space(1))) void*)g,
        (__attribute__((address_space(3))) void*)l, 16, 0, 0);
}

// ---------------------------------------------------------------------------
// Mask-encoding detector, parallel. flag MUST be zeroed before launch.
// ---------------------------------------------------------------------------
__global__ __launch_bounds__(256) void detect_mask_k(
    const uint4* __restrict__ m, int* __restrict__ flag)
{
    const int i = blockIdx.x * 256 + threadIdx.x;
    const uint4 v = m[i];
    unsigned b0 = 0, b1 = 0;
    #pragma unroll
    for (int c = 0; c < 4; ++c) {
        const unsigned u = (&v.x)[c];
        b0 |= (u > 1u) ? 1u : 0u;
        b1 |= (u != 0u && u != 0x3F800000u) ? 1u : 0u;
    }
    const int lane = threadIdx.x & 63;
    if (__any(b0) && lane == 0) atomicOr(flag, 1);
    if (__any(b1) && lane == 0) atomicOr(flag, 2);
}

// ---------------------------------------------------------------------------
// Fused prep: [0,2048) x f32->bf16 conv | [2048,2816) weight transpose+conv
//             [2816, 2816+32768) mask bitmask compaction
// ---------------------------------------------------------------------------
__global__ __launch_bounds__(256) void prep_all_k(
    const float* __restrict__ x, ushort* __restrict__ xb,
    const float* __restrict__ Wq, const float* __restrict__ Wp,
    const float* __restrict__ W1w, const float* __restrict__ W2w,
    ushort* __restrict__ WqT, ushort* __restrict__ WpT,
    ushort* __restrict__ W1T, ushort* __restrict__ W2T,
    const void* __restrict__ maskp, const int* __restrict__ flagp,
    unsigned long long* __restrict__ bits)
{
    __shared__ ushort T[64][65];
    const int bid = blockIdx.x;
    const int t = threadIdx.x;

    if (bid < 2048) {           // x f32 -> bf16
        const size_t i = ((size_t)bid * 256 + t) * 4;
        float4 v = *(const float4*)(x + i);
        ushort4 o;
        o.x = f2bf(v.x); o.y = f2bf(v.y); o.z = f2bf(v.z); o.w = f2bf(v.w);
        *(ushort4*)(xb + i) = o;
        return;
    }
    if (bid >= 2816) {          // mask -> bitmask
        const int w = (bid - 2816) * 4 + (t >> 6);
        const int lane = t & 63;
        const size_t idx = ((size_t)w << 6) + lane;
        const int f = *flagp;
        bool mv;
        if (!(f & 1))      mv = ((const int*)maskp)[idx] != 0;
        else if (!(f & 2)) mv = ((const float*)maskp)[idx] != 0.f;
        else               mv = ((const unsigned char*)maskp)[idx] != 0;
        unsigned long long bal = __ballot(mv);
        if (lane == 0) bits[w] = bal;
        return;
    }
    // weight transpose+convert, 64x64 tiles
    const int wb = bid - 2048;
    const float* W; ushort* Wt; int K, N, tix, tiy;
    if (wb < 192)      { W = Wq;  Wt = WqT; K = 512;  N = 1536; tix = wb % 24;        tiy = wb / 24; }
    else if (wb < 256) { W = Wp;  Wt = WpT; K = 512;  N = 512;  tix = (wb-192) % 8;   tiy = (wb-192) / 8; }
    else if (wb < 512) { W = W1w; Wt = W1T; K = 512;  N = 2048; tix = (wb-256) % 32;  tiy = (wb-256) / 32; }
    else               { W = W2w; Wt = W2T; K = 2048; N = 512;  tix = (wb-512) % 8;   tiy = (wb-512) / 8; }
    const int k0 = tiy * 64, n0 = tix * 64;
    const int r = t >> 4, c4 = (t & 15) * 4;
    #pragma unroll
    for (int it = 0; it < 4; ++it) {
        const int row = it*16 + r;
        float4 v = *(const float4*)&W[(size_t)(k0 + row) * N + n0 + c4];
        T[c4+0][row] = f2bf(v.x);
        T[c4+1][row] = f2bf(v.y);
        T[c4+2][row] = f2bf(v.z);
        T[c4+3][row] = f2bf(v.w);
    }
    __syncthreads();
    #pragma unroll
    for (int it = 0; it < 4; ++it) {
        const int row = it*16 + r;
        ushort4 o;
        o.x = T[row][c4+0]; o.y = T[row][c4+1];
        o.z = T[row][c4+2]; o.w = T[row][c4+3];
        *(ushort4*)&Wt[(size_t)(n0 + row) * K + k0 + c4] = o;
    }
}

// ---------------------------------------------------------------------------
// bf16 MFMA GEMM (m97 structure): C[M,N] = A[M,K] @ Wt[N,K]^T + bias.
// ---------------------------------------------------------------------------
template<int EPI, int BM>
__global__ __launch_bounds__(256) void mgemm_k(
    const ushort* __restrict__ A,   // [M][K] bf16
    const ushort* __restrict__ Wt,  // [N][K] bf16
    const float* __restrict__ bias, // [N] f32
    float* __restrict__ Cf, ushort* __restrict__ Cb,
    ushort* __restrict__ Qo, ushort* __restrict__ Ko, ushort* __restrict__ Vo,
    int M, int N, int K)
{
    constexpr int WM   = BM / 2;
    constexpr int MF   = WM / 16;
    constexpr int APW  = (BM / 8) / 4;

    __shared__ ushort As[BM * 64];
    __shared__ ushort Bs[128 * 64];

    const int tid  = threadIdx.x;
    const int wid  = tid >> 6, lane = tid & 63;
    const int lq   = lane & 15, lg = lane >> 4;
    const int wr   = wid >> 1,  wc = wid & 1;
    const int bm   = blockIdx.y * BM, bn = blockIdx.x * 128;

    const int srow0 = lane >> 3;
    const int sch   = lane & 7;

    f32x4 acc[MF][4] = {};

    for (int k0 = 0; k0 < K; k0 += 64) {
        __syncthreads();
        #pragma unroll
        for (int i = 0; i < APW; ++i) {
            const int seg = wid * APW + i;
            const int row = seg * 8 + srow0;
            const int c16 = sch ^ (row & 7);
            gload_lds16(A + (size_t)(bm + row) * K + k0 + c16 * 8, As + seg * 512);
        }
        #pragma unroll
        for (int i = 0; i < 4; ++i) {
            const int seg = wid * 4 + i;
            const int row = seg * 8 + srow0;
            const int c16 = sch ^ (row & 7);
            gload_lds16(Wt + (size_t)(bn + row) * K + k0 + c16 * 8, Bs + seg * 512);
        }
        __syncthreads();

        #pragma unroll
        for (int ks = 0; ks < 2; ++ks) {
            bf16x8 af[MF], bfr[4];
            #pragma unroll
            for (int m = 0; m < MF; ++m) {
                const int row = wr*WM + m*16 + lq;
                const int c16 = (ks*4 + lg) ^ (row & 7);
                af[m] = *(const bf16x8*)&As[row * 64 + c16 * 8];
            }
            #pragma unroll
            for (int n = 0; n < 4; ++n) {
                const int row = wc*64 + n*16 + lq;
                const int c16 = (ks*4 + lg) ^ (row & 7);
                bfr[n] = *(const bf16x8*)&Bs[row * 64 + c16 * 8];
            }
            #pragma unroll
            for (int m = 0; m < MF; ++m)
                #pragma unroll
                for (int n = 0; n < 4; ++n)
                    acc[m][n] = __builtin_amdgcn_mfma_f32_16x16x32_bf16(
                        af[m], bfr[n], acc[m][n], 0, 0, 0);
        }
    }

    #pragma unroll
    for (int m = 0; m < MF; ++m) {
        const int row0 = bm + wr*WM + m*16 + lg*4;
        #pragma unroll
        for (int n = 0; n < 4; ++n) {
            const int col = bn + wc*64 + n*16 + lq;
            const float bv = bias[col];
            float v[4];
            #pragma unroll
            for (int r = 0; r < 4; ++r) {
                v[r] = acc[m][n][r] + bv;
                if (EPI == 1 || EPI == 2) v[r] = fmaxf(v[r], 0.f);
            }
            if (EPI == 3) {
                const int part = col >> 9, hc = col & 511;
                const int hh = hc >> 6, d0 = hc & 63;
                const int bidx = row0 >> 11, nrow0 = row0 & 2047;
                if (part == 2) {
                    ushort4 pv;
                    pv.x = f2bf(v[0]); pv.y = f2bf(v[1]);
                    pv.z = f2bf(v[2]); pv.w = f2bf(v[3]);
                    *(ushort4*)(Vo + (((size_t)bidx*NH + hh)*DHEAD + d0)*SEQ + nrow0) = pv;
                } else {
                    ushort* dst = (part == 0) ? Qo : Ko;
                    #pragma unroll
                    for (int r = 0; r < 4; ++r)
                        dst[((((size_t)bidx*NH + hh)*SEQ + nrow0 + r) << 6) + d0] = f2bf(v[r]);
                }
            } else {
                #pragma unroll
                for (int r = 0; r < 4; ++r) {
                    const int row = row0 + r;
                    if (EPI == 1) Cb[(size_t)row * N + col] = f2bf(v[r]);
                    else          Cf[(size_t)row * N + col] = v[r];
                }
            }
        }
    }
}

// ---------------------------------------------------------------------------
// bf16 MFMA flash attention, v4: hoisted swizzled addresses + VGPR headroom.
// Grid: (512, 2) KV-split. 4 waves; wave owns 16 q rows; chunk = 64 keys.
// __launch_bounds__(256,4): 4 waves/EU = 16 waves/CU (our 4 blocks x 4 waves),
// VGPR cap 128 so the ~22 swizzled LDS offsets + staging pointers stay live
// (at the default cap=64 the compiler rematerialized them every chunk).
// ---------------------------------------------------------------------------
__global__ __launch_bounds__(256, 4) void attn_mfma_k(
    const ushort* __restrict__ Qb, const ushort* __restrict__ Kb,
    const ushort* __restrict__ Vtb, const unsigned long long* __restrict__ mbits,
    float* __restrict__ Opart, float2* __restrict__ MLpart)
{
    __shared__ ushort Klds[2][64 * 64];   // [key][d], XOR-swizzled 16B chunks
    __shared__ ushort Vlds[2][64 * 64];   // [d][key], XOR-swizzled
    __shared__ ushort Plds[4][16 * 64];   // per-wave [q][key], XOR-swizzled

    const int tid  = threadIdx.x;
    const int wid  = tid >> 6;
    const int lane = tid & 63;
    const int lq   = lane & 15;
    const int lg   = lane >> 4;

    const int tile = blockIdx.x & 31;
    const int bh   = blockIdx.x >> 5;
    const int b    = bh >> 3;
    const int qw   = tile * 64 + wid * 16;
    const int s    = blockIdx.y;           // key-range half
    const int c0   = s * 16, c1 = c0 + 16; // chunk range

    // hoisted Q fragments (B-operand)
    const ushort* Qg = Qb + ((size_t)bh * SEQ + qw + lq) * DHEAD;
    const bf16x8 qf0 = *(const bf16x8*)(Qg + lg * 8);
    const bf16x8 qf1 = *(const bf16x8*)(Qg + 32 + lg * 8);

    const int srow0 = lane >> 3;              // 0..7 (== row&7 for all segs)
    const int sch   = lane & 7;
    const int gc8   = (sch ^ srow0) * 8;      // inverse-swizzled global col

    // per-thread global staging bases (K: [key][d] rows, V: [d][key] rows)
    const ushort* kgb  = Kb  + (size_t)bh * SEQ * DHEAD
                             + (size_t)(wid*16 + srow0) * DHEAD + gc8;
    const ushort* vgb0 = Vtb + (size_t)bh * DHEAD * SEQ
                             + (size_t)(wid*16 + srow0) * SEQ + gc8;
    const ushort* vgb1 = vgb0 + 8 * SEQ;      // i=1 segment (+8 d-rows)

    // LDS staging destinations (wave's two 512-ushort segments per buffer)
    ushort* kd0 = &Klds[0][(wid*2)*512];
    ushort* kd1 = &Klds[1][(wid*2)*512];
    ushort* vd0 = &Vlds[0][(wid*2)*512];
    ushort* vd1 = &Vlds[1][(wid*2)*512];

    // hoisted LDS BYTE offsets (loop-invariant; buffer base folds into imm)
    int kro[4][2], vro[4][2], pwo[4], pro[2];
    #pragma unroll
    for (int kt = 0; kt < 4; ++kt) {
        kro[kt][0] = ((kt*16 + lq)*64 + ((lg     ^ (lq&7))*8)) * 2;
        kro[kt][1] = ((kt*16 + lq)*64 + (((4+lg) ^ (lq&7))*8)) * 2;
        pwo[kt]    = (wid*1024 + lq*64 + (((kt*2 + (lg>>1)) ^ (lq&7))*8) + (lg&1)*4) * 2;
    }
    #pragma unroll
    for (int kk = 0; kk < 2; ++kk) {
        pro[kk] = (wid*1024 + lq*64 + (((kk*4+lg) ^ (lq&7))*8)) * 2;
        #pragma unroll
        for (int nt = 0; nt < 4; ++nt)
            vro[nt][kk] = ((nt*16 + lq)*64 + (((kk*4+lg) ^ (lq&7))*8)) * 2;
    }
    const char* kbase0 = (const char*)&Klds[0][0];
    const char* kbase1 = (const char*)&Klds[1][0];
    const char* vbase0 = (const char*)&Vlds[0][0];
    const char* vbase1 = (const char*)&Vlds[1][0];
    char*       pbase  = (char*)&Plds[0][0];

    const unsigned long long* mrow = mbits + ((size_t)b * SEQ + qw + lq) * (SEQ / 64);

    f32x4 o[4] = {};
    float mrun = -1e30f, lrun = 0.f;
    const float k2 = 0.125f * 1.44269504f;   // 1/sqrt(dh) * log2(e)

    // stage chunk c0 into buf 0
    {
        const ushort* kp0  = kgb  + (size_t)c0 * 4096;   // 64 keys * DHEAD
        const ushort* vq0  = vgb0 + c0 * 64;
        const ushort* vq1  = vgb1 + c0 * 64;
        gload_lds16(kp0,       kd0);
        gload_lds16(kp0 + 512, kd0 + 512);
        gload_lds16(vq0, vd0);
        gload_lds16(vq1, vd0 + 512);
    }
    // pointers for the NEXT chunk to stage
    const ushort* kp  = kgb  + (size_t)(c0 + 1) * 4096;
    const ushort* vp0 = vgb0 + (c0 + 1) * 64;
    const ushort* vp1 = vgb1 + (c0 + 1) * 64;
    __syncthreads();

#define ATTN_CHUNK(CC, KD, VD, KBASE, VBASE)                                   \
    {                                                                          \
        if ((CC) + 1 < c1) {                                                   \
            gload_lds16(kp,       (KD));                                       \
            gload_lds16(kp + 512, (KD) + 512);                                 \
            gload_lds16(vp0, (VD));                                            \
            gload_lds16(vp1, (VD) + 512);                                      \
            kp += 4096; vp0 += 64; vp1 += 64;                                  \
        }                                                                      \
        f32x4 st[4];                                                           \
        __builtin_amdgcn_s_setprio(1);                                         \
        _Pragma("unroll")                                                      \
        for (int kt = 0; kt < 4; ++kt) {                                       \
            bf16x8 kf0 = *(const bf16x8*)((KBASE) + kro[kt][0]);               \
            bf16x8 kf1 = *(const bf16x8*)((KBASE) + kro[kt][1]);               \
            f32x4 a = {};                                                      \
            a = __builtin_amdgcn_mfma_f32_16x16x32_bf16(kf0, qf0, a, 0, 0, 0); \
            a = __builtin_amdgcn_mfma_f32_16x16x32_bf16(kf1, qf1, a, 0, 0, 0); \
            st[kt] = a;                                                        \
        }                                                                      \
        __builtin_amdgcn_s_setprio(0);                                         \
        const unsigned long long mws = mrow[CC] >> (lg * 4);                   \
        const unsigned mlo = (unsigned)mws, mhi = (unsigned)(mws >> 32);       \
        float sv[16];                                                          \
        _Pragma("unroll")                                                      \
        for (int kt = 0; kt < 4; ++kt) {                                       \
            const unsigned half = (kt & 2) ? mhi : mlo;                        \
            _Pragma("unroll")                                                  \
            for (int r = 0; r < 4; ++r) {                                      \
                const unsigned bit = (half >> ((kt & 1)*16 + r)) & 1u;         \
                sv[kt*4 + r] = bit ? st[kt][r] * k2 : -1e9f;                   \
            }                                                                  \
        }                                                                      \
        float cmax = fmaxf(                                                    \
            fmaxf(fmaxf(fmaxf(sv[0],sv[1]),fmaxf(sv[2],sv[3])),                \
                  fmaxf(fmaxf(sv[4],sv[5]),fmaxf(sv[6],sv[7]))),               \
            fmaxf(fmaxf(fmaxf(sv[8],sv[9]),fmaxf(sv[10],sv[11])),              \
                  fmaxf(fmaxf(sv[12],sv[13]),fmaxf(sv[14],sv[15]))));          \
        cmax = fmaxf(cmax, __shfl_xor(cmax, 16));                              \
        cmax = fmaxf(cmax, __shfl_xor(cmax, 32));                              \
        float mnew = mrun, scale = 1.0f;                                       \
        if (!__all(cmax <= mrun)) {                                            \
            mnew  = fmaxf(mrun, cmax);                                         \
            scale = exp2f(mrun - mnew);                                        \
            float sc[4];                                                       \
            _Pragma("unroll")                                                  \
            for (int r = 0; r < 4; ++r) sc[r] = __shfl(scale, lg*4 + r);       \
            _Pragma("unroll")                                                  \
            for (int nt = 0; nt < 4; ++nt)                                     \
                _Pragma("unroll")                                              \
                for (int r = 0; r < 4; ++r) o[nt][r] *= sc[r];                 \
        }                                                                      \
        float ls[4];                                                           \
        _Pragma("unroll")                                                      \
        for (int kt = 0; kt < 4; ++kt) {                                       \
            const float p0 = exp2f(sv[kt*4+0] - mnew);                         \
            const float p1 = exp2f(sv[kt*4+1] - mnew);                         \
            const float p2 = exp2f(sv[kt*4+2] - mnew);                         \
            const float p3 = exp2f(sv[kt*4+3] - mnew);                         \
            ls[kt] = (p0 + p1) + (p2 + p3);                                    \
            uint2 pk;                                                          \
            pk.x = cvtpk_bf16(p0, p1);                                         \
            pk.y = cvtpk_bf16(p2, p3);                                         \
            *(uint2*)(pbase + pwo[kt]) = pk;                                   \
        }                                                                      \
        float lsum = (ls[0] + ls[1]) + (ls[2] + ls[3]);                        \
        lsum += __shfl_xor(lsum, 16);                                          \
        lsum += __shfl_xor(lsum, 32);                                          \
        lrun = lrun * scale + lsum;                                            \
        mrun = mnew;                                                           \
        __builtin_amdgcn_s_setprio(1);                                         \
        _Pragma("unroll")                                                      \
        for (int kk = 0; kk < 2; ++kk) {                                       \
            bf16x8 pf = *(const bf16x8*)(pbase + pro[kk]);                     \
            _Pragma("unroll")                                                  \
            for (int nt = 0; nt < 4; ++nt) {                                   \
                bf16x8 vf = *(const bf16x8*)((VBASE) + vro[nt][kk]);           \
                o[nt] = __builtin_amdgcn_mfma_f32_16x16x32_bf16(               \
                    pf, vf, o[nt], 0, 0, 0);                                   \
            }                                                                  \
        }                                                                      \
        __builtin_amdgcn_s_setprio(0);                                         \
        __syncthreads();                                                       \
    }

    for (int c = c0; c < c1; c += 2) {
        ATTN_CHUNK(c,     kd1, vd1, kbase0, vbase0);   // compute buf0, stage buf1
        ATTN_CHUNK(c + 1, kd0, vd0, kbase1, vbase1);   // compute buf1, stage buf0
    }
#undef ATTN_CHUNK

    // partial epilogue: unnormalized O + (m, l)
    #pragma unroll
    for (int nt = 0; nt < 4; ++nt)
        #pragma unroll
        for (int r = 0; r < 4; ++r) {
            const int qrow = qw + lg*4 + r;
            Opart[(((size_t)s*16 + bh)*SEQ + qrow)*64 + nt*16 + lq] = o[nt][r];
        }
    if (lg == 0) {
        float2 ml; ml.x = mrun; ml.y = lrun;
        MLpart[((size_t)s*16 + bh)*SEQ + qw + lq] = ml;
    }
}

// ---------------------------------------------------------------------------
// Combine the two KV-split halves (exact log-sum-exp merge, base-2 domain).
// ---------------------------------------------------------------------------
__global__ __launch_bounds__(256) void attn_combine_k(
    const float* __restrict__ Op, const float2* __restrict__ ML,
    ushort* __restrict__ attnb)
{
    const int row  = blockIdx.x * 4 + (threadIdx.x >> 6);  // bh*SEQ + q
    const int lane = threadIdx.x & 63;
    const int bh = row >> 11, q = row & 2047;
    const int b = bh >> 3, h = bh & 7;
    const float2 ml0 = ML[row];
    const float2 ml1 = ML[16*SEQ + row];
    const float m  = fmaxf(ml0.x, ml1.x);
    const float a0 = exp2f(ml0.x - m), a1 = exp2f(ml1.x - m);
    const float l  = ml0.y*a0 + ml1.y*a1;
    const float o0 = Op[(size_t)row*64 + lane];
    const float o1 = Op[((size_t)16*SEQ + row)*64 + lane];
    const float o  = (o0*a0 + o1*a1) / l;
    attnb[((size_t)(b*SEQ + q))*DMODEL + h*DHEAD + lane] = f2bf(o);
}

// ---------------------------------------------------------------------------
// out = LayerNorm(X + A)*g + b over DMODEL=512; optional bf16 copy.
// ---------------------------------------------------------------------------
__global__ __launch_bounds__(256) void add_ln_k(
    const float* __restrict__ X, const float* __restrict__ Aa,
    const float* __restrict__ gg, const float* __restrict__ bb,
    float* __restrict__ out, ushort* __restrict__ outb)
{
    const int r = blockIdx.x;
    const int t = threadIdx.x;
    const float2 x2 = ((const float2*)(X  + (size_t)r * DMODEL))[t];
    const float2 a2 = ((const float2*)(Aa + (size_t)r * DMODEL))[t];
    const float v0 = x2.x + a2.x, v1 = x2.y + a2.y;
    float s  = v0 + v1;
    float ss = v0*v0 + v1*v1;
    #pragma unroll
    for (int off = 32; off > 0; off >>= 1) {
        s  += __shfl_down(s,  off);
        ss += __shfl_down(ss, off);
    }
    __shared__ float ps[4], pss[4];
    const int wid = t >> 6;
    if ((t & 63) == 0) { ps[wid] = s; pss[wid] = ss; }
    __syncthreads();
    const float tot  = ps[0] + ps[1] + ps[2] + ps[3];
    const float tots = pss[0] + pss[1] + pss[2] + pss[3];
    const float mean = tot * (1.0f / DMODEL);
    const float var  = tots * (1.0f / DMODEL) - mean * mean;
    const float rstd = rsqrtf(var + 1e-5f);
    const float2 g2 = ((const float2*)gg)[t];
    const float2 b2 = ((const float2*)bb)[t];
    float2 r2;
    r2.x = (v0 - mean) * rstd * g2.x + b2.x;
    r2.y = (v1 - mean) * rstd * g2.y + b2.y;
    ((float2*)(out + (size_t)r * DMODEL))[t] = r2;
    if (outb) {
        ushort2 ob; ob.x = f2bf(r2.x); ob.y = f2bf(r2.y);
        *(ushort2*)(outb + (size_t)r * DMODEL + t*2) = ob;
    }
}

// ---------------------------------------------------------------------------
extern "C" void kernel_launch(void* const* d_in, const int* in_sizes, int n_in,
                              void* d_out, int out_size, void* d_ws, size_t ws_size,
                              hipStream_t stream)
{
    const float* x      = (const float*)d_in[0];
    const void*  mask   = d_in[1];
    const float* W_qkv  = (const float*)d_in[2];
    const float* b_qkv  = (const float*)d_in[3];
    const float* W_proj = (const float*)d_in[4];
    const float* b_proj = (const float*)d_in[5];
    const float* ln1_g  = (const float*)d_in[6];
    const float* ln1_b  = (const float*)d_in[7];
    const float* W1     = (const float*)d_in[8];
    const float* b1     = (const float*)d_in[9];
    const float* W2     = (const float*)d_in[10];
    const float* b2     = (const float*)d_in[11];
    const float* ln2_g  = (const float*)d_in[12];
    const float* ln2_b  = (const float*)d_in[13];

    float* ws = (float*)d_ws;
    ushort* xb    = (ushort*)ws;
    ushort* Qb    = (ushort*)(ws + SZ/2);
    ushort* Kb    = (ushort*)(ws + SZ);
    ushort* Vtb   = (ushort*)(ws + SZ + SZ/2);   // [B,H,DHEAD,SEQ]
    ushort* attnb = (ushort*)(ws + 2*SZ);
    float*  Opart = ws + 2*SZ + SZ/2;            // [2][16][SEQ][64] f32 = 2*SZ
    float2* MLp   = (float2*)(ws + 4*SZ + SZ/2); // [2][16][SEQ]
    float*  ap    = ws + 2*SZ + SZ/2;
    float*  mbuf  = ws + 2*SZ;
    float*  x1    = ws + 3*SZ + SZ/2;
    ushort* x1b   = (ushort*)(ws + 4*SZ + SZ/2);
    ushort* hb    = (ushort*)ws;
    ushort* WqkvT = (ushort*)(ws + 5*SZ);                    // 512*1536
    ushort* WprojT= (ushort*)(ws + 5*SZ + 393216);           // 512*512
    ushort* W1T   = (ushort*)(ws + 5*SZ + 524288);           // 2048*512
    ushort* W2T   = (ushort*)(ws + 5*SZ + 1048576);          // 512*2048
    unsigned long long* bits = (unsigned long long*)(ws + 5*SZ + 1572864);
    int*    flag  = (int*)(ws + 5*SZ + 1572864 + 262144);

    float* out = (float*)d_out;

    hipMemsetAsync(flag, 0, 4, stream);
    detect_mask_k<<<64, 256, 0, stream>>>((const uint4*)mask, flag);
    prep_all_k<<<2816 + 32768, 256, 0, stream>>>(
        x, xb, W_qkv, W_proj, W1, W2, WqkvT, WprojT, W1T, W2T,
        mask, flag, bits);

    // QKV: [4096,512]@[512,1536] -> bf16 Q/K (row) + V (transposed)
    mgemm_k<3,128><<<dim3(12, 32), 256, 0, stream>>>(xb, WqkvT, b_qkv,
        nullptr, nullptr, Qb, Kb, Vtb, ROWS, 3*DMODEL, DMODEL);
    // attention partials (2-way KV split) -> combine -> attnb bf16
    attn_mfma_k<<<dim3(BATCH*NH*(SEQ/64), 2), 256, 0, stream>>>(
        Qb, Kb, Vtb, bits, Opart, MLp);
    attn_combine_k<<<BATCH*NH*SEQ/4, 256, 0, stream>>>(Opart, MLp, attnb);
    // proj: [4096,512]@[512,512] -> ap f32
    mgemm_k<0,64><<<dim3(4, 64), 256, 0, stream>>>(attnb, WprojT, b_proj,
        ap, nullptr, nullptr, nullptr, nullptr, ROWS, DMODEL, DMODEL);
    // x1 = LN(x + ap)  (+ bf16 copy)
    add_ln_k<<<ROWS, 256, 0, stream>>>(x, ap, ln1_g, ln1_b, x1, x1b);
    // MLP1: relu([4096,512]@[512,2048]) -> bf16 hb
    mgemm_k<1,128><<<dim3(16, 32), 256, 0, stream>>>(x1b, W1T, b1,
        nullptr, hb, nullptr, nullptr, nullptr, ROWS, 2048, DMODEL);
    // MLP2: relu([4096,2048]@[2048,512]) -> f32 mbuf
    mgemm_k<2,64><<<dim3(4, 64), 256, 0, stream>>>(hb, W2T, b2,
        mbuf, nullptr, nullptr, nullptr, nullptr, ROWS, DMODEL, 2048);
    // out = LN(x1 + mbuf)
    add_ln_k<<<ROWS, 256, 0, stream>>>(x1, mbuf, ln2_g, ln2_b, out, nullptr);
}

// Round 8
// 161.096 us; speedup vs baseline: 7.0568x; 1.0674x over previous
//
#include <hip/hip_runtime.h>
#include <math.h>

// Problem constants
constexpr int BATCH  = 2;
constexpr int SEQ    = 2048;
constexpr int DMODEL = 512;
constexpr int NH     = 8;
constexpr int DHEAD  = 64;
constexpr int ROWS   = BATCH * SEQ;           // 4096
constexpr size_t SZ  = (size_t)ROWS * DMODEL; // elems of one [4096][512] buffer
constexpr int NSPLIT = 4;                     // attention KV-split ways

typedef __attribute__((ext_vector_type(8))) short bf16x8;
typedef __attribute__((ext_vector_type(4))) float f32x4;

__device__ __forceinline__ ushort f2bf(float f) {
    unsigned u = __float_as_uint(f);
    unsigned r = (u + 0x7FFFu + ((u >> 16) & 1u)) >> 16;
    return (ushort)r;
}
__device__ __forceinline__ float bf2f(ushort u) {
    return __uint_as_float((unsigned)u << 16);
}

// pack 2 f32 -> 2 bf16 (RNE) in one instruction
__device__ __forceinline__ unsigned cvtpk_bf16(float lo, float hi) {
    unsigned r;
    asm("v_cvt_pk_bf16_f32 %0, %1, %2" : "=v"(r) : "v"(lo), "v"(hi));
    return r;
}

__device__ __forceinline__ void gload_lds16(const void* g, void* l) {
    __builtin_amdgcn_global_load_lds(
        (const __attribute__((address_space(1))) void*)g,
        (__attribute__((address_space(3))) void*)l, 16, 0, 0);
}

// ---------------------------------------------------------------------------
// Mask-encoding detector, parallel. flag MUST be zeroed before launch.
// ---------------------------------------------------------------------------
__global__ __launch_bounds__(256) void detect_mask_k(
    const uint4* __restrict__ m, int* __restrict__ flag)
{
    const int i = blockIdx.x * 256 + threadIdx.x;
    const uint4 v = m[i];
    unsigned b0 = 0, b1 = 0;
    #pragma unroll
    for (int c = 0; c < 4; ++c) {
        const unsigned u = (&v.x)[c];
        b0 |= (u > 1u) ? 1u : 0u;
        b1 |= (u != 0u && u != 0x3F800000u) ? 1u : 0u;
    }
    const int lane = threadIdx.x & 63;
    if (__any(b0) && lane == 0) atomicOr(flag, 1);
    if (__any(b1) && lane == 0) atomicOr(flag, 2);
}

// ---------------------------------------------------------------------------
// Fused prep: [0,2048) x f32->bf16 conv | [2048,2816) weight transpose+conv
//             [2816, 2816+32768) mask bitmask compaction
// ---------------------------------------------------------------------------
__global__ __launch_bounds__(256) void prep_all_k(
    const float* __restrict__ x, ushort* __restrict__ xb,
    const float* __restrict__ Wq, const float* __restrict__ Wp,
    const float* __restrict__ W1w, const float* __restrict__ W2w,
    ushort* __restrict__ WqT, ushort* __restrict__ WpT,
    ushort* __restrict__ W1T, ushort* __restrict__ W2T,
    const void* __restrict__ maskp, const int* __restrict__ flagp,
    unsigned long long* __restrict__ bits)
{
    __shared__ ushort T[64][65];
    const int bid = blockIdx.x;
    const int t = threadIdx.x;

    if (bid < 2048) {           // x f32 -> bf16
        const size_t i = ((size_t)bid * 256 + t) * 4;
        float4 v = *(const float4*)(x + i);
        ushort4 o;
        o.x = f2bf(v.x); o.y = f2bf(v.y); o.z = f2bf(v.z); o.w = f2bf(v.w);
        *(ushort4*)(xb + i) = o;
        return;
    }
    if (bid >= 2816) {          // mask -> bitmask
        const int w = (bid - 2816) * 4 + (t >> 6);
        const int lane = t & 63;
        const size_t idx = ((size_t)w << 6) + lane;
        const int f = *flagp;
        bool mv;
        if (!(f & 1))      mv = ((const int*)maskp)[idx] != 0;
        else if (!(f & 2)) mv = ((const float*)maskp)[idx] != 0.f;
        else               mv = ((const unsigned char*)maskp)[idx] != 0;
        unsigned long long bal = __ballot(mv);
        if (lane == 0) bits[w] = bal;
        return;
    }
    // weight transpose+convert, 64x64 tiles
    const int wb = bid - 2048;
    const float* W; ushort* Wt; int K, N, tix, tiy;
    if (wb < 192)      { W = Wq;  Wt = WqT; K = 512;  N = 1536; tix = wb % 24;        tiy = wb / 24; }
    else if (wb < 256) { W = Wp;  Wt = WpT; K = 512;  N = 512;  tix = (wb-192) % 8;   tiy = (wb-192) / 8; }
    else if (wb < 512) { W = W1w; Wt = W1T; K = 512;  N = 2048; tix = (wb-256) % 32;  tiy = (wb-256) / 32; }
    else               { W = W2w; Wt = W2T; K = 2048; N = 512;  tix = (wb-512) % 8;   tiy = (wb-512) / 8; }
    const int k0 = tiy * 64, n0 = tix * 64;
    const int r = t >> 4, c4 = (t & 15) * 4;
    #pragma unroll
    for (int it = 0; it < 4; ++it) {
        const int row = it*16 + r;
        float4 v = *(const float4*)&W[(size_t)(k0 + row) * N + n0 + c4];
        T[c4+0][row] = f2bf(v.x);
        T[c4+1][row] = f2bf(v.y);
        T[c4+2][row] = f2bf(v.z);
        T[c4+3][row] = f2bf(v.w);
    }
    __syncthreads();
    #pragma unroll
    for (int it = 0; it < 4; ++it) {
        const int row = it*16 + r;
        ushort4 o;
        o.x = T[row][c4+0]; o.y = T[row][c4+1];
        o.z = T[row][c4+2]; o.w = T[row][c4+3];
        *(ushort4*)&Wt[(size_t)(n0 + row) * K + k0 + c4] = o;
    }
}

// ---------------------------------------------------------------------------
// bf16 MFMA GEMM (m97 structure): C[M,N] = A[M,K] @ Wt[N,K]^T + bias.
// BM x BN tile, BK=64, 256 threads = 4 waves (2x2).
// EPI: 0 = bias -> f32 | 1 = relu(bias) -> bf16 | 2 = relu(bias) -> f32
//      3 = bias -> bf16 QKV scatter, V written TRANSPOSED [b][h][d][token]
// ---------------------------------------------------------------------------
template<int EPI, int BM, int BN>
__global__ __launch_bounds__(256) void mgemm_k(
    const ushort* __restrict__ A,   // [M][K] bf16
    const ushort* __restrict__ Wt,  // [N][K] bf16
    const float* __restrict__ bias, // [N] f32
    float* __restrict__ Cf, ushort* __restrict__ Cb,
    ushort* __restrict__ Qo, ushort* __restrict__ Ko, ushort* __restrict__ Vo,
    int M, int N, int K)
{
    constexpr int WM  = BM / 2, WN = BN / 2;
    constexpr int MF  = WM / 16, NF = WN / 16;
    constexpr int APW = BM / 32;   // A segments per wave
    constexpr int BPW = BN / 32;   // B segments per wave

    __shared__ ushort As[BM * 64];
    __shared__ ushort Bs[BN * 64];

    const int tid  = threadIdx.x;
    const int wid  = tid >> 6, lane = tid & 63;
    const int lq   = lane & 15, lg = lane >> 4;
    const int wr   = wid >> 1,  wc = wid & 1;
    const int bm   = blockIdx.y * BM, bn = blockIdx.x * BN;

    const int srow0 = lane >> 3;
    const int sch   = lane & 7;

    f32x4 acc[MF][NF] = {};

    for (int k0 = 0; k0 < K; k0 += 64) {
        __syncthreads();
        #pragma unroll
        for (int i = 0; i < APW; ++i) {
            const int seg = wid * APW + i;
            const int row = seg * 8 + srow0;
            const int c16 = sch ^ (row & 7);
            gload_lds16(A + (size_t)(bm + row) * K + k0 + c16 * 8, As + seg * 512);
        }
        #pragma unroll
        for (int i = 0; i < BPW; ++i) {
            const int seg = wid * BPW + i;
            const int row = seg * 8 + srow0;
            const int c16 = sch ^ (row & 7);
            gload_lds16(Wt + (size_t)(bn + row) * K + k0 + c16 * 8, Bs + seg * 512);
        }
        __syncthreads();

        #pragma unroll
        for (int ks = 0; ks < 2; ++ks) {
            bf16x8 af[MF], bfr[NF];
            #pragma unroll
            for (int m = 0; m < MF; ++m) {
                const int row = wr*WM + m*16 + lq;
                const int c16 = (ks*4 + lg) ^ (row & 7);
                af[m] = *(const bf16x8*)&As[row * 64 + c16 * 8];
            }
            #pragma unroll
            for (int n = 0; n < NF; ++n) {
                const int row = wc*WN + n*16 + lq;
                const int c16 = (ks*4 + lg) ^ (row & 7);
                bfr[n] = *(const bf16x8*)&Bs[row * 64 + c16 * 8];
            }
            #pragma unroll
            for (int m = 0; m < MF; ++m)
                #pragma unroll
                for (int n = 0; n < NF; ++n)
                    acc[m][n] = __builtin_amdgcn_mfma_f32_16x16x32_bf16(
                        af[m], bfr[n], acc[m][n], 0, 0, 0);
        }
    }

    #pragma unroll
    for (int m = 0; m < MF; ++m) {
        const int row0 = bm + wr*WM + m*16 + lg*4;
        #pragma unroll
        for (int n = 0; n < NF; ++n) {
            const int col = bn + wc*WN + n*16 + lq;
            const float bv = bias[col];
            float v[4];
            #pragma unroll
            for (int r = 0; r < 4; ++r) {
                v[r] = acc[m][n][r] + bv;
                if (EPI == 1 || EPI == 2) v[r] = fmaxf(v[r], 0.f);
            }
            if (EPI == 3) {
                const int part = col >> 9, hc = col & 511;
                const int hh = hc >> 6, d0 = hc & 63;
                const int bidx = row0 >> 11, nrow0 = row0 & 2047;
                if (part == 2) {
                    ushort4 pv;
                    pv.x = f2bf(v[0]); pv.y = f2bf(v[1]);
                    pv.z = f2bf(v[2]); pv.w = f2bf(v[3]);
                    *(ushort4*)(Vo + (((size_t)bidx*NH + hh)*DHEAD + d0)*SEQ + nrow0) = pv;
                } else {
                    ushort* dst = (part == 0) ? Qo : Ko;
                    #pragma unroll
                    for (int r = 0; r < 4; ++r)
                        dst[((((size_t)bidx*NH + hh)*SEQ + nrow0 + r) << 6) + d0] = f2bf(v[r]);
                }
            } else {
                #pragma unroll
                for (int r = 0; r < 4; ++r) {
                    const int row = row0 + r;
                    if (EPI == 1) Cb[(size_t)row * N + col] = f2bf(v[r]);
                    else          Cf[(size_t)row * N + col] = v[r];
                }
            }
        }
    }
}

// ---------------------------------------------------------------------------
// bf16 MFMA flash attention, v5: 4-way KV-split, bf16 partials.
// Grid: (512, 4). Each block: 8 of 32 64-key chunks; unnormalized partial O
// (bf16) + per-row (m, l). LDS 40KB -> 4 blocks/CU resident; grid 2048 keeps
// the CUs at that cap (occupancy target ~50%).
// ---------------------------------------------------------------------------
__global__ __launch_bounds__(256, 4) void attn_mfma_k(
    const ushort* __restrict__ Qb, const ushort* __restrict__ Kb,
    const ushort* __restrict__ Vtb, const unsigned long long* __restrict__ mbits,
    ushort* __restrict__ Opart, float2* __restrict__ MLpart)
{
    __shared__ ushort Klds[2][64 * 64];   // [key][d], XOR-swizzled 16B chunks
    __shared__ ushort Vlds[2][64 * 64];   // [d][key], XOR-swizzled
    __shared__ ushort Plds[4][16 * 64];   // per-wave [q][key], XOR-swizzled

    const int tid  = threadIdx.x;
    const int wid  = tid >> 6;
    const int lane = tid & 63;
    const int lq   = lane & 15;
    const int lg   = lane >> 4;

    const int tile = blockIdx.x & 31;
    const int bh   = blockIdx.x >> 5;
    const int b    = bh >> 3;
    const int qw   = tile * 64 + wid * 16;
    const int s    = blockIdx.y;                 // key-range quarter
    const int c0   = s * 8, c1 = c0 + 8;         // chunk range

    // hoisted Q fragments (B-operand)
    const ushort* Qg = Qb + ((size_t)bh * SEQ + qw + lq) * DHEAD;
    const bf16x8 qf0 = *(const bf16x8*)(Qg + lg * 8);
    const bf16x8 qf1 = *(const bf16x8*)(Qg + 32 + lg * 8);

    const int srow0 = lane >> 3;              // 0..7 (== row&7 for all segs)
    const int sch   = lane & 7;
    const int gc8   = (sch ^ srow0) * 8;      // inverse-swizzled global col

    // per-thread global staging bases (K: [key][d] rows, V: [d][key] rows)
    const ushort* kgb  = Kb  + (size_t)bh * SEQ * DHEAD
                             + (size_t)(wid*16 + srow0) * DHEAD + gc8;
    const ushort* vgb0 = Vtb + (size_t)bh * DHEAD * SEQ
                             + (size_t)(wid*16 + srow0) * SEQ + gc8;
    const ushort* vgb1 = vgb0 + 8 * SEQ;      // i=1 segment (+8 d-rows)

    // LDS staging destinations (wave's two 512-ushort segments per buffer)
    ushort* kd0 = &Klds[0][(wid*2)*512];
    ushort* kd1 = &Klds[1][(wid*2)*512];
    ushort* vd0 = &Vlds[0][(wid*2)*512];
    ushort* vd1 = &Vlds[1][(wid*2)*512];

    // hoisted LDS BYTE offsets (loop-invariant)
    int kro[4][2], vro[4][2], pwo[4], pro[2];
    #pragma unroll
    for (int kt = 0; kt < 4; ++kt) {
        kro[kt][0] = ((kt*16 + lq)*64 + ((lg     ^ (lq&7))*8)) * 2;
        kro[kt][1] = ((kt*16 + lq)*64 + (((4+lg) ^ (lq&7))*8)) * 2;
        pwo[kt]    = (wid*1024 + lq*64 + (((kt*2 + (lg>>1)) ^ (lq&7))*8) + (lg&1)*4) * 2;
    }
    #pragma unroll
    for (int kk = 0; kk < 2; ++kk) {
        pro[kk] = (wid*1024 + lq*64 + (((kk*4+lg) ^ (lq&7))*8)) * 2;
        #pragma unroll
        for (int nt = 0; nt < 4; ++nt)
            vro[nt][kk] = ((nt*16 + lq)*64 + (((kk*4+lg) ^ (lq&7))*8)) * 2;
    }
    const char* kbase0 = (const char*)&Klds[0][0];
    const char* kbase1 = (const char*)&Klds[1][0];
    const char* vbase0 = (const char*)&Vlds[0][0];
    const char* vbase1 = (const char*)&Vlds[1][0];
    char*       pbase  = (char*)&Plds[0][0];

    const unsigned long long* mrow = mbits + ((size_t)b * SEQ + qw + lq) * (SEQ / 64);

    f32x4 o[4] = {};
    float mrun = -1e30f, lrun = 0.f;
    const float k2 = 0.125f * 1.44269504f;   // 1/sqrt(dh) * log2(e)

    // stage chunk c0 into buf 0
    {
        const ushort* kp0  = kgb  + (size_t)c0 * 4096;   // 64 keys * DHEAD
        const ushort* vq0  = vgb0 + c0 * 64;
        const ushort* vq1  = vgb1 + c0 * 64;
        gload_lds16(kp0,       kd0);
        gload_lds16(kp0 + 512, kd0 + 512);
        gload_lds16(vq0, vd0);
        gload_lds16(vq1, vd0 + 512);
    }
    // pointers for the NEXT chunk to stage
    const ushort* kp  = kgb  + (size_t)(c0 + 1) * 4096;
    const ushort* vp0 = vgb0 + (c0 + 1) * 64;
    const ushort* vp1 = vgb1 + (c0 + 1) * 64;
    __syncthreads();

#define ATTN_CHUNK(CC, KD, VD, KBASE, VBASE)                                   \
    {                                                                          \
        if ((CC) + 1 < c1) {                                                   \
            gload_lds16(kp,       (KD));                                       \
            gload_lds16(kp + 512, (KD) + 512);                                 \
            gload_lds16(vp0, (VD));                                            \
            gload_lds16(vp1, (VD) + 512);                                      \
            kp += 4096; vp0 += 64; vp1 += 64;                                  \
        }                                                                      \
        f32x4 st[4];                                                           \
        __builtin_amdgcn_s_setprio(1);                                         \
        _Pragma("unroll")                                                      \
        for (int kt = 0; kt < 4; ++kt) {                                       \
            bf16x8 kf0 = *(const bf16x8*)((KBASE) + kro[kt][0]);               \
            bf16x8 kf1 = *(const bf16x8*)((KBASE) + kro[kt][1]);               \
            f32x4 a = {};                                                      \
            a = __builtin_amdgcn_mfma_f32_16x16x32_bf16(kf0, qf0, a, 0, 0, 0); \
            a = __builtin_amdgcn_mfma_f32_16x16x32_bf16(kf1, qf1, a, 0, 0, 0); \
            st[kt] = a;                                                        \
        }                                                                      \
        __builtin_amdgcn_s_setprio(0);                                         \
        const unsigned long long mws = mrow[CC] >> (lg * 4);                   \
        const unsigned mlo = (unsigned)mws, mhi = (unsigned)(mws >> 32);       \
        float sv[16];                                                          \
        _Pragma("unroll")                                                      \
        for (int kt = 0; kt < 4; ++kt) {                                       \
            const unsigned half = (kt & 2) ? mhi : mlo;                        \
            _Pragma("unroll")                                                  \
            for (int r = 0; r < 4; ++r) {                                      \
                const unsigned bit = (half >> ((kt & 1)*16 + r)) & 1u;         \
                sv[kt*4 + r] = bit ? st[kt][r] * k2 : -1e9f;                   \
            }                                                                  \
        }                                                                      \
        float cmax = fmaxf(                                                    \
            fmaxf(fmaxf(fmaxf(sv[0],sv[1]),fmaxf(sv[2],sv[3])),                \
                  fmaxf(fmaxf(sv[4],sv[5]),fmaxf(sv[6],sv[7]))),               \
            fmaxf(fmaxf(fmaxf(sv[8],sv[9]),fmaxf(sv[10],sv[11])),              \
                  fmaxf(fmaxf(sv[12],sv[13]),fmaxf(sv[14],sv[15]))));          \
        cmax = fmaxf(cmax, __shfl_xor(cmax, 16));                              \
        cmax = fmaxf(cmax, __shfl_xor(cmax, 32));                              \
        float mnew = mrun, scale = 1.0f;                                       \
        if (!__all(cmax <= mrun)) {                                            \
            mnew  = fmaxf(mrun, cmax);                                         \
            scale = exp2f(mrun - mnew);                                        \
            float sc[4];                                                       \
            _Pragma("unroll")                                                  \
            for (int r = 0; r < 4; ++r) sc[r] = __shfl(scale, lg*4 + r);       \
            _Pragma("unroll")                                                  \
            for (int nt = 0; nt < 4; ++nt)                                     \
                _Pragma("unroll")                                              \
                for (int r = 0; r < 4; ++r) o[nt][r] *= sc[r];                 \
        }                                                                      \
        float ls[4];                                                           \
        _Pragma("unroll")                                                      \
        for (int kt = 0; kt < 4; ++kt) {                                       \
            const float p0 = exp2f(sv[kt*4+0] - mnew);                         \
            const float p1 = exp2f(sv[kt*4+1] - mnew);                         \
            const float p2 = exp2f(sv[kt*4+2] - mnew);                         \
            const float p3 = exp2f(sv[kt*4+3] - mnew);                         \
            ls[kt] = (p0 + p1) + (p2 + p3);                                    \
            uint2 pk;                                                          \
            pk.x = cvtpk_bf16(p0, p1);                                         \
            pk.y = cvtpk_bf16(p2, p3);                                         \
            *(uint2*)(pbase + pwo[kt]) = pk;                                   \
        }                                                                      \
        float lsum = (ls[0] + ls[1]) + (ls[2] + ls[3]);                        \
        lsum += __shfl_xor(lsum, 16);                                          \
        lsum += __shfl_xor(lsum, 32);                                          \
        lrun = lrun * scale + lsum;                                            \
        mrun = mnew;                                                           \
        __builtin_amdgcn_s_setprio(1);                                         \
        _Pragma("unroll")                                                      \
        for (int kk = 0; kk < 2; ++kk) {                                       \
            bf16x8 pf = *(const bf16x8*)(pbase + pro[kk]);                     \
            _Pragma("unroll")                                                  \
            for (int nt = 0; nt < 4; ++nt) {                                   \
                bf16x8 vf = *(const bf16x8*)((VBASE) + vro[nt][kk]);           \
                o[nt] = __builtin_amdgcn_mfma_f32_16x16x32_bf16(               \
                    pf, vf, o[nt], 0, 0, 0);                                   \
            }                                                                  \
        }                                                                      \
        __builtin_amdgcn_s_setprio(0);                                         \
        __syncthreads();                                                       \
    }

    for (int c = c0; c < c1; c += 2) {
        ATTN_CHUNK(c,     kd1, vd1, kbase0, vbase0);   // compute buf0, stage buf1
        ATTN_CHUNK(c + 1, kd0, vd0, kbase1, vbase1);   // compute buf1, stage buf0
    }
#undef ATTN_CHUNK

    // partial epilogue: unnormalized O (bf16) + (m, l)
    #pragma unroll
    for (int nt = 0; nt < 4; ++nt)
        #pragma unroll
        for (int r = 0; r < 4; ++r) {
            const int qrow = qw + lg*4 + r;
            Opart[(((size_t)s*16 + bh)*SEQ + qrow)*64 + nt*16 + lq] = f2bf(o[nt][r]);
        }
    if (lg == 0) {
        float2 ml; ml.x = mrun; ml.y = lrun;
        MLpart[((size_t)s*16 + bh)*SEQ + qw + lq] = ml;
    }
}

// ---------------------------------------------------------------------------
// Combine the NSPLIT KV-split parts (exact log-sum-exp merge, base-2 domain).
// Grid: B*H*SEQ/4 blocks of 256; one wave per row, lane = d.
// ---------------------------------------------------------------------------
__global__ __launch_bounds__(256) void attn_combine_k(
    const ushort* __restrict__ Op, const float2* __restrict__ ML,
    ushort* __restrict__ attnb)
{
    const int row  = blockIdx.x * 4 + (threadIdx.x >> 6);  // bh*SEQ + q
    const int lane = threadIdx.x & 63;
    const int bh = row >> 11, q = row & 2047;
    const int b = bh >> 3, h = bh & 7;
    float2 ml[NSPLIT];
    float m = -1e30f;
    #pragma unroll
    for (int s = 0; s < NSPLIT; ++s) {
        ml[s] = ML[(size_t)s*16*SEQ + row];
        m = fmaxf(m, ml[s].x);
    }
    float l = 0.f, o = 0.f;
    #pragma unroll
    for (int s = 0; s < NSPLIT; ++s) {
        const float a = exp2f(ml[s].x - m);
        l += ml[s].y * a;
        o += bf2f(Op[((size_t)s*16*SEQ + row)*64 + lane]) * a;
    }
    attnb[((size_t)(b*SEQ + q))*DMODEL + h*DHEAD + lane] = f2bf(o / l);
}

// ---------------------------------------------------------------------------
// out = LayerNorm(X + A)*g + b over DMODEL=512; optional bf16 copy.
// ---------------------------------------------------------------------------
__global__ __launch_bounds__(256) void add_ln_k(
    const float* __restrict__ X, const float* __restrict__ Aa,
    const float* __restrict__ gg, const float* __restrict__ bb,
    float* __restrict__ out, ushort* __restrict__ outb)
{
    const int r = blockIdx.x;
    const int t = threadIdx.x;
    const float2 x2 = ((const float2*)(X  + (size_t)r * DMODEL))[t];
    const float2 a2 = ((const float2*)(Aa + (size_t)r * DMODEL))[t];
    const float v0 = x2.x + a2.x, v1 = x2.y + a2.y;
    float s  = v0 + v1;
    float ss = v0*v0 + v1*v1;
    #pragma unroll
    for (int off = 32; off > 0; off >>= 1) {
        s  += __shfl_down(s,  off);
        ss += __shfl_down(ss, off);
    }
    __shared__ float ps[4], pss[4];
    const int wid = t >> 6;
    if ((t & 63) == 0) { ps[wid] = s; pss[wid] = ss; }
    __syncthreads();
    const float tot  = ps[0] + ps[1] + ps[2] + ps[3];
    const float tots = pss[0] + pss[1] + pss[2] + pss[3];
    const float mean = tot * (1.0f / DMODEL);
    const float var  = tots * (1.0f / DMODEL) - mean * mean;
    const float rstd = rsqrtf(var + 1e-5f);
    const float2 g2 = ((const float2*)gg)[t];
    const float2 b2 = ((const float2*)bb)[t];
    float2 r2;
    r2.x = (v0 - mean) * rstd * g2.x + b2.x;
    r2.y = (v1 - mean) * rstd * g2.y + b2.y;
    ((float2*)(out + (size_t)r * DMODEL))[t] = r2;
    if (outb) {
        ushort2 ob; ob.x = f2bf(r2.x); ob.y = f2bf(r2.y);
        *(ushort2*)(outb + (size_t)r * DMODEL + t*2) = ob;
    }
}

// ---------------------------------------------------------------------------
extern "C" void kernel_launch(void* const* d_in, const int* in_sizes, int n_in,
                              void* d_out, int out_size, void* d_ws, size_t ws_size,
                              hipStream_t stream)
{
    const float* x      = (const float*)d_in[0];
    const void*  mask   = d_in[1];
    const float* W_qkv  = (const float*)d_in[2];
    const float* b_qkv  = (const float*)d_in[3];
    const float* W_proj = (const float*)d_in[4];
    const float* b_proj = (const float*)d_in[5];
    const float* ln1_g  = (const float*)d_in[6];
    const float* ln1_b  = (const float*)d_in[7];
    const float* W1     = (const float*)d_in[8];
    const float* b1     = (const float*)d_in[9];
    const float* W2     = (const float*)d_in[10];
    const float* b2     = (const float*)d_in[11];
    const float* ln2_g  = (const float*)d_in[12];
    const float* ln2_b  = (const float*)d_in[13];

    float* ws = (float*)d_ws;
    // Workspace (float-element offsets; SZ = 2,097,152):
    //  [0,   0.5) xb bf16           \
    //  [0.5, 2.0) Qb,Kb,Vtb bf16     } hb bf16 [0,2.0) in MLP phase
    //  [2.0, 2.5) attnb bf16
    //  [2.5, 4.5) Opart bf16 [4][16][SEQ][64] (attn) / ap f32 [2.5,3.5) + x1 [3.5,4.5)
    //  [4.5, 5.0) MLpart [4][16][SEQ] f2 (attn, 1MB) / x1b bf16
    //  mbuf f32 overlays [2.0,3.0) in MLP phase
    //  [5.0, ...) WqkvT, WprojT, W1T, W2T bf16; bits; flag
    ushort* xb    = (ushort*)ws;
    ushort* Qb    = (ushort*)(ws + SZ/2);
    ushort* Kb    = (ushort*)(ws + SZ);
    ushort* Vtb   = (ushort*)(ws + SZ + SZ/2);   // [B,H,DHEAD,SEQ]
    ushort* attnb = (ushort*)(ws + 2*SZ);
    ushort* Opart = (ushort*)(ws + 2*SZ + SZ/2); // [4][16][SEQ][64] bf16 = 2*SZ f32
    float2* MLp   = (float2*)(ws + 4*SZ + SZ/2); // [4][16][SEQ]
    float*  ap    = ws + 2*SZ + SZ/2;
    float*  mbuf  = ws + 2*SZ;
    float*  x1    = ws + 3*SZ + SZ/2;
    ushort* x1b   = (ushort*)(ws + 4*SZ + SZ/2);
    ushort* hb    = (ushort*)ws;
    ushort* WqkvT = (ushort*)(ws + 5*SZ);                    // 512*1536
    ushort* WprojT= (ushort*)(ws + 5*SZ + 393216);           // 512*512
    ushort* W1T   = (ushort*)(ws + 5*SZ + 524288);           // 2048*512
    ushort* W2T   = (ushort*)(ws + 5*SZ + 1048576);          // 512*2048
    unsigned long long* bits = (unsigned long long*)(ws + 5*SZ + 1572864);
    int*    flag  = (int*)(ws + 5*SZ + 1572864 + 262144);

    float* out = (float*)d_out;

    hipMemsetAsync(flag, 0, 4, stream);
    detect_mask_k<<<64, 256, 0, stream>>>((const uint4*)mask, flag);
    prep_all_k<<<2816 + 32768, 256, 0, stream>>>(
        x, xb, W_qkv, W_proj, W1, W2, WqkvT, WprojT, W1T, W2T,
        mask, flag, bits);

    // QKV: [4096,512]@[512,1536] -> bf16 Q/K (row) + V (transposed)
    mgemm_k<3,64,128><<<dim3(12, 64), 256, 0, stream>>>(xb, WqkvT, b_qkv,
        nullptr, nullptr, Qb, Kb, Vtb, ROWS, 3*DMODEL, DMODEL);
    // attention partials (4-way KV split) -> combine -> attnb bf16
    attn_mfma_k<<<dim3(BATCH*NH*(SEQ/64), NSPLIT), 256, 0, stream>>>(
        Qb, Kb, Vtb, bits, Opart, MLp);
    attn_combine_k<<<BATCH*NH*SEQ/4, 256, 0, stream>>>(Opart, MLp, attnb);
    // proj: [4096,512]@[512,512] -> ap f32
    mgemm_k<0,64,64><<<dim3(8, 64), 256, 0, stream>>>(attnb, WprojT, b_proj,
        ap, nullptr, nullptr, nullptr, nullptr, ROWS, DMODEL, DMODEL);
    // x1 = LN(x + ap)  (+ bf16 copy)
    add_ln_k<<<ROWS, 256, 0, stream>>>(x, ap, ln1_g, ln1_b, x1, x1b);
    // MLP1: relu([4096,512]@[512,2048]) -> bf16 hb
    mgemm_k<1,64,128><<<dim3(16, 64), 256, 0, stream>>>(x1b, W1T, b1,
        nullptr, hb, nullptr, nullptr, nullptr, ROWS, 2048, DMODEL);
    // MLP2: relu([4096,2048]@[2048,512]) -> f32 mbuf
    mgemm_k<2,64,64><<<dim3(8, 64), 256, 0, stream>>>(hb, W2T, b2,
        mbuf, nullptr, nullptr, nullptr, nullptr, ROWS, DMODEL, 2048);
    // out = LN(x1 + mbuf)
    add_ln_k<<<ROWS, 256, 0, stream>>>(x1, mbuf, ln2_g, ln2_b, out, nullptr);
}

// Round 9
// 158.360 us; speedup vs baseline: 7.1787x; 1.0173x over previous
//
#include <hip/hip_runtime.h>
#include <math.h>

// Problem constants
constexpr int BATCH  = 2;
constexpr int SEQ    = 2048;
constexpr int DMODEL = 512;
constexpr int NH     = 8;
constexpr int DHEAD  = 64;
constexpr int ROWS   = BATCH * SEQ;           // 4096
constexpr size_t SZ  = (size_t)ROWS * DMODEL; // elems of one [4096][512] f32 buffer
constexpr int NSPLIT = 4;                     // attention KV-split ways

typedef __attribute__((ext_vector_type(8))) short bf16x8;
typedef __attribute__((ext_vector_type(4))) float f32x4;

__device__ __forceinline__ ushort f2bf(float f) {
    unsigned u = __float_as_uint(f);
    unsigned r = (u + 0x7FFFu + ((u >> 16) & 1u)) >> 16;
    return (ushort)r;
}
__device__ __forceinline__ float bf2f(ushort u) {
    return __uint_as_float((unsigned)u << 16);
}

// pack 2 f32 -> 2 bf16 (RNE) in one instruction
__device__ __forceinline__ unsigned cvtpk_bf16(float lo, float hi) {
    unsigned r;
    asm("v_cvt_pk_bf16_f32 %0, %1, %2" : "=v"(r) : "v"(lo), "v"(hi));
    return r;
}

__device__ __forceinline__ void gload_lds16(const void* g, void* l) {
    __builtin_amdgcn_global_load_lds(
        (const __attribute__((address_space(1))) void*)g,
        (__attribute__((address_space(3))) void*)l, 16, 0, 0);
}

// ---------------------------------------------------------------------------
// Mask-encoding detector, parallel. flag MUST be zeroed before launch.
// ---------------------------------------------------------------------------
__global__ __launch_bounds__(256) void detect_mask_k(
    const uint4* __restrict__ m, int* __restrict__ flag)
{
    const int i = blockIdx.x * 256 + threadIdx.x;
    const uint4 v = m[i];
    unsigned b0 = 0, b1 = 0;
    #pragma unroll
    for (int c = 0; c < 4; ++c) {
        const unsigned u = (&v.x)[c];
        b0 |= (u > 1u) ? 1u : 0u;
        b1 |= (u != 0u && u != 0x3F800000u) ? 1u : 0u;
    }
    const int lane = threadIdx.x & 63;
    if (__any(b0) && lane == 0) atomicOr(flag, 1);
    if (__any(b1) && lane == 0) atomicOr(flag, 2);
}

// ---------------------------------------------------------------------------
// Fused prep: [0,2048) x f32->bf16 conv | [2048,2816) weight transpose+conv
//             [2816, 2816+32768) mask bitmask compaction
// ---------------------------------------------------------------------------
__global__ __launch_bounds__(256) void prep_all_k(
    const float* __restrict__ x, ushort* __restrict__ xb,
    const float* __restrict__ Wq, const float* __restrict__ Wp,
    const float* __restrict__ W1w, const float* __restrict__ W2w,
    ushort* __restrict__ WqT, ushort* __restrict__ WpT,
    ushort* __restrict__ W1T, ushort* __restrict__ W2T,
    const void* __restrict__ maskp, const int* __restrict__ flagp,
    unsigned long long* __restrict__ bits)
{
    __shared__ ushort T[64][65];
    const int bid = blockIdx.x;
    const int t = threadIdx.x;

    if (bid < 2048) {           // x f32 -> bf16
        const size_t i = ((size_t)bid * 256 + t) * 4;
        float4 v = *(const float4*)(x + i);
        ushort4 o;
        o.x = f2bf(v.x); o.y = f2bf(v.y); o.z = f2bf(v.z); o.w = f2bf(v.w);
        *(ushort4*)(xb + i) = o;
        return;
    }
    if (bid >= 2816) {          // mask -> bitmask
        const int w = (bid - 2816) * 4 + (t >> 6);
        const int lane = t & 63;
        const size_t idx = ((size_t)w << 6) + lane;
        const int f = *flagp;
        bool mv;
        if (!(f & 1))      mv = ((const int*)maskp)[idx] != 0;
        else if (!(f & 2)) mv = ((const float*)maskp)[idx] != 0.f;
        else               mv = ((const unsigned char*)maskp)[idx] != 0;
        unsigned long long bal = __ballot(mv);
        if (lane == 0) bits[w] = bal;
        return;
    }
    // weight transpose+convert, 64x64 tiles
    const int wb = bid - 2048;
    const float* W; ushort* Wt; int K, N, tix, tiy;
    if (wb < 192)      { W = Wq;  Wt = WqT; K = 512;  N = 1536; tix = wb % 24;        tiy = wb / 24; }
    else if (wb < 256) { W = Wp;  Wt = WpT; K = 512;  N = 512;  tix = (wb-192) % 8;   tiy = (wb-192) / 8; }
    else if (wb < 512) { W = W1w; Wt = W1T; K = 512;  N = 2048; tix = (wb-256) % 32;  tiy = (wb-256) / 32; }
    else               { W = W2w; Wt = W2T; K = 2048; N = 512;  tix = (wb-512) % 8;   tiy = (wb-512) / 8; }
    const int k0 = tiy * 64, n0 = tix * 64;
    const int r = t >> 4, c4 = (t & 15) * 4;
    #pragma unroll
    for (int it = 0; it < 4; ++it) {
        const int row = it*16 + r;
        float4 v = *(const float4*)&W[(size_t)(k0 + row) * N + n0 + c4];
        T[c4+0][row] = f2bf(v.x);
        T[c4+1][row] = f2bf(v.y);
        T[c4+2][row] = f2bf(v.z);
        T[c4+3][row] = f2bf(v.w);
    }
    __syncthreads();
    #pragma unroll
    for (int it = 0; it < 4; ++it) {
        const int row = it*16 + r;
        ushort4 o;
        o.x = T[row][c4+0]; o.y = T[row][c4+1];
        o.z = T[row][c4+2]; o.w = T[row][c4+3];
        *(ushort4*)&Wt[(size_t)(n0 + row) * K + k0 + c4] = o;
    }
}

// ---------------------------------------------------------------------------
// bf16 MFMA GEMM (m97 structure): C[M,N] = A[M,K] @ Wt[N,K]^T + bias.
// BM x BN tile, BK=64, 256 threads = 4 waves (2x2).
// EPI: 1 = relu(bias) -> bf16 | 3 = bias -> bf16 QKV scatter (V transposed)
//      4 = bias -> bf16
// ---------------------------------------------------------------------------
template<int EPI, int BM, int BN>
__global__ __launch_bounds__(256) void mgemm_k(
    const ushort* __restrict__ A,   // [M][K] bf16
    const ushort* __restrict__ Wt,  // [N][K] bf16
    const float* __restrict__ bias, // [N] f32
    ushort* __restrict__ Cb,
    ushort* __restrict__ Qo, ushort* __restrict__ Ko, ushort* __restrict__ Vo,
    int M, int N, int K)
{
    constexpr int WM  = BM / 2, WN = BN / 2;
    constexpr int MF  = WM / 16, NF = WN / 16;
    constexpr int APW = BM / 32;   // A segments per wave
    constexpr int BPW = BN / 32;   // B segments per wave

    __shared__ ushort As[BM * 64];
    __shared__ ushort Bs[BN * 64];

    const int tid  = threadIdx.x;
    const int wid  = tid >> 6, lane = tid & 63;
    const int lq   = lane & 15, lg = lane >> 4;
    const int wr   = wid >> 1,  wc = wid & 1;
    const int bm   = blockIdx.y * BM, bn = blockIdx.x * BN;

    const int srow0 = lane >> 3;
    const int sch   = lane & 7;

    f32x4 acc[MF][NF] = {};

    for (int k0 = 0; k0 < K; k0 += 64) {
        __syncthreads();
        #pragma unroll
        for (int i = 0; i < APW; ++i) {
            const int seg = wid * APW + i;
            const int row = seg * 8 + srow0;
            const int c16 = sch ^ (row & 7);
            gload_lds16(A + (size_t)(bm + row) * K + k0 + c16 * 8, As + seg * 512);
        }
        #pragma unroll
        for (int i = 0; i < BPW; ++i) {
            const int seg = wid * BPW + i;
            const int row = seg * 8 + srow0;
            const int c16 = sch ^ (row & 7);
            gload_lds16(Wt + (size_t)(bn + row) * K + k0 + c16 * 8, Bs + seg * 512);
        }
        __syncthreads();

        #pragma unroll
        for (int ks = 0; ks < 2; ++ks) {
            bf16x8 af[MF], bfr[NF];
            #pragma unroll
            for (int m = 0; m < MF; ++m) {
                const int row = wr*WM + m*16 + lq;
                const int c16 = (ks*4 + lg) ^ (row & 7);
                af[m] = *(const bf16x8*)&As[row * 64 + c16 * 8];
            }
            #pragma unroll
            for (int n = 0; n < NF; ++n) {
                const int row = wc*WN + n*16 + lq;
                const int c16 = (ks*4 + lg) ^ (row & 7);
                bfr[n] = *(const bf16x8*)&Bs[row * 64 + c16 * 8];
            }
            #pragma unroll
            for (int m = 0; m < MF; ++m)
                #pragma unroll
                for (int n = 0; n < NF; ++n)
                    acc[m][n] = __builtin_amdgcn_mfma_f32_16x16x32_bf16(
                        af[m], bfr[n], acc[m][n], 0, 0, 0);
        }
    }

    #pragma unroll
    for (int m = 0; m < MF; ++m) {
        const int row0 = bm + wr*WM + m*16 + lg*4;
        #pragma unroll
        for (int n = 0; n < NF; ++n) {
            const int col = bn + wc*WN + n*16 + lq;
            const float bv = bias[col];
            float v[4];
            #pragma unroll
            for (int r = 0; r < 4; ++r) {
                v[r] = acc[m][n][r] + bv;
                if (EPI == 1) v[r] = fmaxf(v[r], 0.f);
            }
            if (EPI == 3) {
                const int part = col >> 9, hc = col & 511;
                const int hh = hc >> 6, d0 = hc & 63;
                const int bidx = row0 >> 11, nrow0 = row0 & 2047;
                if (part == 2) {
                    ushort4 pv;
                    pv.x = f2bf(v[0]); pv.y = f2bf(v[1]);
                    pv.z = f2bf(v[2]); pv.w = f2bf(v[3]);
                    *(ushort4*)(Vo + (((size_t)bidx*NH + hh)*DHEAD + d0)*SEQ + nrow0) = pv;
                } else {
                    ushort* dst = (part == 0) ? Qo : Ko;
                    #pragma unroll
                    for (int r = 0; r < 4; ++r)
                        dst[((((size_t)bidx*NH + hh)*SEQ + nrow0 + r) << 6) + d0] = f2bf(v[r]);
                }
            } else {
                #pragma unroll
                for (int r = 0; r < 4; ++r)
                    Cb[(size_t)(row0 + r) * N + col] = f2bf(v[r]);
            }
        }
    }
}

// ---------------------------------------------------------------------------
// bf16 MFMA flash attention, v6: XCD-aware block swizzle (same-head q-tiles
// colocate per XCD -> K/V quarters L2-resident) + mask-word software pipeline
// (next chunk's mask word loaded one chunk ahead, out of the serial chain).
// Grid: (512, NSPLIT). Each block: SEQ/64/NSPLIT chunks of 64 keys.
// ---------------------------------------------------------------------------
__global__ __launch_bounds__(256, 4) void attn_mfma_k(
    const ushort* __restrict__ Qb, const ushort* __restrict__ Kb,
    const ushort* __restrict__ Vtb, const unsigned long long* __restrict__ mbits,
    ushort* __restrict__ Opart, float2* __restrict__ MLpart)
{
    __shared__ ushort Klds[2][64 * 64];   // [key][d], XOR-swizzled 16B chunks
    __shared__ ushort Vlds[2][64 * 64];   // [d][key], XOR-swizzled
    __shared__ ushort Plds[4][16 * 64];   // per-wave [q][key], XOR-swizzled

    const int tid  = threadIdx.x;
    const int wid  = tid >> 6;
    const int lane = tid & 63;
    const int lq   = lane & 15;
    const int lg   = lane >> 4;

    // XCD-aware swizzle: xcd = bid&7 (dispatch round-robin); give each XCD
    // two whole heads so its K/V quarter stays L2-resident across 32 q-tiles.
    const int raw  = blockIdx.x;          // 0..511
    const int xcd  = raw & 7;
    const int idx  = raw >> 3;            // 0..63
    const int bh   = xcd * 2 + (idx >> 5);
    const int tile = idx & 31;
    const int b    = bh >> 3;
    const int qw   = tile * 64 + wid * 16;
    const int s    = blockIdx.y;                 // key-range quarter
    const int c0   = s * 8, c1 = c0 + 8;         // chunk range

    // hoisted Q fragments (B-operand)
    const ushort* Qg = Qb + ((size_t)bh * SEQ + qw + lq) * DHEAD;
    const bf16x8 qf0 = *(const bf16x8*)(Qg + lg * 8);
    const bf16x8 qf1 = *(const bf16x8*)(Qg + 32 + lg * 8);

    const int srow0 = lane >> 3;              // 0..7 (== row&7 for all segs)
    const int sch   = lane & 7;
    const int gc8   = (sch ^ srow0) * 8;      // inverse-swizzled global col

    // per-thread global staging bases (K: [key][d] rows, V: [d][key] rows)
    const ushort* kgb  = Kb  + (size_t)bh * SEQ * DHEAD
                             + (size_t)(wid*16 + srow0) * DHEAD + gc8;
    const ushort* vgb0 = Vtb + (size_t)bh * DHEAD * SEQ
                             + (size_t)(wid*16 + srow0) * SEQ + gc8;
    const ushort* vgb1 = vgb0 + 8 * SEQ;      // i=1 segment (+8 d-rows)

    // LDS staging destinations (wave's two 512-ushort segments per buffer)
    ushort* kd0 = &Klds[0][(wid*2)*512];
    ushort* kd1 = &Klds[1][(wid*2)*512];
    ushort* vd0 = &Vlds[0][(wid*2)*512];
    ushort* vd1 = &Vlds[1][(wid*2)*512];

    // hoisted LDS BYTE offsets (loop-invariant)
    int kro[4][2], vro[4][2], pwo[4], pro[2];
    #pragma unroll
    for (int kt = 0; kt < 4; ++kt) {
        kro[kt][0] = ((kt*16 + lq)*64 + ((lg     ^ (lq&7))*8)) * 2;
        kro[kt][1] = ((kt*16 + lq)*64 + (((4+lg) ^ (lq&7))*8)) * 2;
        pwo[kt]    = (wid*1024 + lq*64 + (((kt*2 + (lg>>1)) ^ (lq&7))*8) + (lg&1)*4) * 2;
    }
    #pragma unroll
    for (int kk = 0; kk < 2; ++kk) {
        pro[kk] = (wid*1024 + lq*64 + (((kk*4+lg) ^ (lq&7))*8)) * 2;
        #pragma unroll
        for (int nt = 0; nt < 4; ++nt)
            vro[nt][kk] = ((nt*16 + lq)*64 + (((kk*4+lg) ^ (lq&7))*8)) * 2;
    }
    const char* kbase0 = (const char*)&Klds[0][0];
    const char* kbase1 = (const char*)&Klds[1][0];
    const char* vbase0 = (const char*)&Vlds[0][0];
    const char* vbase1 = (const char*)&Vlds[1][0];
    char*       pbase  = (char*)&Plds[0][0];

    const unsigned long long* mrow = mbits + ((size_t)b * SEQ + qw + lq) * (SEQ / 64);

    f32x4 o[4] = {};
    float mrun = -1e30f, lrun = 0.f;
    const float k2 = 0.125f * 1.44269504f;   // 1/sqrt(dh) * log2(e)

    // stage chunk c0 into buf 0; prefetch chunk c0's mask word
    {
        const ushort* kp0  = kgb  + (size_t)c0 * 4096;   // 64 keys * DHEAD
        const ushort* vq0  = vgb0 + c0 * 64;
        const ushort* vq1  = vgb1 + c0 * 64;
        gload_lds16(kp0,       kd0);
        gload_lds16(kp0 + 512, kd0 + 512);
        gload_lds16(vq0, vd0);
        gload_lds16(vq1, vd0 + 512);
    }
    // pointers for the NEXT chunk to stage
    const ushort* kp  = kgb  + (size_t)(c0 + 1) * 4096;
    const ushort* vp0 = vgb0 + (c0 + 1) * 64;
    const ushort* vp1 = vgb1 + (c0 + 1) * 64;
    unsigned long long mw_cur = mrow[c0];     // mask word, pipelined 1 ahead
    __syncthreads();

#define ATTN_CHUNK(CC, KD, VD, KBASE, VBASE)                                   \
    {                                                                          \
        unsigned long long mw_nxt = 0;                                         \
        if ((CC) + 1 < c1) {                                                   \
            mw_nxt = mrow[(CC) + 1];                                           \
            gload_lds16(kp,       (KD));                                       \
            gload_lds16(kp + 512, (KD) + 512);                                 \
            gload_lds16(vp0, (VD));                                            \
            gload_lds16(vp1, (VD) + 512);                                      \
            kp += 4096; vp0 += 64; vp1 += 64;                                  \
        }                                                                      \
        f32x4 st[4];                                                           \
        __builtin_amdgcn_s_setprio(1);                                         \
        _Pragma("unroll")                                                      \
        for (int kt = 0; kt < 4; ++kt) {                                       \
            bf16x8 kf0 = *(const bf16x8*)((KBASE) + kro[kt][0]);               \
            bf16x8 kf1 = *(const bf16x8*)((KBASE) + kro[kt][1]);               \
            f32x4 a = {};                                                      \
            a = __builtin_amdgcn_mfma_f32_16x16x32_bf16(kf0, qf0, a, 0, 0, 0); \
            a = __builtin_amdgcn_mfma_f32_16x16x32_bf16(kf1, qf1, a, 0, 0, 0); \
            st[kt] = a;                                                        \
        }                                                                      \
        __builtin_amdgcn_s_setprio(0);                                         \
        const unsigned long long mws = mw_cur >> (lg * 4);                     \
        const unsigned mlo = (unsigned)mws, mhi = (unsigned)(mws >> 32);       \
        float sv[16];                                                          \
        _Pragma("unroll")                                                      \
        for (int kt = 0; kt < 4; ++kt) {                                       \
            const unsigned half = (kt & 2) ? mhi : mlo;                        \
            _Pragma("unroll")                                                  \
            for (int r = 0; r < 4; ++r) {                                      \
                const unsigned bit = (half >> ((kt & 1)*16 + r)) & 1u;         \
                sv[kt*4 + r] = bit ? st[kt][r] * k2 : -1e9f;                   \
            }                                                                  \
        }                                                                      \
        float cmax = fmaxf(                                                    \
            fmaxf(fmaxf(fmaxf(sv[0],sv[1]),fmaxf(sv[2],sv[3])),                \
                  fmaxf(fmaxf(sv[4],sv[5]),fmaxf(sv[6],sv[7]))),               \
            fmaxf(fmaxf(fmaxf(sv[8],sv[9]),fmaxf(sv[10],sv[11])),              \
                  fmaxf(fmaxf(sv[12],sv[13]),fmaxf(sv[14],sv[15]))));          \
        cmax = fmaxf(cmax, __shfl_xor(cmax, 16));                              \
        cmax = fmaxf(cmax, __shfl_xor(cmax, 32));                              \
        float mnew = mrun, scale = 1.0f;                                       \
        if (!__all(cmax <= mrun)) {                                            \
            mnew  = fmaxf(mrun, cmax);                                         \
            scale = exp2f(mrun - mnew);                                        \
            float sc[4];                                                       \
            _Pragma("unroll")                                                  \
            for (int r = 0; r < 4; ++r) sc[r] = __shfl(scale, lg*4 + r);       \
            _Pragma("unroll")                                                  \
            for (int nt = 0; nt < 4; ++nt)                                     \
                _Pragma("unroll")                                              \
                for (int r = 0; r < 4; ++r) o[nt][r] *= sc[r];                 \
        }                                                                      \
        float ls[4];                                                           \
        _Pragma("unroll")                                                      \
        for (int kt = 0; kt < 4; ++kt) {                                       \
            const float p0 = exp2f(sv[kt*4+0] - mnew);                         \
            const float p1 = exp2f(sv[kt*4+1] - mnew);                         \
            const float p2 = exp2f(sv[kt*4+2] - mnew);                         \
            const float p3 = exp2f(sv[kt*4+3] - mnew);                         \
            ls[kt] = (p0 + p1) + (p2 + p3);                                    \
            uint2 pk;                                                          \
            pk.x = cvtpk_bf16(p0, p1);                                         \
            pk.y = cvtpk_bf16(p2, p3);                                         \
            *(uint2*)(pbase + pwo[kt]) = pk;                                   \
        }                                                                      \
        float lsum = (ls[0] + ls[1]) + (ls[2] + ls[3]);                        \
        lsum += __shfl_xor(lsum, 16);                                          \
        lsum += __shfl_xor(lsum, 32);                                          \
        lrun = lrun * scale + lsum;                                            \
        mrun = mnew;                                                           \
        __builtin_amdgcn_s_setprio(1);                                         \
        _Pragma("unroll")                                                      \
        for (int kk = 0; kk < 2; ++kk) {                                       \
            bf16x8 pf = *(const bf16x8*)(pbase + pro[kk]);                     \
            _Pragma("unroll")                                                  \
            for (int nt = 0; nt < 4; ++nt) {                                   \
                bf16x8 vf = *(const bf16x8*)((VBASE) + vro[nt][kk]);           \
                o[nt] = __builtin_amdgcn_mfma_f32_16x16x32_bf16(               \
                    pf, vf, o[nt], 0, 0, 0);                                   \
            }                                                                  \
        }                                                                      \
        __builtin_amdgcn_s_setprio(0);                                         \
        __syncthreads();                                                       \
        mw_cur = mw_nxt;                                                       \
    }

    for (int c = c0; c < c1; c += 2) {
        ATTN_CHUNK(c,     kd1, vd1, kbase0, vbase0);   // compute buf0, stage buf1
        ATTN_CHUNK(c + 1, kd0, vd0, kbase1, vbase1);   // compute buf1, stage buf0
    }
#undef ATTN_CHUNK

    // partial epilogue: unnormalized O (bf16) + (m, l)
    #pragma unroll
    for (int nt = 0; nt < 4; ++nt)
        #pragma unroll
        for (int r = 0; r < 4; ++r) {
            const int qrow = qw + lg*4 + r;
            Opart[(((size_t)s*16 + bh)*SEQ + qrow)*64 + nt*16 + lq] = f2bf(o[nt][r]);
        }
    if (lg == 0) {
        float2 ml; ml.x = mrun; ml.y = lrun;
        MLpart[((size_t)s*16 + bh)*SEQ + qw + lq] = ml;
    }
}

// ---------------------------------------------------------------------------
// Combine the NSPLIT KV-split parts (exact log-sum-exp merge, base-2 domain).
// ---------------------------------------------------------------------------
__global__ __launch_bounds__(256) void attn_combine_k(
    const ushort* __restrict__ Op, const float2* __restrict__ ML,
    ushort* __restrict__ attnb)
{
    const int row  = blockIdx.x * 4 + (threadIdx.x >> 6);  // bh*SEQ + q
    const int lane = threadIdx.x & 63;
    const int bh = row >> 11, q = row & 2047;
    const int b = bh >> 3, h = bh & 7;
    float2 ml[NSPLIT];
    float m = -1e30f;
    #pragma unroll
    for (int s = 0; s < NSPLIT; ++s) {
        ml[s] = ML[(size_t)s*16*SEQ + row];
        m = fmaxf(m, ml[s].x);
    }
    float l = 0.f, o = 0.f;
    #pragma unroll
    for (int s = 0; s < NSPLIT; ++s) {
        const float a = exp2f(ml[s].x - m);
        l += ml[s].y * a;
        o += bf2f(Op[((size_t)s*16*SEQ + row)*64 + lane]) * a;
    }
    attnb[((size_t)(b*SEQ + q))*DMODEL + h*DHEAD + lane] = f2bf(o / l);
}

// ---------------------------------------------------------------------------
// out = LayerNorm(X + A)*g + b over DMODEL=512.
// XBF/ABF: input dtypes (0 = f32, 1 = bf16). Outputs: f32 (outf) and/or bf16.
// ---------------------------------------------------------------------------
template<int XBF, int ABF>
__global__ __launch_bounds__(256) void add_ln_k(
    const void* __restrict__ X, const void* __restrict__ Aa,
    const float* __restrict__ gg, const float* __restrict__ bb,
    float* __restrict__ outf, ushort* __restrict__ outb)
{
    const int r = blockIdx.x;
    const int t = threadIdx.x;
    const size_t i2 = (size_t)r * 256 + t;   // index of a 2-element pair
    float x0, x1;
    if (XBF) {
        ushort2 u = ((const ushort2*)X)[i2];
        x0 = bf2f(u.x); x1 = bf2f(u.y);
    } else {
        float2 f = ((const float2*)X)[i2];
        x0 = f.x; x1 = f.y;
    }
    float a0, a1;
    if (ABF) {
        ushort2 u = ((const ushort2*)Aa)[i2];
        a0 = bf2f(u.x); a1 = bf2f(u.y);
    } else {
        float2 f = ((const float2*)Aa)[i2];
        a0 = f.x; a1 = f.y;
    }
    const float v0 = x0 + a0, v1 = x1 + a1;
    float s  = v0 + v1;
    float ss = v0*v0 + v1*v1;
    #pragma unroll
    for (int off = 32; off > 0; off >>= 1) {
        s  += __shfl_down(s,  off);
        ss += __shfl_down(ss, off);
    }
    __shared__ float ps[4], pss[4];
    const int wid = t >> 6;
    if ((t & 63) == 0) { ps[wid] = s; pss[wid] = ss; }
    __syncthreads();
    const float tot  = ps[0] + ps[1] + ps[2] + ps[3];
    const float tots = pss[0] + pss[1] + pss[2] + pss[3];
    const float mean = tot * (1.0f / DMODEL);
    const float var  = tots * (1.0f / DMODEL) - mean * mean;
    const float rstd = rsqrtf(var + 1e-5f);
    const float2 g2 = ((const float2*)gg)[t];
    const float2 b2 = ((const float2*)bb)[t];
    float2 r2;
    r2.x = (v0 - mean) * rstd * g2.x + b2.x;
    r2.y = (v1 - mean) * rstd * g2.y + b2.y;
    if (outf) ((float2*)outf)[i2] = r2;
    if (outb) {
        ushort2 ob; ob.x = f2bf(r2.x); ob.y = f2bf(r2.y);
        ((ushort2*)outb)[i2] = ob;
    }
}

// ---------------------------------------------------------------------------
extern "C" void kernel_launch(void* const* d_in, const int* in_sizes, int n_in,
                              void* d_out, int out_size, void* d_ws, size_t ws_size,
                              hipStream_t stream)
{
    const float* x      = (const float*)d_in[0];
    const void*  mask   = d_in[1];
    const float* W_qkv  = (const float*)d_in[2];
    const float* b_qkv  = (const float*)d_in[3];
    const float* W_proj = (const float*)d_in[4];
    const float* b_proj = (const float*)d_in[5];
    const float* ln1_g  = (const float*)d_in[6];
    const float* ln1_b  = (const float*)d_in[7];
    const float* W1     = (const float*)d_in[8];
    const float* b1     = (const float*)d_in[9];
    const float* W2     = (const float*)d_in[10];
    const float* b2     = (const float*)d_in[11];
    const float* ln2_g  = (const float*)d_in[12];
    const float* ln2_b  = (const float*)d_in[13];

    float* ws = (float*)d_ws;
    // Workspace (float-element offsets; SZ = 2,097,152 f32 = 8 MB):
    //  [0,   0.5) xb bf16            \
    //  [0.5, 2.0) Qb,Kb,Vtb bf16      } hb bf16 [0,2.0) in MLP phase
    //  [2.0, 2.5) attnb bf16
    //  [2.5, 4.5) Opart bf16 [4][16][SEQ][64] (attn phase)
    //    after combine: ap bf16 [2.5,3.0) | x1b bf16 [3.0,3.5) | mbuf bf16 [3.5,4.0)
    //  [4.5, 5.0) MLpart [4][16][SEQ] float2 (attn phase only)
    //  [5.0, ...) WqkvT, WprojT, W1T, W2T bf16; bits; flag
    ushort* xb    = (ushort*)ws;
    ushort* Qb    = (ushort*)(ws + SZ/2);
    ushort* Kb    = (ushort*)(ws + SZ);
    ushort* Vtb   = (ushort*)(ws + SZ + SZ/2);   // [B,H,DHEAD,SEQ]
    ushort* attnb = (ushort*)(ws + 2*SZ);
    ushort* Opart = (ushort*)(ws + 2*SZ + SZ/2); // [4][16][SEQ][64] bf16
    float2* MLp   = (float2*)(ws + 4*SZ + SZ/2); // [4][16][SEQ]
    ushort* ap    = (ushort*)(ws + 2*SZ + SZ/2); // bf16, overlays Opart (dead)
    ushort* x1b   = (ushort*)(ws + 3*SZ);        // bf16
    ushort* mbuf  = (ushort*)(ws + 3*SZ + SZ/2); // bf16
    ushort* hb    = (ushort*)ws;
    ushort* WqkvT = (ushort*)(ws + 5*SZ);                    // 512*1536
    ushort* WprojT= (ushort*)(ws + 5*SZ + 393216);           // 512*512
    ushort* W1T   = (ushort*)(ws + 5*SZ + 524288);           // 2048*512
    ushort* W2T   = (ushort*)(ws + 5*SZ + 1048576);          // 512*2048
    unsigned long long* bits = (unsigned long long*)(ws + 5*SZ + 1572864);
    int*    flag  = (int*)(ws + 5*SZ + 1572864 + 262144);

    float* out = (float*)d_out;

    hipMemsetAsync(flag, 0, 4, stream);
    detect_mask_k<<<64, 256, 0, stream>>>((const uint4*)mask, flag);
    prep_all_k<<<2816 + 32768, 256, 0, stream>>>(
        x, xb, W_qkv, W_proj, W1, W2, WqkvT, WprojT, W1T, W2T,
        mask, flag, bits);

    // QKV: [4096,512]@[512,1536] -> bf16 Q/K (row) + V (transposed)
    mgemm_k<3,64,128><<<dim3(12, 64), 256, 0, stream>>>(xb, WqkvT, b_qkv,
        nullptr, Qb, Kb, Vtb, ROWS, 3*DMODEL, DMODEL);
    // attention partials (4-way KV split) -> combine -> attnb bf16
    attn_mfma_k<<<dim3(BATCH*NH*(SEQ/64), NSPLIT), 256, 0, stream>>>(
        Qb, Kb, Vtb, bits, Opart, MLp);
    attn_combine_k<<<BATCH*NH*SEQ/4, 256, 0, stream>>>(Opart, MLp, attnb);
    // proj: [4096,512]@[512,512] -> ap bf16
    mgemm_k<4,64,64><<<dim3(8, 64), 256, 0, stream>>>(attnb, WprojT, b_proj,
        ap, nullptr, nullptr, nullptr, ROWS, DMODEL, DMODEL);
    // x1b = LN(x + ap)  (bf16 only)
    add_ln_k<0,1><<<ROWS, 256, 0, stream>>>(x, ap, ln1_g, ln1_b, nullptr, x1b);
    // MLP1: relu([4096,512]@[512,2048]) -> bf16 hb
    mgemm_k<1,64,128><<<dim3(16, 64), 256, 0, stream>>>(x1b, W1T, b1,
        hb, nullptr, nullptr, nullptr, ROWS, 2048, DMODEL);
    // MLP2: relu([4096,2048]@[2048,512]) -> bf16 mbuf
    mgemm_k<1,64,64><<<dim3(8, 64), 256, 0, stream>>>(hb, W2T, b2,
        mbuf, nullptr, nullptr, nullptr, ROWS, DMODEL, 2048);
    // out = LN(x1b + mbuf) -> f32 d_out
    add_ln_k<1,1><<<ROWS, 256, 0, stream>>>(x1b, mbuf, ln2_g, ln2_b, out, nullptr);
}

// Round 10
// 155.259 us; speedup vs baseline: 7.3221x; 1.0200x over previous
//
#include <hip/hip_runtime.h>
#include <math.h>

// Problem constants
constexpr int BATCH  = 2;
constexpr int SEQ    = 2048;
constexpr int DMODEL = 512;
constexpr int NH     = 8;
constexpr int DHEAD  = 64;
constexpr int ROWS   = BATCH * SEQ;           // 4096
constexpr size_t SZ  = (size_t)ROWS * DMODEL; // elems of one [4096][512] f32 buffer
constexpr int NSPLIT = 4;                     // attention KV-split ways

typedef __attribute__((ext_vector_type(8)))  short bf16x8;
typedef __attribute__((ext_vector_type(4)))  float f32x4;
typedef __attribute__((ext_vector_type(16))) float f32x16;

__device__ __forceinline__ ushort f2bf(float f) {
    unsigned u = __float_as_uint(f);
    unsigned r = (u + 0x7FFFu + ((u >> 16) & 1u)) >> 16;
    return (ushort)r;
}
__device__ __forceinline__ float bf2f(ushort u) {
    return __uint_as_float((unsigned)u << 16);
}

// pack 2 f32 -> 2 bf16 (RNE) in one instruction
__device__ __forceinline__ unsigned cvtpk_bf16(float lo, float hi) {
    unsigned r;
    asm("v_cvt_pk_bf16_f32 %0, %1, %2" : "=v"(r) : "v"(lo), "v"(hi));
    return r;
}

__device__ __forceinline__ void gload_lds16(const void* g, void* l) {
    __builtin_amdgcn_global_load_lds(
        (const __attribute__((address_space(1))) void*)g,
        (__attribute__((address_space(3))) void*)l, 16, 0, 0);
}

union u32x4_bf16x8 { unsigned u[4]; bf16x8 v; };

// ---------------------------------------------------------------------------
// Mask-encoding detector, parallel. flag MUST be zeroed before launch.
// ---------------------------------------------------------------------------
__global__ __launch_bounds__(256) void detect_mask_k(
    const uint4* __restrict__ m, int* __restrict__ flag)
{
    const int i = blockIdx.x * 256 + threadIdx.x;
    const uint4 v = m[i];
    unsigned b0 = 0, b1 = 0;
    #pragma unroll
    for (int c = 0; c < 4; ++c) {
        const unsigned u = (&v.x)[c];
        b0 |= (u > 1u) ? 1u : 0u;
        b1 |= (u != 0u && u != 0x3F800000u) ? 1u : 0u;
    }
    const int lane = threadIdx.x & 63;
    if (__any(b0) && lane == 0) atomicOr(flag, 1);
    if (__any(b1) && lane == 0) atomicOr(flag, 2);
}

// ---------------------------------------------------------------------------
// Fused prep: [0,2048) x f32->bf16 conv | [2048,2816) weight transpose+conv
//             [2816, 2816+32768) mask bitmask compaction
// ---------------------------------------------------------------------------
__global__ __launch_bounds__(256) void prep_all_k(
    const float* __restrict__ x, ushort* __restrict__ xb,
    const float* __restrict__ Wq, const float* __restrict__ Wp,
    const float* __restrict__ W1w, const float* __restrict__ W2w,
    ushort* __restrict__ WqT, ushort* __restrict__ WpT,
    ushort* __restrict__ W1T, ushort* __restrict__ W2T,
    const void* __restrict__ maskp, const int* __restrict__ flagp,
    unsigned long long* __restrict__ bits)
{
    __shared__ ushort T[64][65];
    const int bid = blockIdx.x;
    const int t = threadIdx.x;

    if (bid < 2048) {           // x f32 -> bf16
        const size_t i = ((size_t)bid * 256 + t) * 4;
        float4 v = *(const float4*)(x + i);
        ushort4 o;
        o.x = f2bf(v.x); o.y = f2bf(v.y); o.z = f2bf(v.z); o.w = f2bf(v.w);
        *(ushort4*)(xb + i) = o;
        return;
    }
    if (bid >= 2816) {          // mask -> bitmask
        const int w = (bid - 2816) * 4 + (t >> 6);
        const int lane = t & 63;
        const size_t idx = ((size_t)w << 6) + lane;
        const int f = *flagp;
        bool mv;
        if (!(f & 1))      mv = ((const int*)maskp)[idx] != 0;
        else if (!(f & 2)) mv = ((const float*)maskp)[idx] != 0.f;
        else               mv = ((const unsigned char*)maskp)[idx] != 0;
        unsigned long long bal = __ballot(mv);
        if (lane == 0) bits[w] = bal;
        return;
    }
    // weight transpose+convert, 64x64 tiles
    const int wb = bid - 2048;
    const float* W; ushort* Wt; int K, N, tix, tiy;
    if (wb < 192)      { W = Wq;  Wt = WqT; K = 512;  N = 1536; tix = wb % 24;        tiy = wb / 24; }
    else if (wb < 256) { W = Wp;  Wt = WpT; K = 512;  N = 512;  tix = (wb-192) % 8;   tiy = (wb-192) / 8; }
    else if (wb < 512) { W = W1w; Wt = W1T; K = 512;  N = 2048; tix = (wb-256) % 32;  tiy = (wb-256) / 32; }
    else               { W = W2w; Wt = W2T; K = 2048; N = 512;  tix = (wb-512) % 8;   tiy = (wb-512) / 8; }
    const int k0 = tiy * 64, n0 = tix * 64;
    const int r = t >> 4, c4 = (t & 15) * 4;
    #pragma unroll
    for (int it = 0; it < 4; ++it) {
        const int row = it*16 + r;
        float4 v = *(const float4*)&W[(size_t)(k0 + row) * N + n0 + c4];
        T[c4+0][row] = f2bf(v.x);
        T[c4+1][row] = f2bf(v.y);
        T[c4+2][row] = f2bf(v.z);
        T[c4+3][row] = f2bf(v.w);
    }
    __syncthreads();
    #pragma unroll
    for (int it = 0; it < 4; ++it) {
        const int row = it*16 + r;
        ushort4 o;
        o.x = T[row][c4+0]; o.y = T[row][c4+1];
        o.z = T[row][c4+2]; o.w = T[row][c4+3];
        *(ushort4*)&Wt[(size_t)(n0 + row) * K + k0 + c4] = o;
    }
}

// ---------------------------------------------------------------------------
// bf16 MFMA GEMM (m97 structure): C[M,N] = A[M,K] @ Wt[N,K]^T + bias.
// EPI: 1 = relu(bias) -> bf16 | 3 = QKV scatter (V transposed) | 4 = bias -> bf16
// ---------------------------------------------------------------------------
template<int EPI, int BM, int BN>
__global__ __launch_bounds__(256) void mgemm_k(
    const ushort* __restrict__ A,   // [M][K] bf16
    const ushort* __restrict__ Wt,  // [N][K] bf16
    const float* __restrict__ bias, // [N] f32
    ushort* __restrict__ Cb,
    ushort* __restrict__ Qo, ushort* __restrict__ Ko, ushort* __restrict__ Vo,
    int M, int N, int K)
{
    constexpr int WM  = BM / 2, WN = BN / 2;
    constexpr int MF  = WM / 16, NF = WN / 16;
    constexpr int APW = BM / 32;
    constexpr int BPW = BN / 32;

    __shared__ ushort As[BM * 64];
    __shared__ ushort Bs[BN * 64];

    const int tid  = threadIdx.x;
    const int wid  = tid >> 6, lane = tid & 63;
    const int lq   = lane & 15, lg = lane >> 4;
    const int wr   = wid >> 1,  wc = wid & 1;
    const int bm   = blockIdx.y * BM, bn = blockIdx.x * BN;

    const int srow0 = lane >> 3;
    const int sch   = lane & 7;

    f32x4 acc[MF][NF] = {};

    for (int k0 = 0; k0 < K; k0 += 64) {
        __syncthreads();
        #pragma unroll
        for (int i = 0; i < APW; ++i) {
            const int seg = wid * APW + i;
            const int row = seg * 8 + srow0;
            const int c16 = sch ^ (row & 7);
            gload_lds16(A + (size_t)(bm + row) * K + k0 + c16 * 8, As + seg * 512);
        }
        #pragma unroll
        for (int i = 0; i < BPW; ++i) {
            const int seg = wid * BPW + i;
            const int row = seg * 8 + srow0;
            const int c16 = sch ^ (row & 7);
            gload_lds16(Wt + (size_t)(bn + row) * K + k0 + c16 * 8, Bs + seg * 512);
        }
        __syncthreads();

        #pragma unroll
        for (int ks = 0; ks < 2; ++ks) {
            bf16x8 af[MF], bfr[NF];
            #pragma unroll
            for (int m = 0; m < MF; ++m) {
                const int row = wr*WM + m*16 + lq;
                const int c16 = (ks*4 + lg) ^ (row & 7);
                af[m] = *(const bf16x8*)&As[row * 64 + c16 * 8];
            }
            #pragma unroll
            for (int n = 0; n < NF; ++n) {
                const int row = wc*WN + n*16 + lq;
                const int c16 = (ks*4 + lg) ^ (row & 7);
                bfr[n] = *(const bf16x8*)&Bs[row * 64 + c16 * 8];
            }
            #pragma unroll
            for (int m = 0; m < MF; ++m)
                #pragma unroll
                for (int n = 0; n < NF; ++n)
                    acc[m][n] = __builtin_amdgcn_mfma_f32_16x16x32_bf16(
                        af[m], bfr[n], acc[m][n], 0, 0, 0);
        }
    }

    #pragma unroll
    for (int m = 0; m < MF; ++m) {
        const int row0 = bm + wr*WM + m*16 + lg*4;
        #pragma unroll
        for (int n = 0; n < NF; ++n) {
            const int col = bn + wc*WN + n*16 + lq;
            const float bv = bias[col];
            float v[4];
            #pragma unroll
            for (int r = 0; r < 4; ++r) {
                v[r] = acc[m][n][r] + bv;
                if (EPI == 1) v[r] = fmaxf(v[r], 0.f);
            }
            if (EPI == 3) {
                const int part = col >> 9, hc = col & 511;
                const int hh = hc >> 6, d0 = hc & 63;
                const int bidx = row0 >> 11, nrow0 = row0 & 2047;
                if (part == 2) {
                    ushort4 pv;
                    pv.x = f2bf(v[0]); pv.y = f2bf(v[1]);
                    pv.z = f2bf(v[2]); pv.w = f2bf(v[3]);
                    *(ushort4*)(Vo + (((size_t)bidx*NH + hh)*DHEAD + d0)*SEQ + nrow0) = pv;
                } else {
                    ushort* dst = (part == 0) ? Qo : Ko;
                    #pragma unroll
                    for (int r = 0; r < 4; ++r)
                        dst[((((size_t)bidx*NH + hh)*SEQ + nrow0 + r) << 6) + d0] = f2bf(v[r]);
                }
            } else {
                #pragma unroll
                for (int r = 0; r < 4; ++r)
                    Cb[(size_t)(row0 + r) * N + col] = f2bf(v[r]);
            }
        }
    }
}

// ---------------------------------------------------------------------------
// bf16 MFMA flash attention, v7: 32x32 swapped structure (m214 family).
//  - S^T = mfma_32x32x16(K, Q): softmax rows lane-local (q = lane&31)
//  - P stays in registers: cvt_pk + half-exchange (shfl_xor 32) builds PV A-frags
//  - defer-max THR=8 (exact LSE merge), k2 scale folded into Q regs
//  - LDS 32KB (no P buffer) -> grid 1024 = 4 blocks/CU, all resident
// Grid: (256, NSPLIT); x = tile*16 + bh so linear%8 = bh%8 (XCD locality).
// Wave owns 32 q rows; block = 128 q; chunk = 64 keys.
// ---------------------------------------------------------------------------
__global__ __launch_bounds__(256, 4) void attn_mfma_k(
    const ushort* __restrict__ Qb, const ushort* __restrict__ Kb,
    const ushort* __restrict__ Vtb, const unsigned long long* __restrict__ mbits,
    ushort* __restrict__ Opart, float2* __restrict__ MLpart)
{
    __shared__ ushort Klds[2][64 * 64];   // [key][d], XOR-swizzled 16B chunks
    __shared__ ushort Vlds[2][64 * 64];   // [d][key], XOR-swizzled

    const int tid  = threadIdx.x;
    const int wid  = tid >> 6;
    const int lane = tid & 63;
    const int l31  = lane & 31;
    const int hi   = lane >> 5;

    const int bh   = blockIdx.x & 15;
    const int tile = blockIdx.x >> 4;     // 0..15 (SEQ/128 q-tiles)
    const int b    = bh >> 3;
    const int qw   = tile * 128 + wid * 32;
    const int s    = blockIdx.y;
    const int c0   = s * 8, c1 = c0 + 8;

    const float k2 = 0.125f * 1.44269504f;   // 1/sqrt(dh) * log2(e)

    // Q fragments (B-operand of 32x32x16): col=q=lane&31, k=hi*8+j within each
    // 16-d slice kd. Pre-scaled by k2 (folded softmax scale).
    bf16x8 qf[4];
    {
        const ushort* Qg = Qb + ((size_t)bh * SEQ + qw + l31) * DHEAD;
        #pragma unroll
        for (int kd = 0; kd < 4; ++kd) {
            bf16x8 raw = *(const bf16x8*)(Qg + kd*16 + hi*8);
            u32x4_bf16x8 cc;
            #pragma unroll
            for (int p2 = 0; p2 < 4; ++p2) {
                const float a = bf2f((ushort)raw[2*p2])   * k2;
                const float c = bf2f((ushort)raw[2*p2+1]) * k2;
                cc.u[p2] = cvtpk_bf16(a, c);
            }
            qf[kd] = cc.v;
        }
    }

    const int srow0 = lane >> 3;
    const int sch   = lane & 7;
    const int gc8   = (sch ^ srow0) * 8;      // inverse-swizzled global col

    const ushort* kgb  = Kb  + (size_t)bh * SEQ * DHEAD
                             + (size_t)(wid*16 + srow0) * DHEAD + gc8;
    const ushort* vgb0 = Vtb + (size_t)bh * DHEAD * SEQ
                             + (size_t)(wid*16 + srow0) * SEQ + gc8;
    const ushort* vgb1 = vgb0 + 8 * SEQ;

    ushort* kd0 = &Klds[0][(wid*2)*512];
    ushort* kd1 = &Klds[1][(wid*2)*512];
    ushort* vd0 = &Vlds[0][(wid*2)*512];
    ushort* vd1 = &Vlds[1][(wid*2)*512];

    // hoisted LDS byte offsets. K A-frag (kt,kd): row=kt*32+l31, chunk=(kd*2+hi)^(lane&7)
    // V B-frag (ks,dt): row=dt*32+l31, chunk=(ks*2+hi)^(lane&7)
    int kro0[4], kro1[4], vro[4][2];
    #pragma unroll
    for (int kd = 0; kd < 4; ++kd) {
        kro0[kd] = ( (l31)      * 64 + (((kd*2+hi) ^ (lane&7)) * 8) ) * 2;
        kro1[kd] = ( (32 + l31) * 64 + (((kd*2+hi) ^ (lane&7)) * 8) ) * 2;
    }
    #pragma unroll
    for (int ks = 0; ks < 4; ++ks)
        #pragma unroll
        for (int dt = 0; dt < 2; ++dt)
            vro[ks][dt] = ( (dt*32 + l31) * 64 + (((ks*2+hi) ^ (lane&7)) * 8) ) * 2;

    const char* kbase0 = (const char*)&Klds[0][0];
    const char* kbase1 = (const char*)&Klds[1][0];
    const char* vbase0 = (const char*)&Vlds[0][0];
    const char* vbase1 = (const char*)&Vlds[1][0];

    const unsigned long long* mrow = mbits + ((size_t)b * SEQ + qw + l31) * (SEQ / 64);

    f32x16 o0 = {}, o1 = {};   // O[q][d]: col=d=l31(+dt*32), row q=(r&3)+8(r>>2)+4hi
    float mrun = -1e30f, lrun = 0.f;

    // stage chunk c0 into buf 0
    {
        const ushort* kp0 = kgb  + (size_t)c0 * 4096;
        const ushort* vq0 = vgb0 + c0 * 64;
        const ushort* vq1 = vgb1 + c0 * 64;
        gload_lds16(kp0,       kd0);
        gload_lds16(kp0 + 512, kd0 + 512);
        gload_lds16(vq0, vd0);
        gload_lds16(vq1, vd0 + 512);
    }
    const ushort* kp  = kgb  + (size_t)(c0 + 1) * 4096;
    const ushort* vp0 = vgb0 + (c0 + 1) * 64;
    const ushort* vp1 = vgb1 + (c0 + 1) * 64;
    unsigned long long mw_cur = mrow[c0];
    __syncthreads();

#define ATTN_CHUNK(CC, KD, VD, KBASE, VBASE)                                   \
    {                                                                          \
        unsigned long long mw_nxt = 0;                                         \
        if ((CC) + 1 < c1) {                                                   \
            mw_nxt = mrow[(CC) + 1];                                           \
            gload_lds16(kp,       (KD));                                       \
            gload_lds16(kp + 512, (KD) + 512);                                 \
            gload_lds16(vp0, (VD));                                            \
            gload_lds16(vp1, (VD) + 512);                                      \
            kp += 4096; vp0 += 64; vp1 += 64;                                  \
        }                                                                      \
        f32x16 st0 = {}, st1 = {};                                             \
        __builtin_amdgcn_s_setprio(1);                                         \
        _Pragma("unroll")                                                      \
        for (int kd = 0; kd < 4; ++kd) {                                       \
            bf16x8 kf0 = *(const bf16x8*)((KBASE) + kro0[kd]);                 \
            bf16x8 kf1 = *(const bf16x8*)((KBASE) + kro1[kd]);                 \
            st0 = __builtin_amdgcn_mfma_f32_32x32x16_bf16(kf0, qf[kd], st0, 0, 0, 0); \
            st1 = __builtin_amdgcn_mfma_f32_32x32x16_bf16(kf1, qf[kd], st1, 0, 0, 0); \
        }                                                                      \
        __builtin_amdgcn_s_setprio(0);                                         \
        const unsigned long long mws = mw_cur >> (hi * 4);                     \
        const unsigned mlo = (unsigned)mws, mhi2 = (unsigned)(mws >> 32);      \
        _Pragma("unroll")                                                      \
        for (int r = 0; r < 16; ++r) {                                         \
            const int pos = (r & 3) + 8 * (r >> 2);                            \
            st0[r] = ((mlo  >> pos) & 1u) ? st0[r] : -1e9f;                    \
            st1[r] = ((mhi2 >> pos) & 1u) ? st1[r] : -1e9f;                    \
        }                                                                      \
        float cm0 = fmaxf(fmaxf(fmaxf(st0[0],st0[1]),fmaxf(st0[2],st0[3])),    \
                          fmaxf(fmaxf(st0[4],st0[5]),fmaxf(st0[6],st0[7])));   \
        cm0 = fmaxf(cm0, fmaxf(fmaxf(fmaxf(st0[8],st0[9]),fmaxf(st0[10],st0[11])), \
                               fmaxf(fmaxf(st0[12],st0[13]),fmaxf(st0[14],st0[15])))); \
        float cm1 = fmaxf(fmaxf(fmaxf(st1[0],st1[1]),fmaxf(st1[2],st1[3])),    \
                          fmaxf(fmaxf(st1[4],st1[5]),fmaxf(st1[6],st1[7])));   \
        cm1 = fmaxf(cm1, fmaxf(fmaxf(fmaxf(st1[8],st1[9]),fmaxf(st1[10],st1[11])), \
                               fmaxf(fmaxf(st1[12],st1[13]),fmaxf(st1[14],st1[15])))); \
        float cmax = fmaxf(cm0, cm1);                                          \
        cmax = fmaxf(cmax, __shfl_xor(cmax, 32));                              \
        if (!__all(cmax <= mrun + 8.0f)) {                                     \
            const float mnew  = fmaxf(mrun, cmax);                             \
            const float scale = exp2f(mrun - mnew);                            \
            _Pragma("unroll")                                                  \
            for (int r = 0; r < 16; ++r) {                                     \
                const float sc = __shfl(scale, (r&3) + 8*(r>>2) + 4*hi);       \
                o0[r] *= sc; o1[r] *= sc;                                      \
            }                                                                  \
            lrun *= scale;                                                     \
            mrun = mnew;                                                       \
        }                                                                      \
        float lsum = 0.f;                                                      \
        _Pragma("unroll")                                                      \
        for (int r = 0; r < 16; ++r) {                                         \
            st0[r] = exp2f(st0[r] - mrun);                                     \
            st1[r] = exp2f(st1[r] - mrun);                                     \
            lsum += st0[r] + st1[r];                                           \
        }                                                                      \
        lsum += __shfl_xor(lsum, 32);                                          \
        lrun += lsum;                                                          \
        unsigned w0[8], w1[8];                                                 \
        _Pragma("unroll")                                                      \
        for (int g = 0; g < 4; ++g) {                                          \
            w0[2*g]   = cvtpk_bf16(st0[4*g+0], st0[4*g+1]);                    \
            w0[2*g+1] = cvtpk_bf16(st0[4*g+2], st0[4*g+3]);                    \
            w1[2*g]   = cvtpk_bf16(st1[4*g+0], st1[4*g+1]);                    \
            w1[2*g+1] = cvtpk_bf16(st1[4*g+2], st1[4*g+3]);                    \
        }                                                                      \
        unsigned rcv0[4], rcv1[4];                                             \
        _Pragma("unroll")                                                      \
        for (int i = 0; i < 4; ++i) {                                          \
            const int i2 = i >> 1, wi = i & 1;                                 \
            const unsigned s0 = hi ? w0[4*i2+wi] : w0[4*i2+2+wi];              \
            const unsigned s1 = hi ? w1[4*i2+wi] : w1[4*i2+2+wi];              \
            rcv0[i] = (unsigned)__shfl_xor((int)s0, 32);                       \
            rcv1[i] = (unsigned)__shfl_xor((int)s1, 32);                       \
        }                                                                      \
        __builtin_amdgcn_s_setprio(1);                                         \
        _Pragma("unroll")                                                      \
        for (int ks = 0; ks < 4; ++ks) {                                       \
            const int i2 = ks & 1;                                             \
            u32x4_bf16x8 fw;                                                   \
            if (ks < 2) {                                                      \
                fw.u[0] = hi ? rcv0[2*i2+0] : w0[4*i2+0];                      \
                fw.u[1] = hi ? rcv0[2*i2+1] : w0[4*i2+1];                      \
                fw.u[2] = hi ? w0[4*i2+2]   : rcv0[2*i2+0];                    \
                fw.u[3] = hi ? w0[4*i2+3]   : rcv0[2*i2+1];                    \
            } else {                                                           \
                fw.u[0] = hi ? rcv1[2*i2+0] : w1[4*i2+0];                      \
                fw.u[1] = hi ? rcv1[2*i2+1] : w1[4*i2+1];                      \
                fw.u[2] = hi ? w1[4*i2+2]   : rcv1[2*i2+0];                    \
                fw.u[3] = hi ? w1[4*i2+3]   : rcv1[2*i2+1];                    \
            }                                                                  \
            bf16x8 vf0 = *(const bf16x8*)((VBASE) + vro[ks][0]);               \
            bf16x8 vf1 = *(const bf16x8*)((VBASE) + vro[ks][1]);               \
            o0 = __builtin_amdgcn_mfma_f32_32x32x16_bf16(fw.v, vf0, o0, 0, 0, 0); \
            o1 = __builtin_amdgcn_mfma_f32_32x32x16_bf16(fw.v, vf1, o1, 0, 0, 0); \
        }                                                                      \
        __builtin_amdgcn_s_setprio(0);                                         \
        __syncthreads();                                                       \
        mw_cur = mw_nxt;                                                       \
    }

    for (int c = c0; c < c1; c += 2) {
        ATTN_CHUNK(c,     kd1, vd1, kbase0, vbase0);   // compute buf0, stage buf1
        ATTN_CHUNK(c + 1, kd0, vd0, kbase1, vbase1);   // compute buf1, stage buf0
    }
#undef ATTN_CHUNK

    // partial epilogue: unnormalized O (bf16) + (m, l)
    #pragma unroll
    for (int r = 0; r < 16; ++r) {
        const int qrow = qw + (r&3) + 8*(r>>2) + 4*hi;
        const size_t base = (((size_t)s*16 + bh)*SEQ + qrow)*64;
        Opart[base + l31]      = f2bf(o0[r]);
        Opart[base + 32 + l31] = f2bf(o1[r]);
    }
    if (hi == 0) {
        float2 ml; ml.x = mrun; ml.y = lrun;
        MLpart[((size_t)s*16 + bh)*SEQ + qw + l31] = ml;
    }
}

// ---------------------------------------------------------------------------
// Combine the NSPLIT KV-split parts (exact log-sum-exp merge, base-2 domain).
// ---------------------------------------------------------------------------
__global__ __launch_bounds__(256) void attn_combine_k(
    const ushort* __restrict__ Op, const float2* __restrict__ ML,
    ushort* __restrict__ attnb)
{
    const int row  = blockIdx.x * 4 + (threadIdx.x >> 6);  // bh*SEQ + q
    const int lane = threadIdx.x & 63;
    const int bh = row >> 11, q = row & 2047;
    const int b = bh >> 3, h = bh & 7;
    float2 ml[NSPLIT];
    float m = -1e30f;
    #pragma unroll
    for (int s = 0; s < NSPLIT; ++s) {
        ml[s] = ML[(size_t)s*16*SEQ + row];
        m = fmaxf(m, ml[s].x);
    }
    float l = 0.f, o = 0.f;
    #pragma unroll
    for (int s = 0; s < NSPLIT; ++s) {
        const float a = exp2f(ml[s].x - m);
        l += ml[s].y * a;
        o += bf2f(Op[((size_t)s*16*SEQ + row)*64 + lane]) * a;
    }
    attnb[((size_t)(b*SEQ + q))*DMODEL + h*DHEAD + lane] = f2bf(o / l);
}

// ---------------------------------------------------------------------------
// out = LayerNorm(X + A)*g + b over DMODEL=512.
// XBF/ABF: input dtypes (0 = f32, 1 = bf16). Outputs: f32 (outf) and/or bf16.
// ---------------------------------------------------------------------------
template<int XBF, int ABF>
__global__ __launch_bounds__(256) void add_ln_k(
    const void* __restrict__ X, const void* __restrict__ Aa,
    const float* __restrict__ gg, const float* __restrict__ bb,
    float* __restrict__ outf, ushort* __restrict__ outb)
{
    const int r = blockIdx.x;
    const int t = threadIdx.x;
    const size_t i2 = (size_t)r * 256 + t;   // index of a 2-element pair
    float x0, x1;
    if (XBF) {
        ushort2 u = ((const ushort2*)X)[i2];
        x0 = bf2f(u.x); x1 = bf2f(u.y);
    } else {
        float2 f = ((const float2*)X)[i2];
        x0 = f.x; x1 = f.y;
    }
    float a0, a1;
    if (ABF) {
        ushort2 u = ((const ushort2*)Aa)[i2];
        a0 = bf2f(u.x); a1 = bf2f(u.y);
    } else {
        float2 f = ((const float2*)Aa)[i2];
        a0 = f.x; a1 = f.y;
    }
    const float v0 = x0 + a0, v1 = x1 + a1;
    float s  = v0 + v1;
    float ss = v0*v0 + v1*v1;
    #pragma unroll
    for (int off = 32; off > 0; off >>= 1) {
        s  += __shfl_down(s,  off);
        ss += __shfl_down(ss, off);
    }
    __shared__ float ps[4], pss[4];
    const int wid = t >> 6;
    if ((t & 63) == 0) { ps[wid] = s; pss[wid] = ss; }
    __syncthreads();
    const float tot  = ps[0] + ps[1] + ps[2] + ps[3];
    const float tots = pss[0] + pss[1] + pss[2] + pss[3];
    const float mean = tot * (1.0f / DMODEL);
    const float var  = tots * (1.0f / DMODEL) - mean * mean;
    const float rstd = rsqrtf(var + 1e-5f);
    const float2 g2 = ((const float2*)gg)[t];
    const float2 b2 = ((const float2*)bb)[t];
    float2 r2;
    r2.x = (v0 - mean) * rstd * g2.x + b2.x;
    r2.y = (v1 - mean) * rstd * g2.y + b2.y;
    if (outf) ((float2*)outf)[i2] = r2;
    if (outb) {
        ushort2 ob; ob.x = f2bf(r2.x); ob.y = f2bf(r2.y);
        ((ushort2*)outb)[i2] = ob;
    }
}

// ---------------------------------------------------------------------------
extern "C" void kernel_launch(void* const* d_in, const int* in_sizes, int n_in,
                              void* d_out, int out_size, void* d_ws, size_t ws_size,
                              hipStream_t stream)
{
    const float* x      = (const float*)d_in[0];
    const void*  mask   = d_in[1];
    const float* W_qkv  = (const float*)d_in[2];
    const float* b_qkv  = (const float*)d_in[3];
    const float* W_proj = (const float*)d_in[4];
    const float* b_proj = (const float*)d_in[5];
    const float* ln1_g  = (const float*)d_in[6];
    const float* ln1_b  = (const float*)d_in[7];
    const float* W1     = (const float*)d_in[8];
    const float* b1     = (const float*)d_in[9];
    const float* W2     = (const float*)d_in[10];
    const float* b2     = (const float*)d_in[11];
    const float* ln2_g  = (const float*)d_in[12];
    const float* ln2_b  = (const float*)d_in[13];

    float* ws = (float*)d_ws;
    ushort* xb    = (ushort*)ws;
    ushort* Qb    = (ushort*)(ws + SZ/2);
    ushort* Kb    = (ushort*)(ws + SZ);
    ushort* Vtb   = (ushort*)(ws + SZ + SZ/2);   // [B,H,DHEAD,SEQ]
    ushort* attnb = (ushort*)(ws + 2*SZ);
    ushort* Opart = (ushort*)(ws + 2*SZ + SZ/2); // [4][16][SEQ][64] bf16
    float2* MLp   = (float2*)(ws + 4*SZ + SZ/2); // [4][16][SEQ]
    ushort* ap    = (ushort*)(ws + 2*SZ + SZ/2); // bf16, overlays Opart (dead)
    ushort* x1b   = (ushort*)(ws + 3*SZ);        // bf16
    ushort* mbuf  = (ushort*)(ws + 3*SZ + SZ/2); // bf16
    ushort* hb    = (ushort*)ws;
    ushort* WqkvT = (ushort*)(ws + 5*SZ);                    // 512*1536
    ushort* WprojT= (ushort*)(ws + 5*SZ + 393216);           // 512*512
    ushort* W1T   = (ushort*)(ws + 5*SZ + 524288);           // 2048*512
    ushort* W2T   = (ushort*)(ws + 5*SZ + 1048576);          // 512*2048
    unsigned long long* bits = (unsigned long long*)(ws + 5*SZ + 1572864);
    int*    flag  = (int*)(ws + 5*SZ + 1572864 + 262144);

    float* out = (float*)d_out;

    hipMemsetAsync(flag, 0, 4, stream);
    detect_mask_k<<<64, 256, 0, stream>>>((const uint4*)mask, flag);
    prep_all_k<<<2816 + 32768, 256, 0, stream>>>(
        x, xb, W_qkv, W_proj, W1, W2, WqkvT, WprojT, W1T, W2T,
        mask, flag, bits);

    // QKV: [4096,512]@[512,1536] -> bf16 Q/K (row) + V (transposed)
    mgemm_k<3,64,128><<<dim3(12, 64), 256, 0, stream>>>(xb, WqkvT, b_qkv,
        nullptr, Qb, Kb, Vtb, ROWS, 3*DMODEL, DMODEL);
    // attention partials (4-way KV split) -> combine -> attnb bf16
    attn_mfma_k<<<dim3(256, NSPLIT), 256, 0, stream>>>(
        Qb, Kb, Vtb, bits, Opart, MLp);
    attn_combine_k<<<BATCH*NH*SEQ/4, 256, 0, stream>>>(Opart, MLp, attnb);
    // proj: [4096,512]@[512,512] -> ap bf16
    mgemm_k<4,64,64><<<dim3(8, 64), 256, 0, stream>>>(attnb, WprojT, b_proj,
        ap, nullptr, nullptr, nullptr, ROWS, DMODEL, DMODEL);
    // x1b = LN(x + ap)  (bf16 only)
    add_ln_k<0,1><<<ROWS, 256, 0, stream>>>(x, ap, ln1_g, ln1_b, nullptr, x1b);
    // MLP1: relu([4096,512]@[512,2048]) -> bf16 hb
    mgemm_k<1,64,128><<<dim3(16, 64), 256, 0, stream>>>(x1b, W1T, b1,
        hb, nullptr, nullptr, nullptr, ROWS, 2048, DMODEL);
    // MLP2: relu([4096,2048]@[2048,512]) -> bf16 mbuf
    mgemm_k<1,64,64><<<dim3(8, 64), 256, 0, stream>>>(hb, W2T, b2,
        mbuf, nullptr, nullptr, nullptr, ROWS, DMODEL, 2048);
    // out = LN(x1b + mbuf) -> f32 d_out
    add_ln_k<1,1><<<ROWS, 256, 0, stream>>>(x1b, mbuf, ln2_g, ln2_b, out, nullptr);
}